// Round 2
// baseline (1241.828 us; speedup 1.0000x reference)
//
#include <hip/hip_runtime.h>
#include <math.h>

#define BB   8
#define NN   2048
#define KNbr 16
#define BNpts 16384
#define BNKr  262144
#define NBS   256

__device__ __forceinline__ double elu_d(double v) { return v > 0.0 ? v : expm1(v); }

// ---------------- KNN: f32 distances emulating XLA rounding, stable top-16 ----
__global__ __launch_bounds__(256) void knn_kernel(const float* __restrict__ pos,
                                                  int* __restrict__ idxout,
                                                  float* __restrict__ drel) {
  int bn = blockIdx.x;
  int b = bn >> 11, n = bn & (NN - 1);
  const float* pb = pos + (size_t)b * NN * 3;
  __shared__ float d2s[NN];
  __shared__ float wv[4];
  __shared__ int   wi[4];
  float qx = pb[n*3], qy = pb[n*3+1], qz = pb[n*3+2];
  // sq: products rounded individually, then summed left-to-right (XLA mul+reduce)
  float sqn = __fadd_rn(__fadd_rn(__fmul_rn(qx,qx), __fmul_rn(qy,qy)), __fmul_rn(qz,qz));
  for (int m = threadIdx.x; m < NN; m += 256) {
    float px = pb[m*3], py = pb[m*3+1], pz = pb[m*3+2];
    float sqm = __fadd_rn(__fadd_rn(__fmul_rn(px,px), __fmul_rn(py,py)), __fmul_rn(pz,pz));
    // dot: ascending-k FMA chain (sgemm style)
    float dot = __fmaf_rn(qz, pz, __fmaf_rn(qy, py, __fmul_rn(qx, px)));
    d2s[m] = __fsub_rn(__fadd_rn(sqn, sqm), __fmul_rn(2.0f, dot));
  }
  __syncthreads();
  int lane = threadIdx.x & 63, wav = threadIdx.x >> 6;
  for (int k = 0; k < KNbr; ++k) {
    float bv = INFINITY; int bi = 1 << 30;
    for (int m = threadIdx.x; m < NN; m += 256) {
      float v = d2s[m];
      if (v < bv || (v == bv && m < bi)) { bv = v; bi = m; }
    }
    for (int s = 32; s > 0; s >>= 1) {
      float ov = __shfl_down(bv, s);
      int   oi = __shfl_down(bi, s);
      if (ov < bv || (ov == bv && oi < bi)) { bv = ov; bi = oi; }
    }
    if (lane == 0) { wv[wav] = bv; wi[wav] = bi; }
    __syncthreads();
    if (threadIdx.x == 0) {
      float fv = wv[0]; int fi = wi[0];
      for (int w = 1; w < 4; ++w)
        if (wv[w] < fv || (wv[w] == fv && wi[w] < fi)) { fv = wv[w]; fi = wi[w]; }
      idxout[bn*KNbr + k] = fi;
      d2s[fi] = INFINITY;
      drel[(size_t)(bn*KNbr + k)*3 + 0] = __fsub_rn(qx, pb[fi*3+0]);
      drel[(size_t)(bn*KNbr + k)*3 + 1] = __fsub_rn(qy, pb[fi*3+1]);
      drel[(size_t)(bn*KNbr + k)*3 + 2] = __fsub_rn(qz, pb[fi*3+2]);
    }
    __syncthreads();
  }
}

// ---------------- stats over mlp1 layer 1 output (f64) ----
__global__ __launch_bounds__(256) void stats1a_kernel(const float* __restrict__ drel,
                                                      const float* __restrict__ W1,
                                                      const float* __restrict__ b1,
                                                      double* __restrict__ part) {
  __shared__ float sW[48]; __shared__ float sb[16];
  if (threadIdx.x < 48) sW[threadIdx.x] = W1[threadIdx.x];
  if (threadIdx.x < 16) sb[threadIdx.x] = b1[threadIdx.x];
  __syncthreads();
  double s[16], s2[16];
#pragma unroll
  for (int c = 0; c < 16; ++c) { s[c] = 0.0; s2[c] = 0.0; }
  for (int r = blockIdx.x*256 + threadIdx.x; r < BNKr; r += NBS*256) {
    double a0 = drel[(size_t)r*3], a1 = drel[(size_t)r*3+1], a2 = drel[(size_t)r*3+2];
#pragma unroll
    for (int c = 0; c < 16; ++c) {
      double v = a0*(double)sW[c] + a1*(double)sW[16+c] + a2*(double)sW[32+c] + (double)sb[c];
      double e = elu_d(v);
      s[c] += e; s2[c] += e*e;
    }
  }
  __shared__ double wred[4][32];
  int lane = threadIdx.x & 63, wav = threadIdx.x >> 6;
#pragma unroll
  for (int j = 0; j < 32; ++j) {
    double v = (j < 16) ? s[j] : s2[j-16];
    for (int sh = 32; sh > 0; sh >>= 1) v += __shfl_down(v, sh);
    if (lane == 0) wred[wav][j] = v;
  }
  __syncthreads();
  if (threadIdx.x < 32)
    part[(size_t)blockIdx.x*32 + threadIdx.x] =
      wred[0][threadIdx.x] + wred[1][threadIdx.x] + wred[2][threadIdx.x] + wred[3][threadIdx.x];
}

// ---------------- BN reduce: f64 partials -> scale/shift (f64) ----
__global__ void bnreduce_kernel(const double* __restrict__ part, int nb, int nch, double nrows,
                                const float* __restrict__ g, const float* __restrict__ be,
                                double* __restrict__ bnp) {
  int c = threadIdx.x;
  if (c >= nch) return;
  double S = 0.0, S2 = 0.0;
  for (int bk = 0; bk < nb; ++bk) {
    S  += part[(size_t)bk*2*nch + c];
    S2 += part[(size_t)bk*2*nch + nch + c];
  }
  double m = S / nrows;
  double var = S2 / nrows - m*m;
  double sc = (double)g[c] / sqrt(var + 1e-5);
  bnp[c]       = sc;
  bnp[nch + c] = (double)be[c] - m*sc;
}

// ---------------- stats over mlp1 layer 2 output (recompute h1, f64) ----
__global__ __launch_bounds__(256) void stats1b_kernel(const float* __restrict__ drel,
                                                      const float* __restrict__ W1,
                                                      const float* __restrict__ b1,
                                                      const double* __restrict__ bn1,
                                                      const float* __restrict__ W2,
                                                      const float* __restrict__ b2,
                                                      double* __restrict__ part) {
  __shared__ float sW1[48], sb1v[16], sW2[256], sb2v[16];
  __shared__ double dsc[16], dsh[16];
  if (threadIdx.x < 48) sW1[threadIdx.x] = W1[threadIdx.x];
  if (threadIdx.x < 16) {
    sb1v[threadIdx.x] = b1[threadIdx.x];
    sb2v[threadIdx.x] = b2[threadIdx.x];
    dsc[threadIdx.x] = bn1[threadIdx.x];
    dsh[threadIdx.x] = bn1[16 + threadIdx.x];
  }
  sW2[threadIdx.x] = W2[threadIdx.x];
  __syncthreads();
  double s[16], s2[16];
#pragma unroll
  for (int c = 0; c < 16; ++c) { s[c] = 0.0; s2[c] = 0.0; }
  for (int r = blockIdx.x*256 + threadIdx.x; r < BNKr; r += NBS*256) {
    double a0 = drel[(size_t)r*3], a1 = drel[(size_t)r*3+1], a2 = drel[(size_t)r*3+2];
    double y[16];
#pragma unroll
    for (int c = 0; c < 16; ++c) {
      double v = a0*(double)sW1[c] + a1*(double)sW1[16+c] + a2*(double)sW1[32+c] + (double)sb1v[c];
      y[c] = elu_d(v)*dsc[c] + dsh[c];
    }
#pragma unroll
    for (int c2 = 0; c2 < 16; ++c2) {
      double v = (double)sb2v[c2];
#pragma unroll
      for (int c = 0; c < 16; ++c) v += y[c]*(double)sW2[c*16 + c2];
      double e = elu_d(v);
      s[c2] += e; s2[c2] += e*e;
    }
  }
  __shared__ double wred[4][32];
  int lane = threadIdx.x & 63, wav = threadIdx.x >> 6;
#pragma unroll
  for (int j = 0; j < 32; ++j) {
    double v = (j < 16) ? s[j] : s2[j-16];
    for (int sh = 32; sh > 0; sh >>= 1) v += __shfl_down(v, sh);
    if (lane == 0) wred[wav][j] = v;
  }
  __syncthreads();
  if (threadIdx.x < 32)
    part[(size_t)blockIdx.x*32 + threadIdx.x] =
      wred[0][threadIdx.x] + wred[1][threadIdx.x] + wred[2][threadIdx.x] + wred[3][threadIdx.x];
}

// ---------------- stats over mlp2 linear output (f64) ----
__global__ __launch_bounds__(256) void stats2l_kernel(const float* __restrict__ drel,
                                                      const float* __restrict__ Wl,
                                                      const float* __restrict__ bl,
                                                      double* __restrict__ part) {
  __shared__ float srow[48];
  int tid = threadIdx.x;
  double bias = (double)bl[tid];
  double s = 0.0, s2 = 0.0;
  for (int r = blockIdx.x; r < BNpts; r += NBS) {
    __syncthreads();
    if (tid < 48) srow[tid] = drel[(size_t)r*48 + tid];
    __syncthreads();
    double v = bias;
#pragma unroll
    for (int j = 0; j < 48; ++j) v += (double)srow[j]*(double)Wl[j*256 + tid];
    double e = elu_d(v);
    s += e; s2 += e*e;
  }
  part[(size_t)blockIdx.x*512 + tid]       = s;
  part[(size_t)blockIdx.x*512 + 256 + tid] = s2;
}

// ---------------- stats over conv A output (recompute chain, f64) ----
__global__ __launch_bounds__(256) void stats2A_kernel(const float* __restrict__ drel,
                                                      const float* __restrict__ Wl,
                                                      const float* __restrict__ bl,
                                                      const double* __restrict__ bnl,
                                                      const float* __restrict__ WcA,
                                                      const float* __restrict__ bcA,
                                                      double* __restrict__ part) {
  __shared__ float srow[48];
  __shared__ double tl[256];
  int tid = threadIdx.x;
  int g = tid >> 4, o = tid & 15;
  double bias = (double)bl[tid];
  double scl = bnl[tid], shl = bnl[256 + tid];
  double s = 0.0, s2 = 0.0;
  for (int r = blockIdx.x; r < BNpts; r += NBS) {
    __syncthreads();
    if (tid < 48) srow[tid] = drel[(size_t)r*48 + tid];
    __syncthreads();
    double v = bias;
#pragma unroll
    for (int j = 0; j < 48; ++j) v += (double)srow[j]*(double)Wl[j*256 + tid];
    tl[tid] = elu_d(v)*scl + shl;
    __syncthreads();
    double u = (double)bcA[tid];
#pragma unroll
    for (int k = 0; k < 16; ++k) u += tl[g*16 + k]*(double)WcA[g*256 + o*16 + k];
    double e = elu_d(u);
    s += e; s2 += e*e;
  }
  part[(size_t)blockIdx.x*512 + tid]       = s;
  part[(size_t)blockIdx.x*512 + 256 + tid] = s2;
}

// ---------------- stats over conv B output (recompute chain, f64) ----
__global__ __launch_bounds__(256) void stats2B_kernel(const float* __restrict__ drel,
                                                      const float* __restrict__ Wl,
                                                      const float* __restrict__ bl,
                                                      const double* __restrict__ bnl,
                                                      const float* __restrict__ WcA,
                                                      const float* __restrict__ bcA,
                                                      const double* __restrict__ bnA,
                                                      const float* __restrict__ WcB,
                                                      const float* __restrict__ bcB,
                                                      double* __restrict__ part) {
  __shared__ float srow[48];
  __shared__ double tl[256];
  __shared__ double y2[256];
  int tid = threadIdx.x;
  int g = tid >> 4, o = tid & 15;
  double bias = (double)bl[tid];
  double scl = bnl[tid], shl = bnl[256 + tid];
  double scA = bnA[tid], shA = bnA[256 + tid];
  double s = 0.0, s2 = 0.0;
  for (int r = blockIdx.x; r < BNpts; r += NBS) {
    __syncthreads();
    if (tid < 48) srow[tid] = drel[(size_t)r*48 + tid];
    __syncthreads();
    double v = bias;
#pragma unroll
    for (int j = 0; j < 48; ++j) v += (double)srow[j]*(double)Wl[j*256 + tid];
    tl[tid] = elu_d(v)*scl + shl;
    __syncthreads();
    double u = (double)bcA[tid];
#pragma unroll
    for (int k = 0; k < 16; ++k) u += tl[g*16 + k]*(double)WcA[g*256 + o*16 + k];
    y2[tid] = elu_d(u)*scA + shA;
    __syncthreads();
    double w = (double)bcB[tid];
#pragma unroll
    for (int k = 0; k < 16; ++k) w += y2[g*16 + k]*(double)WcB[g*256 + o*16 + k];
    s += w; s2 += w*w;
  }
  part[(size_t)blockIdx.x*512 + tid]       = s;
  part[(size_t)blockIdx.x*512 + 256 + tid] = s2;
}

// ---------------- final: full f64 recompute per point ----
__global__ __launch_bounds__(256) void final_kernel(
    const float* __restrict__ x, const int* __restrict__ idxbuf, const float* __restrict__ drel,
    const float* __restrict__ W1, const float* __restrict__ b1, const double* __restrict__ bn1,
    const float* __restrict__ W2, const float* __restrict__ b2, const double* __restrict__ bn2,
    const float* __restrict__ Wl, const float* __restrict__ bl, const double* __restrict__ bnl,
    const float* __restrict__ WcA, const float* __restrict__ bcA, const double* __restrict__ bnA,
    const float* __restrict__ WcB, const float* __restrict__ bcB, const double* __restrict__ bnB,
    const float* __restrict__ Wd, const float* __restrict__ bd,
    const float* __restrict__ Wo, const float* __restrict__ bo,
    float* __restrict__ out) {
  int bn = blockIdx.x;
  int b = bn >> 11;
  int tid = threadIdx.x;
  __shared__ float  srow[48];
  __shared__ int    sidx[16];
  __shared__ float  sW1[48], sb1v[16], sW2[256], sb2v[16];
  __shared__ double tl[256];
  __shared__ double t2[256];
  __shared__ float  tmat[256];
  __shared__ double hs[16][16];
  __shared__ float  xs[80][16];
  __shared__ float  xtl[80][16];
  __shared__ double ov[160];
  if (tid < 16)  sidx[tid] = idxbuf[bn*16 + tid];
  if (tid < 48)  srow[tid] = drel[(size_t)bn*48 + tid];
  if (tid < 48)  sW1[tid] = W1[tid];
  if (tid >= 64 && tid < 80)   sb1v[tid-64]  = b1[tid-64];
  if (tid >= 128 && tid < 144) sb2v[tid-128] = b2[tid-128];
  sW2[tid] = W2[tid];
  __syncthreads();
  // t chain: linear
  {
    double v = (double)bl[tid];
#pragma unroll
    for (int j = 0; j < 48; ++j) v += (double)srow[j]*(double)Wl[j*256 + tid];
    tl[tid] = elu_d(v)*bnl[tid] + bnl[256 + tid];
  }
  __syncthreads();
  // conv A
  {
    int g = tid >> 4, o = tid & 15;
    double v = (double)bcA[tid];
#pragma unroll
    for (int k = 0; k < 16; ++k) v += tl[g*16 + k]*(double)WcA[g*256 + o*16 + k];
    t2[tid] = elu_d(v)*bnA[tid] + bnA[256 + tid];
  }
  __syncthreads();
  // conv B -> tmat[k][o]
  {
    int g = tid >> 4, o = tid & 15;
    double v = (double)bcB[tid];
#pragma unroll
    for (int k = 0; k < 16; ++k) v += t2[g*16 + k]*(double)WcB[g*256 + o*16 + k];
    tmat[tid] = (float)(v*bnB[tid] + bnB[256 + tid]);
  }
  // h chain layer 1
  {
    int k = tid >> 4, c = tid & 15;
    double pre = (double)srow[k*3]*(double)sW1[c] + (double)srow[k*3+1]*(double)sW1[16+c]
               + (double)srow[k*3+2]*(double)sW1[32+c] + (double)sb1v[c];
    hs[k][c] = elu_d(pre)*bn1[c] + bn1[16 + c];
  }
  __syncthreads();
  // h chain layer 2 -> xs[0..15][k]
  {
    int k = tid >> 4, c = tid & 15;
    double v = (double)sb2v[c];
#pragma unroll
    for (int j = 0; j < 16; ++j) v += hs[k][j]*(double)sW2[j*16 + c];
    xs[c][k] = (float)(elu_d(v)*bn2[c] + bn2[16 + c]);
  }
  // x gather -> xs[16..79][k]
  for (int i = tid; i < 1024; i += 256) {
    int k = i & 15, c = i >> 4;
    xs[16 + c][k] = x[((size_t)b*NN + sidx[k])*64 + c];
  }
  __syncthreads();
  // xt = xs @ t
  for (int i = tid; i < 1280; i += 256) {
    int c = i >> 4, o = i & 15;
    double v = 0.0;
#pragma unroll
    for (int k = 0; k < 16; ++k) v += (double)xs[c][k]*(double)tmat[k*16 + o];
    xtl[c][o] = (float)v;
  }
  __syncthreads();
  // depthwise conv
  if (tid < 160) {
    int c = tid >> 1, m = tid & 1;
    double v = (double)bd[tid];
#pragma unroll
    for (int k = 0; k < 16; ++k) v += (double)xtl[c][k]*(double)Wd[c*32 + m*16 + k];
    ov[tid] = v;
  }
  __syncthreads();
  // final linear
  if (tid < 128) {
    double v = (double)bo[tid];
    for (int i = 0; i < 160; ++i) v += ov[i]*(double)Wo[i*128 + tid];
    out[(size_t)bn*128 + tid] = (float)v;
  }
}

extern "C" void kernel_launch(void* const* d_in, const int* in_sizes, int n_in,
                              void* d_out, int out_size, void* d_ws, size_t ws_size,
                              hipStream_t stream) {
  (void)in_sizes; (void)n_in; (void)out_size; (void)ws_size;
  const float* x   = (const float*)d_in[0];
  const float* pos = (const float*)d_in[1];
  const float* W1  = (const float*)d_in[2];
  const float* b1  = (const float*)d_in[3];
  const float* g1  = (const float*)d_in[4];
  const float* be1 = (const float*)d_in[5];
  const float* W2  = (const float*)d_in[6];
  const float* b2  = (const float*)d_in[7];
  const float* g2  = (const float*)d_in[8];
  const float* be2 = (const float*)d_in[9];
  const float* Wl  = (const float*)d_in[10];
  const float* bl  = (const float*)d_in[11];
  const float* gl  = (const float*)d_in[12];
  const float* bel = (const float*)d_in[13];
  const float* WcA = (const float*)d_in[14];
  const float* bcA = (const float*)d_in[15];
  const float* gA  = (const float*)d_in[16];
  const float* beA = (const float*)d_in[17];
  const float* WcB = (const float*)d_in[18];
  const float* bcB = (const float*)d_in[19];
  const float* gB  = (const float*)d_in[20];
  const float* beB = (const float*)d_in[21];
  const float* Wd  = (const float*)d_in[22];
  const float* bd  = (const float*)d_in[23];
  const float* Wo  = (const float*)d_in[24];
  const float* bo  = (const float*)d_in[25];
  float* out = (float*)d_out;

  char* ws = (char*)d_ws;
  int*    idxbuf = (int*)ws;                              // 1 MB
  float*  drel   = (float*)(ws + (1 << 20));              // 3 MB
  double* part   = (double*)(ws + (4 << 20));             // 1 MB
  double* bnp    = (double*)(ws + (5 << 20) + (1 << 16)); // ~13 KB
  // bnp layout (doubles): bn1 @0 (32), bn2 @32 (32), bnl @64 (512), bnA @576 (512), bnB @1088 (512)

  knn_kernel<<<dim3(BNpts), dim3(256), 0, stream>>>(pos, idxbuf, drel);

  stats1a_kernel<<<dim3(NBS), dim3(256), 0, stream>>>(drel, W1, b1, part);
  bnreduce_kernel<<<dim3(1), dim3(256), 0, stream>>>(part, NBS, 16, (double)BNKr, g1, be1, bnp + 0);

  stats1b_kernel<<<dim3(NBS), dim3(256), 0, stream>>>(drel, W1, b1, bnp + 0, W2, b2, part);
  bnreduce_kernel<<<dim3(1), dim3(256), 0, stream>>>(part, NBS, 16, (double)BNKr, g2, be2, bnp + 32);

  stats2l_kernel<<<dim3(NBS), dim3(256), 0, stream>>>(drel, Wl, bl, part);
  bnreduce_kernel<<<dim3(1), dim3(256), 0, stream>>>(part, NBS, 256, (double)BNpts, gl, bel, bnp + 64);

  stats2A_kernel<<<dim3(NBS), dim3(256), 0, stream>>>(drel, Wl, bl, bnp + 64, WcA, bcA, part);
  bnreduce_kernel<<<dim3(1), dim3(256), 0, stream>>>(part, NBS, 256, (double)BNpts, gA, beA, bnp + 576);

  stats2B_kernel<<<dim3(NBS), dim3(256), 0, stream>>>(drel, Wl, bl, bnp + 64, WcA, bcA, bnp + 576,
                                                      WcB, bcB, part);
  bnreduce_kernel<<<dim3(1), dim3(256), 0, stream>>>(part, NBS, 256, (double)BNpts, gB, beB, bnp + 1088);

  final_kernel<<<dim3(BNpts), dim3(256), 0, stream>>>(x, idxbuf, drel,
                                                      W1, b1, bnp + 0,
                                                      W2, b2, bnp + 32,
                                                      Wl, bl, bnp + 64,
                                                      WcA, bcA, bnp + 576,
                                                      WcB, bcB, bnp + 1088,
                                                      Wd, bd,
                                                      Wo, bo,
                                                      out);
}

// Round 5
// 812.386 us; speedup vs baseline: 1.5286x; 1.5286x over previous
//
#include <hip/hip_runtime.h>
#include <math.h>

#define NN 2048
#define KNbr 16
#define BNpts 16384
#define BNKr  262144

__device__ __forceinline__ double elu_d(double v) { return v > 0.0 ? v : expm1(v); }

// ---------------- KNN: VERBATIM round-2 kernel (the version that PASSED). ---
// f32 distances emulating XLA rounding; LDS d2s; stable top-16 extraction.
// DO NOT TOUCH: rounds 3/4 failed with a "semantically identical" register
// rewrite of the selection; this exact code is the validated baseline.
__global__ __launch_bounds__(256) void knn_kernel(const float* __restrict__ pos,
                                                  int* __restrict__ idxout,
                                                  float* __restrict__ drel) {
  int bn = blockIdx.x;
  int b = bn >> 11, n = bn & (NN - 1);
  const float* pb = pos + (size_t)b * NN * 3;
  __shared__ float d2s[NN];
  __shared__ float wv[4];
  __shared__ int   wi[4];
  float qx = pb[n*3], qy = pb[n*3+1], qz = pb[n*3+2];
  float sqn = __fadd_rn(__fadd_rn(__fmul_rn(qx,qx), __fmul_rn(qy,qy)), __fmul_rn(qz,qz));
  for (int m = threadIdx.x; m < NN; m += 256) {
    float px = pb[m*3], py = pb[m*3+1], pz = pb[m*3+2];
    float sqm = __fadd_rn(__fadd_rn(__fmul_rn(px,px), __fmul_rn(py,py)), __fmul_rn(pz,pz));
    float dot = __fmaf_rn(qz, pz, __fmaf_rn(qy, py, __fmul_rn(qx, px)));
    d2s[m] = __fsub_rn(__fadd_rn(sqn, sqm), __fmul_rn(2.0f, dot));
  }
  __syncthreads();
  int lane = threadIdx.x & 63, wav = threadIdx.x >> 6;
  for (int k = 0; k < KNbr; ++k) {
    float bv = INFINITY; int bi = 1 << 30;
    for (int m = threadIdx.x; m < NN; m += 256) {
      float v = d2s[m];
      if (v < bv || (v == bv && m < bi)) { bv = v; bi = m; }
    }
    for (int s = 32; s > 0; s >>= 1) {
      float ov = __shfl_down(bv, s);
      int   oi = __shfl_down(bi, s);
      if (ov < bv || (ov == bv && oi < bi)) { bv = ov; bi = oi; }
    }
    if (lane == 0) { wv[wav] = bv; wi[wav] = bi; }
    __syncthreads();
    if (threadIdx.x == 0) {
      float fv = wv[0]; int fi = wi[0];
      for (int w = 1; w < 4; ++w)
        if (wv[w] < fv || (wv[w] == fv && wi[w] < fi)) { fv = wv[w]; fi = wi[w]; }
      idxout[bn*KNbr + k] = fi;
      d2s[fi] = INFINITY;
      drel[(size_t)(bn*KNbr + k)*3 + 0] = __fsub_rn(qx, pb[fi*3+0]);
      drel[(size_t)(bn*KNbr + k)*3 + 1] = __fsub_rn(qy, pb[fi*3+1]);
      drel[(size_t)(bn*KNbr + k)*3 + 2] = __fsub_rn(qz, pb[fi*3+2]);
    }
    __syncthreads();
  }
}

// ---------------- mlp1 layer-1 stats (f64 compute & accum) ------------------
__global__ __launch_bounds__(256) void s1a_kernel(const float* __restrict__ drel,
                                                  const float* __restrict__ W1,
                                                  const float* __restrict__ b1,
                                                  double* __restrict__ part1) {
  __shared__ float sW[64];
  int tid = threadIdx.x;
  if (tid < 48) sW[tid] = W1[tid];
  if (tid < 16) sW[48+tid] = b1[tid];
  __syncthreads();
  const float4* src4 = (const float4*)(drel + ((size_t)blockIdx.x*1024 + tid*4)*3);
  float a[12];
#pragma unroll
  for (int q = 0; q < 3; ++q) { float4 t = src4[q]; a[q*4]=t.x; a[q*4+1]=t.y; a[q*4+2]=t.z; a[q*4+3]=t.w; }
  double s[16], s2[16];
#pragma unroll
  for (int c = 0; c < 16; ++c) { s[c] = 0.0; s2[c] = 0.0; }
#pragma unroll
  for (int i = 0; i < 4; ++i) {
    double a0 = a[i*3], a1 = a[i*3+1], a2 = a[i*3+2];
#pragma unroll
    for (int c = 0; c < 16; ++c) {
      double v = a0*(double)sW[c] + a1*(double)sW[16+c] + a2*(double)sW[32+c] + (double)sW[48+c];
      double e = elu_d(v);
      s[c] += e; s2[c] += e*e;
    }
  }
  __shared__ double wred[4][32];
  int lane = tid & 63, wav = tid >> 6;
#pragma unroll
  for (int j = 0; j < 32; ++j) {
    double v = (j < 16) ? s[j] : s2[j-16];
    for (int sh = 32; sh > 0; sh >>= 1) v += __shfl_down(v, sh);
    if (lane == 0) wred[wav][j] = v;
  }
  __syncthreads();
  if (tid < 32)
    part1[(size_t)blockIdx.x*32 + tid] =
      wred[0][tid] + wred[1][tid] + wred[2][tid] + wred[3][tid];
}

// ---------------- mlp1 layer-2 stats (folds bn1 reduce; f64) ----------------
__global__ __launch_bounds__(256) void s1b_kernel(const float* __restrict__ drel,
                                                  const float* __restrict__ W1,
                                                  const float* __restrict__ b1,
                                                  const float* __restrict__ W2,
                                                  const float* __restrict__ b2,
                                                  const double* __restrict__ part1,
                                                  const float* __restrict__ g1,
                                                  const float* __restrict__ be1,
                                                  double* __restrict__ part2) {
  int tid = threadIdx.x;
  __shared__ double red[8][32];
  __shared__ double dsc1[16], dsh1[16];
  __shared__ float  sW[64];
  __shared__ double sW2t[256];
  {
    int j = tid & 31, grp = tid >> 5;
    double v = 0.0;
    for (int bk = grp; bk < 256; bk += 8) v += part1[(size_t)bk*32 + j];
    red[grp][j] = v;
  }
  if (tid < 48) sW[tid] = W1[tid];
  if (tid < 16) sW[48+tid] = b1[tid];
  sW2t[tid] = (double)W2[(tid & 15)*16 + (tid >> 4)];   // sW2t[c2*16+j] = W2[j][c2]
  __syncthreads();
  if (tid < 32) {
    double v = 0.0;
    for (int g = 0; g < 8; ++g) v += red[g][tid];
    red[0][tid] = v;
  }
  __syncthreads();
  if (tid < 16) {
    double S = red[0][tid], S2 = red[0][16 + tid];
    double m = S/262144.0, var = S2/262144.0 - m*m;
    double sc = (double)g1[tid]/sqrt(var + 1e-5);
    dsc1[tid] = sc;
    dsh1[tid] = (double)be1[tid] - m*sc;
  }
  __syncthreads();
  const float4* src4 = (const float4*)(drel + ((size_t)blockIdx.x*1024 + tid*4)*3);
  float a[12];
#pragma unroll
  for (int q = 0; q < 3; ++q) { float4 t = src4[q]; a[q*4]=t.x; a[q*4+1]=t.y; a[q*4+2]=t.z; a[q*4+3]=t.w; }
  double s[16], s2[16];
#pragma unroll
  for (int c = 0; c < 16; ++c) { s[c] = 0.0; s2[c] = 0.0; }
#pragma unroll
  for (int i = 0; i < 4; ++i) {
    double a0 = a[i*3], a1 = a[i*3+1], a2 = a[i*3+2];
    double y[16];
#pragma unroll
    for (int c = 0; c < 16; ++c) {
      double v = a0*(double)sW[c] + a1*(double)sW[16+c] + a2*(double)sW[32+c] + (double)sW[48+c];
      y[c] = elu_d(v)*dsc1[c] + dsh1[c];
    }
#pragma unroll
    for (int c2 = 0; c2 < 16; ++c2) {
      double v = (double)b2[c2];
#pragma unroll
      for (int j = 0; j < 16; ++j) v += y[j]*sW2t[c2*16 + j];
      double e = elu_d(v);
      s[c2] += e; s2[c2] += e*e;
    }
  }
  __shared__ double wred[4][32];
  int lane = tid & 63, wav = tid >> 6;
#pragma unroll
  for (int j = 0; j < 32; ++j) {
    double v = (j < 16) ? s[j] : s2[j-16];
    for (int sh = 32; sh > 0; sh >>= 1) v += __shfl_down(v, sh);
    if (lane == 0) wred[wav][j] = v;
  }
  __syncthreads();
  if (tid < 32)
    part2[(size_t)blockIdx.x*32 + tid] =
      wred[0][tid] + wred[1][tid] + wred[2][tid] + wred[3][tid];
}

// ---------------- mlp2 linear: f64 compute, f32 store, f64 stats ------------
__global__ __launch_bounds__(256) void s2l_kernel(const float* __restrict__ drel,
                                                  const float* __restrict__ Wl,
                                                  const float* __restrict__ bl,
                                                  float* __restrict__ tL,
                                                  double* __restrict__ partL) {
  __shared__ float srows[128*48];
  int tid = threadIdx.x;
  const float* src = drel + (size_t)blockIdx.x * 6144;
  for (int i = tid; i < 6144; i += 256) srows[i] = src[i];
  float w[48];
#pragma unroll
  for (int j = 0; j < 48; ++j) w[j] = Wl[j*256 + tid];
  double bias = (double)bl[tid];
  __syncthreads();
  double s = 0.0, s2 = 0.0;
  for (int r = 0; r < 128; ++r) {
    double v = bias;
    const float* sr = &srows[r*48];
#pragma unroll
    for (int j = 0; j < 48; ++j) v += (double)sr[j]*(double)w[j];
    float ef = (float)elu_d(v);
    tL[(size_t)(blockIdx.x*128 + r)*256 + tid] = ef;
    double ed = (double)ef;
    s += ed; s2 += ed*ed;
  }
  partL[(size_t)blockIdx.x*512 + tid]       = s;
  partL[(size_t)blockIdx.x*512 + 256 + tid] = s2;
}

// ---------------- grouped conv (A: elu, B: none); folds prev BN reduce ------
template<int DO_ELU>
__global__ __launch_bounds__(256) void s2conv_kernel(const double* __restrict__ partIn,
                                                     const float* __restrict__ gIn,
                                                     const float* __restrict__ beIn,
                                                     const float* __restrict__ Wc,
                                                     const float* __restrict__ bc,
                                                     const float* __restrict__ tIn,
                                                     float* __restrict__ tOut,
                                                     double* __restrict__ partOut) {
  int tid = threadIdx.x;
  double S = 0.0, S2 = 0.0;
  for (int bk = 0; bk < 128; ++bk) {
    S  += partIn[(size_t)bk*512 + tid];
    S2 += partIn[(size_t)bk*512 + 256 + tid];
  }
  double m = S/16384.0, var = S2/16384.0 - m*m;
  double sc = (double)gIn[tid]/sqrt(var + 1e-5);
  double sh = (double)beIn[tid] - m*sc;
  int g = tid >> 4, o = tid & 15;
  float w[16];
#pragma unroll
  for (int k = 0; k < 16; ++k) w[k] = Wc[g*256 + o*16 + k];
  double bias = (double)bc[tid];
  __shared__ float sin_[16*256];
  double s = 0.0, s2 = 0.0;
  const float* base = tIn + (size_t)blockIdx.x*128*256;
  float* outb = tOut + (size_t)blockIdx.x*128*256;
  for (int chunk = 0; chunk < 8; ++chunk) {
    __syncthreads();
    for (int rr = 0; rr < 16; ++rr)
      sin_[rr*256 + tid] = (float)((double)base[(chunk*16 + rr)*256 + tid]*sc + sh);
    __syncthreads();
    for (int rr = 0; rr < 16; ++rr) {
      double v = bias;
      const float* row = &sin_[rr*256 + g*16];
#pragma unroll
      for (int k = 0; k < 16; ++k) v += (double)row[k]*(double)w[k];
      float ef = DO_ELU ? (float)elu_d(v) : (float)v;
      outb[(chunk*16 + rr)*256 + tid] = ef;
      double ed = (double)ef;
      s += ed; s2 += ed*ed;
    }
  }
  partOut[(size_t)blockIdx.x*512 + tid]       = s;
  partOut[(size_t)blockIdx.x*512 + 256 + tid] = s2;
}

// ---------------- bn1/bn2/bnB -> f64 scale/shift ----------------------------
__global__ void bnall_kernel(const double* __restrict__ part1,
                             const double* __restrict__ part2,
                             const double* __restrict__ partB,
                             const float* __restrict__ g1, const float* __restrict__ be1,
                             const float* __restrict__ g2, const float* __restrict__ be2,
                             const float* __restrict__ gB, const float* __restrict__ beB,
                             double* __restrict__ bnp) {
  int tid = threadIdx.x;
  if (tid < 32) {
    int c = tid & 15;
    const double* P = (tid < 16) ? part1 : part2;
    double S = 0.0, S2 = 0.0;
    for (int bk = 0; bk < 256; ++bk) { S += P[(size_t)bk*32 + c]; S2 += P[(size_t)bk*32 + 16 + c]; }
    double m = S/262144.0, var = S2/262144.0 - m*m;
    const float* g  = (tid < 16) ? g1 : g2;
    const float* be = (tid < 16) ? be1 : be2;
    double sc = (double)g[c]/sqrt(var + 1e-5);
    int off = (tid < 16) ? 0 : 32;
    bnp[off + c]      = sc;
    bnp[off + 16 + c] = (double)be[c] - m*sc;
  }
  {
    double S = 0.0, S2 = 0.0;
    for (int bk = 0; bk < 128; ++bk) { S += partB[(size_t)bk*512 + tid]; S2 += partB[(size_t)bk*512 + 256 + tid]; }
    double m = S/16384.0, var = S2/16384.0 - m*m;
    double sc = (double)gB[tid]/sqrt(var + 1e-5);
    bnp[64 + tid]  = sc;
    bnp[320 + tid] = (double)beB[tid] - m*sc;
  }
}

// ---------------- final: 4 points/block, f64 compute, f32 staging -----------
__global__ __launch_bounds__(256) void final_kernel(const float* __restrict__ x,
                                                    const int* __restrict__ idxbuf,
                                                    const float* __restrict__ drel,
                                                    const float* __restrict__ tB,
                                                    const double* __restrict__ bnp,
                                                    const float* __restrict__ W1,
                                                    const float* __restrict__ b1,
                                                    const float* __restrict__ W2,
                                                    const float* __restrict__ b2,
                                                    const float* __restrict__ Wd,
                                                    const float* __restrict__ bd,
                                                    const float* __restrict__ Wo,
                                                    const float* __restrict__ bo,
                                                    float* __restrict__ out) {
  int tid = threadIdx.x;
  int bn0 = blockIdx.x*4;
  int b = bn0 >> 11;
  __shared__ double sbn1[32], sbn2[32];
  __shared__ double sBs[256], sBh[256];
  __shared__ int    sidx[64];
  __shared__ float  sdrel[192];
  __shared__ float  sW1[48], sb1[16], sb2[16];
  __shared__ double sW2t[256];
  __shared__ float  tmat[1024];
  __shared__ double hs[4][16][16];
  __shared__ float  xs[4][80][16];
  __shared__ float  xt[4][80][16];
  __shared__ double ovs[4][160];
  if (tid < 32) { sbn1[tid] = bnp[tid]; sbn2[tid] = bnp[32 + tid]; }
  sBs[tid] = bnp[64 + tid];
  sBh[tid] = bnp[320 + tid];
  if (tid < 64)  sidx[tid]  = idxbuf[bn0*16 + tid];
  if (tid < 192) sdrel[tid] = drel[(size_t)bn0*48 + tid];
  if (tid < 48)  sW1[tid] = W1[tid];
  if (tid < 16) { sb1[tid] = b1[tid]; sb2[tid] = b2[tid]; }
  sW2t[tid] = (double)W2[(tid & 15)*16 + (tid >> 4)];
  __syncthreads();
  for (int i = tid; i < 1024; i += 256) {
    int c = i & 255;
    tmat[i] = (float)((double)tB[(size_t)bn0*256 + i]*sBs[c] + sBh[c]);
  }
  for (int i = tid; i < 1024; i += 256) {
    int pt = i >> 8, k = (i >> 4) & 15, c = i & 15;
    double a0 = sdrel[pt*48 + k*3], a1 = sdrel[pt*48 + k*3 + 1], a2 = sdrel[pt*48 + k*3 + 2];
    double v = a0*(double)sW1[c] + a1*(double)sW1[16+c] + a2*(double)sW1[32+c] + (double)sb1[c];
    hs[pt][k][c] = elu_d(v)*sbn1[c] + sbn1[16+c];
  }
  __syncthreads();
  for (int i = tid; i < 1024; i += 256) {
    int pt = i >> 8, k = (i >> 4) & 15, c2 = i & 15;
    double v = (double)sb2[c2];
#pragma unroll
    for (int j = 0; j < 16; ++j) v += hs[pt][k][j]*sW2t[c2*16 + j];
    xs[pt][c2][k] = (float)(elu_d(v)*sbn2[c2] + sbn2[16+c2]);
  }
  for (int i = tid; i < 4096; i += 256) {
    int pt = i >> 10, k = (i >> 6) & 15, c = i & 63;
    xs[pt][16 + c][k] = x[((size_t)b*NN + sidx[pt*16 + k])*64 + c];
  }
  __syncthreads();
  for (int pt = 0; pt < 4; ++pt)
    for (int i = tid; i < 1280; i += 256) {
      int c = i >> 4, o = i & 15;
      double v = 0.0;
#pragma unroll
      for (int k = 0; k < 16; ++k) v += (double)xs[pt][c][k]*(double)tmat[pt*256 + k*16 + o];
      xt[pt][c][o] = (float)v;
    }
  __syncthreads();
  for (int pt = 0; pt < 4; ++pt)
    for (int i = tid; i < 160; i += 256) {
      int c = i >> 1, mm = i & 1;
      double v = (double)bd[i];
#pragma unroll
      for (int k = 0; k < 16; ++k) v += (double)xt[pt][c][k]*(double)Wd[c*32 + mm*16 + k];
      ovs[pt][i] = v;
    }
  __syncthreads();
  {
    int pt0 = tid >> 7, co = tid & 127;
    double v0 = (double)bo[co], v1 = v0;
    for (int i = 0; i < 160; ++i) {
      double wv = (double)Wo[i*128 + co];
      v0 += ovs[pt0][i]*wv;
      v1 += ovs[pt0 + 2][i]*wv;
    }
    out[(size_t)(bn0 + pt0)*128 + co]     = (float)v0;
    out[(size_t)(bn0 + pt0 + 2)*128 + co] = (float)v1;
  }
}

extern "C" void kernel_launch(void* const* d_in, const int* in_sizes, int n_in,
                              void* d_out, int out_size, void* d_ws, size_t ws_size,
                              hipStream_t stream) {
  (void)in_sizes; (void)n_in; (void)out_size; (void)ws_size;
  const float* x   = (const float*)d_in[0];
  const float* pos = (const float*)d_in[1];
  const float* W1  = (const float*)d_in[2];
  const float* b1  = (const float*)d_in[3];
  const float* g1  = (const float*)d_in[4];
  const float* be1 = (const float*)d_in[5];
  const float* W2  = (const float*)d_in[6];
  const float* b2  = (const float*)d_in[7];
  const float* g2  = (const float*)d_in[8];
  const float* be2 = (const float*)d_in[9];
  const float* Wl  = (const float*)d_in[10];
  const float* bl  = (const float*)d_in[11];
  const float* gl  = (const float*)d_in[12];
  const float* bel = (const float*)d_in[13];
  const float* WcA = (const float*)d_in[14];
  const float* bcA = (const float*)d_in[15];
  const float* gA  = (const float*)d_in[16];
  const float* beA = (const float*)d_in[17];
  const float* WcB = (const float*)d_in[18];
  const float* bcB = (const float*)d_in[19];
  const float* gB  = (const float*)d_in[20];
  const float* beB = (const float*)d_in[21];
  const float* Wd  = (const float*)d_in[22];
  const float* bd  = (const float*)d_in[23];
  const float* Wo  = (const float*)d_in[24];
  const float* bo  = (const float*)d_in[25];
  float* out = (float*)d_out;

  char* ws = (char*)d_ws;
  int*    idxbuf = (int*)ws;                                   // 1 MB
  float*  drel   = (float*)(ws + (1u<<20));                    // 3 MB
  float*  bufX   = (float*)(ws + (4u<<20));                    // 16 MB
  float*  bufY   = (float*)(ws + (20u<<20));                   // 16 MB
  double* part1  = (double*)(ws + (36u<<20));                  // 64 KB
  double* part2  = (double*)(ws + (36u<<20) + (64u<<10));      // 64 KB
  double* partL  = (double*)(ws + (36u<<20) + (128u<<10));     // 512 KB
  double* partA  = (double*)(ws + (36u<<20) + (640u<<10));     // 512 KB
  double* partB  = (double*)(ws + (36u<<20) + (1152u<<10));    // 512 KB
  double* bnp    = (double*)(ws + (36u<<20) + (1664u<<10));    // 4.5 KB

  knn_kernel<<<dim3(BNpts), dim3(256), 0, stream>>>(pos, idxbuf, drel);
  s1a_kernel<<<dim3(256), dim3(256), 0, stream>>>(drel, W1, b1, part1);
  s1b_kernel<<<dim3(256), dim3(256), 0, stream>>>(drel, W1, b1, W2, b2, part1, g1, be1, part2);
  s2l_kernel<<<dim3(128), dim3(256), 0, stream>>>(drel, Wl, bl, bufX, partL);
  s2conv_kernel<1><<<dim3(128), dim3(256), 0, stream>>>(partL, gl, bel, WcA, bcA, bufX, bufY, partA);
  s2conv_kernel<0><<<dim3(128), dim3(256), 0, stream>>>(partA, gA, beA, WcB, bcB, bufY, bufX, partB);
  bnall_kernel<<<dim3(1), dim3(256), 0, stream>>>(part1, part2, partB, g1, be1, g2, be2, gB, beB, bnp);
  final_kernel<<<dim3(4096), dim3(256), 0, stream>>>(x, idxbuf, drel, bufX, bnp,
                                                     W1, b1, W2, b2, Wd, bd, Wo, bo, out);
}

// Round 6
// 623.270 us; speedup vs baseline: 1.9924x; 1.3034x over previous
//
#include <hip/hip_runtime.h>
#include <math.h>

#define NN 2048
#define KNbr 16
#define BNpts 16384
#define BNKr  262144

__device__ __forceinline__ float eluf(float v) { return v > 0.f ? v : expm1f(v); }

// ---------------- KNN: VERBATIM round-2 kernel (the version that PASSED). ---
// f32 distances emulating XLA rounding; LDS d2s; stable top-16 extraction.
// DO NOT TOUCH: rounds 3/4 failed with a "semantically identical" register
// rewrite of the selection; this exact code is the validated baseline.
__global__ __launch_bounds__(256) void knn_kernel(const float* __restrict__ pos,
                                                  int* __restrict__ idxout,
                                                  float* __restrict__ drel) {
  int bn = blockIdx.x;
  int b = bn >> 11, n = bn & (NN - 1);
  const float* pb = pos + (size_t)b * NN * 3;
  __shared__ float d2s[NN];
  __shared__ float wv[4];
  __shared__ int   wi[4];
  float qx = pb[n*3], qy = pb[n*3+1], qz = pb[n*3+2];
  float sqn = __fadd_rn(__fadd_rn(__fmul_rn(qx,qx), __fmul_rn(qy,qy)), __fmul_rn(qz,qz));
  for (int m = threadIdx.x; m < NN; m += 256) {
    float px = pb[m*3], py = pb[m*3+1], pz = pb[m*3+2];
    float sqm = __fadd_rn(__fadd_rn(__fmul_rn(px,px), __fmul_rn(py,py)), __fmul_rn(pz,pz));
    float dot = __fmaf_rn(qz, pz, __fmaf_rn(qy, py, __fmul_rn(qx, px)));
    d2s[m] = __fsub_rn(__fadd_rn(sqn, sqm), __fmul_rn(2.0f, dot));
  }
  __syncthreads();
  int lane = threadIdx.x & 63, wav = threadIdx.x >> 6;
  for (int k = 0; k < KNbr; ++k) {
    float bv = INFINITY; int bi = 1 << 30;
    for (int m = threadIdx.x; m < NN; m += 256) {
      float v = d2s[m];
      if (v < bv || (v == bv && m < bi)) { bv = v; bi = m; }
    }
    for (int s = 32; s > 0; s >>= 1) {
      float ov = __shfl_down(bv, s);
      int   oi = __shfl_down(bi, s);
      if (ov < bv || (ov == bv && oi < bi)) { bv = ov; bi = oi; }
    }
    if (lane == 0) { wv[wav] = bv; wi[wav] = bi; }
    __syncthreads();
    if (threadIdx.x == 0) {
      float fv = wv[0]; int fi = wi[0];
      for (int w = 1; w < 4; ++w)
        if (wv[w] < fv || (wv[w] == fv && wi[w] < fi)) { fv = wv[w]; fi = wi[w]; }
      idxout[bn*KNbr + k] = fi;
      d2s[fi] = INFINITY;
      drel[(size_t)(bn*KNbr + k)*3 + 0] = __fsub_rn(qx, pb[fi*3+0]);
      drel[(size_t)(bn*KNbr + k)*3 + 1] = __fsub_rn(qy, pb[fi*3+1]);
      drel[(size_t)(bn*KNbr + k)*3 + 2] = __fsub_rn(qz, pb[fi*3+2]);
    }
    __syncthreads();
  }
}

// ---------------- mlp1 layer-1 stats (f32 compute, f64 partial store) -------
__global__ __launch_bounds__(256) void s1a_kernel(const float* __restrict__ drel,
                                                  const float* __restrict__ W1,
                                                  const float* __restrict__ b1,
                                                  double* __restrict__ part1) {
  __shared__ float sW[64];
  int tid = threadIdx.x;
  if (tid < 48) sW[tid] = W1[tid];
  if (tid < 16) sW[48+tid] = b1[tid];
  __syncthreads();
  const float4* src4 = (const float4*)(drel + ((size_t)blockIdx.x*1024 + tid*4)*3);
  float a[12];
#pragma unroll
  for (int q = 0; q < 3; ++q) { float4 t = src4[q]; a[q*4]=t.x; a[q*4+1]=t.y; a[q*4+2]=t.z; a[q*4+3]=t.w; }
  float s[16], s2[16];
#pragma unroll
  for (int c = 0; c < 16; ++c) { s[c] = 0.f; s2[c] = 0.f; }
#pragma unroll
  for (int i = 0; i < 4; ++i) {
    float a0 = a[i*3], a1 = a[i*3+1], a2 = a[i*3+2];
#pragma unroll
    for (int c = 0; c < 16; ++c) {
      float v = a0*sW[c] + a1*sW[16+c] + a2*sW[32+c] + sW[48+c];
      float e = eluf(v);
      s[c] += e; s2[c] += e*e;
    }
  }
  __shared__ float wred[4][32];
  int lane = tid & 63, wav = tid >> 6;
#pragma unroll
  for (int j = 0; j < 32; ++j) {
    float v = (j < 16) ? s[j] : s2[j-16];
    for (int sh = 32; sh > 0; sh >>= 1) v += __shfl_down(v, sh);
    if (lane == 0) wred[wav][j] = v;
  }
  __syncthreads();
  if (tid < 32)
    part1[(size_t)blockIdx.x*32 + tid] =
      (double)wred[0][tid] + (double)wred[1][tid] + (double)wred[2][tid] + (double)wred[3][tid];
}

// ---------------- mlp1 layer-2 stats (folds bn1 reduce; f32 compute) --------
__global__ __launch_bounds__(256) void s1b_kernel(const float* __restrict__ drel,
                                                  const float* __restrict__ W1,
                                                  const float* __restrict__ b1,
                                                  const float* __restrict__ W2,
                                                  const float* __restrict__ b2,
                                                  const double* __restrict__ part1,
                                                  const float* __restrict__ g1,
                                                  const float* __restrict__ be1,
                                                  double* __restrict__ part2) {
  int tid = threadIdx.x;
  __shared__ double red[8][32];
  __shared__ float fsc1[16], fsh1[16];
  __shared__ float sW[64];
  __shared__ float sW2t[256];
  {
    int j = tid & 31, grp = tid >> 5;
    double v = 0.0;
    for (int bk = grp; bk < 256; bk += 8) v += part1[(size_t)bk*32 + j];
    red[grp][j] = v;
  }
  if (tid < 48) sW[tid] = W1[tid];
  if (tid < 16) sW[48+tid] = b1[tid];
  sW2t[tid] = W2[(tid & 15)*16 + (tid >> 4)];   // sW2t[c2*16+j] = W2[j][c2]
  __syncthreads();
  if (tid < 32) {
    double v = 0.0;
    for (int g = 0; g < 8; ++g) v += red[g][tid];
    red[0][tid] = v;
  }
  __syncthreads();
  if (tid < 16) {
    double S = red[0][tid], S2 = red[0][16 + tid];
    double m = S/262144.0, var = S2/262144.0 - m*m;
    double sc = (double)g1[tid]/sqrt(var + 1e-5);
    fsc1[tid] = (float)sc;
    fsh1[tid] = (float)((double)be1[tid] - m*sc);
  }
  __syncthreads();
  const float4* src4 = (const float4*)(drel + ((size_t)blockIdx.x*1024 + tid*4)*3);
  float a[12];
#pragma unroll
  for (int q = 0; q < 3; ++q) { float4 t = src4[q]; a[q*4]=t.x; a[q*4+1]=t.y; a[q*4+2]=t.z; a[q*4+3]=t.w; }
  float s[16], s2[16];
#pragma unroll
  for (int c = 0; c < 16; ++c) { s[c] = 0.f; s2[c] = 0.f; }
#pragma unroll
  for (int i = 0; i < 4; ++i) {
    float a0 = a[i*3], a1 = a[i*3+1], a2 = a[i*3+2];
    float y[16];
#pragma unroll
    for (int c = 0; c < 16; ++c) {
      float v = a0*sW[c] + a1*sW[16+c] + a2*sW[32+c] + sW[48+c];
      y[c] = eluf(v)*fsc1[c] + fsh1[c];
    }
#pragma unroll
    for (int c2 = 0; c2 < 16; ++c2) {
      float v = b2[c2];
      const float4* w4 = (const float4*)&sW2t[c2*16];
#pragma unroll
      for (int j4 = 0; j4 < 4; ++j4) {
        float4 ww = w4[j4];
        v += y[j4*4]*ww.x + y[j4*4+1]*ww.y + y[j4*4+2]*ww.z + y[j4*4+3]*ww.w;
      }
      float e = eluf(v);
      s[c2] += e; s2[c2] += e*e;
    }
  }
  __shared__ float wred[4][32];
  int lane = tid & 63, wav = tid >> 6;
#pragma unroll
  for (int j = 0; j < 32; ++j) {
    float v = (j < 16) ? s[j] : s2[j-16];
    for (int sh = 32; sh > 0; sh >>= 1) v += __shfl_down(v, sh);
    if (lane == 0) wred[wav][j] = v;
  }
  __syncthreads();
  if (tid < 32)
    part2[(size_t)blockIdx.x*32 + tid] =
      (double)wred[0][tid] + (double)wred[1][tid] + (double)wred[2][tid] + (double)wred[3][tid];
}

// ---------------- mlp2 linear: f32 compute, f32 store, f64 accum ------------
__global__ __launch_bounds__(256) void s2l_kernel(const float* __restrict__ drel,
                                                  const float* __restrict__ Wl,
                                                  const float* __restrict__ bl,
                                                  float* __restrict__ tL,
                                                  double* __restrict__ partL) {
  __shared__ float srows[128*48];
  int tid = threadIdx.x;
  const float* src = drel + (size_t)blockIdx.x * 6144;
  for (int i = tid; i < 6144; i += 256) srows[i] = src[i];
  float w[48];
#pragma unroll
  for (int j = 0; j < 48; ++j) w[j] = Wl[j*256 + tid];
  float bias = bl[tid];
  __syncthreads();
  double s = 0.0, s2 = 0.0;
  for (int r = 0; r < 128; ++r) {
    float v = bias;
    const float4* sr = (const float4*)&srows[r*48];
#pragma unroll
    for (int j4 = 0; j4 < 12; ++j4) {
      float4 a4 = sr[j4];
      v += a4.x*w[j4*4] + a4.y*w[j4*4+1] + a4.z*w[j4*4+2] + a4.w*w[j4*4+3];
    }
    float e = eluf(v);
    tL[(size_t)(blockIdx.x*128 + r)*256 + tid] = e;
    double ed = (double)e;
    s += ed; s2 += ed*ed;
  }
  partL[(size_t)blockIdx.x*512 + tid]       = s;
  partL[(size_t)blockIdx.x*512 + 256 + tid] = s2;
}

// ---------------- grouped conv (A: elu, B: none); folds prev BN reduce ------
template<int DO_ELU>
__global__ __launch_bounds__(256) void s2conv_kernel(const double* __restrict__ partIn,
                                                     const float* __restrict__ gIn,
                                                     const float* __restrict__ beIn,
                                                     const float* __restrict__ Wc,
                                                     const float* __restrict__ bc,
                                                     const float* __restrict__ tIn,
                                                     float* __restrict__ tOut,
                                                     double* __restrict__ partOut) {
  int tid = threadIdx.x;
  double S = 0.0, S2 = 0.0;
  for (int bk = 0; bk < 128; ++bk) {
    S  += partIn[(size_t)bk*512 + tid];
    S2 += partIn[(size_t)bk*512 + 256 + tid];
  }
  double m = S/16384.0, var = S2/16384.0 - m*m;
  double scd = (double)gIn[tid]/sqrt(var + 1e-5);
  float sc = (float)scd, sh = (float)((double)beIn[tid] - m*scd);
  int g = tid >> 4, o = tid & 15;
  float w[16];
#pragma unroll
  for (int k = 0; k < 16; ++k) w[k] = Wc[g*256 + o*16 + k];
  float bias = bc[tid];
  __shared__ float sin_[16*256];
  double s = 0.0, s2 = 0.0;
  const float* base = tIn + (size_t)blockIdx.x*128*256;
  float* outb = tOut + (size_t)blockIdx.x*128*256;
  for (int chunk = 0; chunk < 8; ++chunk) {
    __syncthreads();
    for (int rr = 0; rr < 16; ++rr)
      sin_[rr*256 + tid] = base[(chunk*16 + rr)*256 + tid]*sc + sh;
    __syncthreads();
    for (int rr = 0; rr < 16; ++rr) {
      float v = bias;
      const float4* row4 = (const float4*)&sin_[rr*256 + g*16];
#pragma unroll
      for (int k4 = 0; k4 < 4; ++k4) {
        float4 a4 = row4[k4];
        v += a4.x*w[k4*4] + a4.y*w[k4*4+1] + a4.z*w[k4*4+2] + a4.w*w[k4*4+3];
      }
      float e = DO_ELU ? eluf(v) : v;
      outb[(chunk*16 + rr)*256 + tid] = e;
      double ed = (double)e;
      s += ed; s2 += ed*ed;
    }
  }
  partOut[(size_t)blockIdx.x*512 + tid]       = s;
  partOut[(size_t)blockIdx.x*512 + 256 + tid] = s2;
}

// ---------------- bn1/bn2/bnB -> f32 scale/shift ----------------------------
__global__ void bnall_kernel(const double* __restrict__ part1,
                             const double* __restrict__ part2,
                             const double* __restrict__ partB,
                             const float* __restrict__ g1, const float* __restrict__ be1,
                             const float* __restrict__ g2, const float* __restrict__ be2,
                             const float* __restrict__ gB, const float* __restrict__ beB,
                             float* __restrict__ bnp) {
  int tid = threadIdx.x;
  if (tid < 32) {
    int c = tid & 15;
    const double* P = (tid < 16) ? part1 : part2;
    double S = 0.0, S2 = 0.0;
    for (int bk = 0; bk < 256; ++bk) { S += P[(size_t)bk*32 + c]; S2 += P[(size_t)bk*32 + 16 + c]; }
    double m = S/262144.0, var = S2/262144.0 - m*m;
    const float* g  = (tid < 16) ? g1 : g2;
    const float* be = (tid < 16) ? be1 : be2;
    double sc = (double)g[c]/sqrt(var + 1e-5);
    int off = (tid < 16) ? 0 : 32;
    bnp[off + c]      = (float)sc;
    bnp[off + 16 + c] = (float)((double)be[c] - m*sc);
  }
  {
    double S = 0.0, S2 = 0.0;
    for (int bk = 0; bk < 128; ++bk) { S += partB[(size_t)bk*512 + tid]; S2 += partB[(size_t)bk*512 + 256 + tid]; }
    double m = S/16384.0, var = S2/16384.0 - m*m;
    double sc = (double)gB[tid]/sqrt(var + 1e-5);
    bnp[64 + tid]  = (float)sc;
    bnp[320 + tid] = (float)((double)beB[tid] - m*sc);
  }
}

// ---------------- final: 4 points/block, f32 compute ------------------------
__global__ __launch_bounds__(256) void final_kernel(const float* __restrict__ x,
                                                    const int* __restrict__ idxbuf,
                                                    const float* __restrict__ drel,
                                                    const float* __restrict__ tB,
                                                    const float* __restrict__ bnp,
                                                    const float* __restrict__ W1,
                                                    const float* __restrict__ b1,
                                                    const float* __restrict__ W2,
                                                    const float* __restrict__ b2,
                                                    const float* __restrict__ Wd,
                                                    const float* __restrict__ bd,
                                                    const float* __restrict__ Wo,
                                                    const float* __restrict__ bo,
                                                    float* __restrict__ out) {
  int tid = threadIdx.x;
  int bn0 = blockIdx.x*4;
  int b = bn0 >> 11;
  __shared__ float sbn1[32], sbn2[32];
  __shared__ float sBs[256], sBh[256];
  __shared__ int   sidx[64];
  __shared__ float sdrel[192];
  __shared__ float sW1[48], sb1[16], sb2[16];
  __shared__ float sW2t[256];
  __shared__ float tmat[1024];
  __shared__ float hs[4][16][16];
  __shared__ float xs[4][80][16];
  __shared__ float xt[4][80][16];
  __shared__ float ovs[4][160];
  if (tid < 32) { sbn1[tid] = bnp[tid]; sbn2[tid] = bnp[32 + tid]; }
  sBs[tid] = bnp[64 + tid];
  sBh[tid] = bnp[320 + tid];
  if (tid < 64)  sidx[tid]  = idxbuf[bn0*16 + tid];
  if (tid < 192) sdrel[tid] = drel[(size_t)bn0*48 + tid];
  if (tid < 48)  sW1[tid] = W1[tid];
  if (tid < 16) { sb1[tid] = b1[tid]; sb2[tid] = b2[tid]; }
  sW2t[tid] = W2[(tid & 15)*16 + (tid >> 4)];
  __syncthreads();
  for (int i = tid; i < 1024; i += 256) {
    int c = i & 255;
    tmat[i] = tB[(size_t)bn0*256 + i]*sBs[c] + sBh[c];
  }
  for (int i = tid; i < 1024; i += 256) {
    int pt = i >> 8, k = (i >> 4) & 15, c = i & 15;
    float a0 = sdrel[pt*48 + k*3], a1 = sdrel[pt*48 + k*3 + 1], a2 = sdrel[pt*48 + k*3 + 2];
    float v = a0*sW1[c] + a1*sW1[16+c] + a2*sW1[32+c] + sb1[c];
    hs[pt][k][c] = eluf(v)*sbn1[c] + sbn1[16+c];
  }
  __syncthreads();
  for (int i = tid; i < 1024; i += 256) {
    int pt = i >> 8, k = (i >> 4) & 15, c2 = i & 15;
    float v = sb2[c2];
    const float4* w4 = (const float4*)&sW2t[c2*16];
    float* hrow = &hs[pt][k][0];
#pragma unroll
    for (int j4 = 0; j4 < 4; ++j4) {
      float4 ww = w4[j4];
      v += hrow[j4*4]*ww.x + hrow[j4*4+1]*ww.y + hrow[j4*4+2]*ww.z + hrow[j4*4+3]*ww.w;
    }
    xs[pt][c2][k] = eluf(v)*sbn2[c2] + sbn2[16+c2];
  }
  for (int i = tid; i < 4096; i += 256) {
    int pt = i >> 10, k = (i >> 6) & 15, c = i & 63;
    xs[pt][16 + c][k] = x[((size_t)b*NN + sidx[pt*16 + k])*64 + c];
  }
  __syncthreads();
  for (int pt = 0; pt < 4; ++pt)
    for (int i = tid; i < 1280; i += 256) {
      int c = i >> 4, o = i & 15;
      float v = 0.f;
#pragma unroll
      for (int k = 0; k < 16; ++k) v += xs[pt][c][k]*tmat[pt*256 + k*16 + o];
      xt[pt][c][o] = v;
    }
  __syncthreads();
  for (int pt = 0; pt < 4; ++pt)
    for (int i = tid; i < 160; i += 256) {
      int c = i >> 1, mm = i & 1;
      float v = bd[i];
#pragma unroll
      for (int k = 0; k < 16; ++k) v += xt[pt][c][k]*Wd[c*32 + mm*16 + k];
      ovs[pt][i] = v;
    }
  __syncthreads();
  {
    int pt0 = tid >> 7, co = tid & 127;
    float v0 = bo[co], v1 = v0;
    for (int i = 0; i < 160; ++i) {
      float wv = Wo[i*128 + co];
      v0 += ovs[pt0][i]*wv;
      v1 += ovs[pt0 + 2][i]*wv;
    }
    out[(size_t)(bn0 + pt0)*128 + co]     = v0;
    out[(size_t)(bn0 + pt0 + 2)*128 + co] = v1;
  }
}

extern "C" void kernel_launch(void* const* d_in, const int* in_sizes, int n_in,
                              void* d_out, int out_size, void* d_ws, size_t ws_size,
                              hipStream_t stream) {
  (void)in_sizes; (void)n_in; (void)out_size; (void)ws_size;
  const float* x   = (const float*)d_in[0];
  const float* pos = (const float*)d_in[1];
  const float* W1  = (const float*)d_in[2];
  const float* b1  = (const float*)d_in[3];
  const float* g1  = (const float*)d_in[4];
  const float* be1 = (const float*)d_in[5];
  const float* W2  = (const float*)d_in[6];
  const float* b2  = (const float*)d_in[7];
  const float* g2  = (const float*)d_in[8];
  const float* be2 = (const float*)d_in[9];
  const float* Wl  = (const float*)d_in[10];
  const float* bl  = (const float*)d_in[11];
  const float* gl  = (const float*)d_in[12];
  const float* bel = (const float*)d_in[13];
  const float* WcA = (const float*)d_in[14];
  const float* bcA = (const float*)d_in[15];
  const float* gA  = (const float*)d_in[16];
  const float* beA = (const float*)d_in[17];
  const float* WcB = (const float*)d_in[18];
  const float* bcB = (const float*)d_in[19];
  const float* gB  = (const float*)d_in[20];
  const float* beB = (const float*)d_in[21];
  const float* Wd  = (const float*)d_in[22];
  const float* bd  = (const float*)d_in[23];
  const float* Wo  = (const float*)d_in[24];
  const float* bo  = (const float*)d_in[25];
  float* out = (float*)d_out;

  char* ws = (char*)d_ws;
  int*    idxbuf = (int*)ws;                                   // 1 MB
  float*  drel   = (float*)(ws + (1u<<20));                    // 3 MB
  float*  bufX   = (float*)(ws + (4u<<20));                    // 16 MB
  float*  bufY   = (float*)(ws + (20u<<20));                   // 16 MB
  double* part1  = (double*)(ws + (36u<<20));                  // 64 KB
  double* part2  = (double*)(ws + (36u<<20) + (64u<<10));      // 64 KB
  double* partL  = (double*)(ws + (36u<<20) + (128u<<10));     // 512 KB
  double* partA  = (double*)(ws + (36u<<20) + (640u<<10));     // 512 KB
  double* partB  = (double*)(ws + (36u<<20) + (1152u<<10));    // 512 KB
  float*  bnp    = (float*)(ws + (36u<<20) + (1664u<<10));     // 2.3 KB

  knn_kernel<<<dim3(BNpts), dim3(256), 0, stream>>>(pos, idxbuf, drel);
  s1a_kernel<<<dim3(256), dim3(256), 0, stream>>>(drel, W1, b1, part1);
  s1b_kernel<<<dim3(256), dim3(256), 0, stream>>>(drel, W1, b1, W2, b2, part1, g1, be1, part2);
  s2l_kernel<<<dim3(128), dim3(256), 0, stream>>>(drel, Wl, bl, bufX, partL);
  s2conv_kernel<1><<<dim3(128), dim3(256), 0, stream>>>(partL, gl, bel, WcA, bcA, bufX, bufY, partA);
  s2conv_kernel<0><<<dim3(128), dim3(256), 0, stream>>>(partA, gA, beA, WcB, bcB, bufY, bufX, partB);
  bnall_kernel<<<dim3(1), dim3(256), 0, stream>>>(part1, part2, partB, g1, be1, g2, be2, gB, beB, bnp);
  final_kernel<<<dim3(4096), dim3(256), 0, stream>>>(x, idxbuf, drel, bufX, bnp,
                                                     W1, b1, W2, b2, Wd, bd, Wo, bo, out);
}

// Round 7
// 521.187 us; speedup vs baseline: 2.3827x; 1.1959x over previous
//
#include <hip/hip_runtime.h>
#include <math.h>

#define NN 2048
#define KNbr 16
#define BNpts 16384
#define BNKr  262144

__device__ __forceinline__ float eluf(float v) { return v > 0.f ? v : expm1f(v); }

__device__ __forceinline__ unsigned long long shfl_xor_u64(unsigned long long v, int off) {
  unsigned int lo = (unsigned int)v, hi = (unsigned int)(v >> 32);
  lo = (unsigned int)__shfl_xor((int)lo, off, 64);
  hi = (unsigned int)__shfl_xor((int)hi, off, 64);
  return ((unsigned long long)hi << 32) | (unsigned long long)lo;
}

// ---------------- KNN: packed-u64-key variant of the VALIDATED round-2/5/6
// structure. d2 formula bit-identical. key = (monotone_u32(d2) << 32) | m:
//   u = bits ^ (0x80000000 | arith_shr(bits,31))  -- strictly monotone over
//   floats; d2 can never be -0.0 (fadd(sqn,sqm) >= +0; IEEE RN equal-sub
//   gives +0), never NaN/Inf. Index in low bits => keys unique => u64 '<'
//   IS the reference lexicographic (d2, index) order; min is tie-free and
//   order-independent. Same scan pattern / butterfly / thread0-merge /
//   2 barriers per round as the validated kernel.
__global__ __launch_bounds__(256) void knn_kernel(const float* __restrict__ pos,
                                                  int* __restrict__ idxout,
                                                  float* __restrict__ drel) {
  int bn = blockIdx.x;
  int b = bn >> 11, n = bn & (NN - 1);
  const float* pb = pos + (size_t)b * NN * 3;
  __shared__ unsigned long long keys[NN];
  __shared__ unsigned long long wk[4];
  float qx = pb[n*3], qy = pb[n*3+1], qz = pb[n*3+2];
  float sqn = __fadd_rn(__fadd_rn(__fmul_rn(qx,qx), __fmul_rn(qy,qy)), __fmul_rn(qz,qz));
  for (int m = threadIdx.x; m < NN; m += 256) {
    float px = pb[m*3], py = pb[m*3+1], pz = pb[m*3+2];
    float sqm = __fadd_rn(__fadd_rn(__fmul_rn(px,px), __fmul_rn(py,py)), __fmul_rn(pz,pz));
    float dot = __fmaf_rn(qz, pz, __fmaf_rn(qy, py, __fmul_rn(qx, px)));
    float d2  = __fsub_rn(__fadd_rn(sqn, sqm), __fmul_rn(2.0f, dot));
    unsigned int bits = __float_as_uint(d2);
    unsigned int u = bits ^ (0x80000000u | (unsigned int)((int)bits >> 31));
    keys[m] = ((unsigned long long)u << 32) | (unsigned int)m;
  }
  __syncthreads();
  int lane = threadIdx.x & 63, wav = threadIdx.x >> 6;
  for (int k = 0; k < KNbr; ++k) {
    unsigned long long bk = 0xFFFFFFFFFFFFFFFFull;
#pragma unroll
    for (int r = 0; r < 8; ++r) {
      unsigned long long kk = keys[r*256 + threadIdx.x];
      if (kk < bk) bk = kk;
    }
#pragma unroll
    for (int off = 32; off > 0; off >>= 1) {
      unsigned long long ok = shfl_xor_u64(bk, off);
      if (ok < bk) bk = ok;
    }
    if (lane == 0) wk[wav] = bk;
    __syncthreads();
    if (threadIdx.x == 0) {
      unsigned long long fk = wk[0];
      if (wk[1] < fk) fk = wk[1];
      if (wk[2] < fk) fk = wk[2];
      if (wk[3] < fk) fk = wk[3];
      int fi = (int)(unsigned int)(fk & 0xFFFFFFFFull);
      idxout[bn*KNbr + k] = fi;
      keys[fi] = 0xFFFFFFFFFFFFFFFFull;
      drel[(size_t)(bn*KNbr + k)*3 + 0] = __fsub_rn(qx, pb[fi*3+0]);
      drel[(size_t)(bn*KNbr + k)*3 + 1] = __fsub_rn(qy, pb[fi*3+1]);
      drel[(size_t)(bn*KNbr + k)*3 + 2] = __fsub_rn(qz, pb[fi*3+2]);
    }
    __syncthreads();
  }
}

// ---------------- mlp1 layer-1 stats (f32 compute, f64 partial store) -------
__global__ __launch_bounds__(256) void s1a_kernel(const float* __restrict__ drel,
                                                  const float* __restrict__ W1,
                                                  const float* __restrict__ b1,
                                                  double* __restrict__ part1) {
  __shared__ float sW[64];
  int tid = threadIdx.x;
  if (tid < 48) sW[tid] = W1[tid];
  if (tid < 16) sW[48+tid] = b1[tid];
  __syncthreads();
  const float4* src4 = (const float4*)(drel + ((size_t)blockIdx.x*1024 + tid*4)*3);
  float a[12];
#pragma unroll
  for (int q = 0; q < 3; ++q) { float4 t = src4[q]; a[q*4]=t.x; a[q*4+1]=t.y; a[q*4+2]=t.z; a[q*4+3]=t.w; }
  float s[16], s2[16];
#pragma unroll
  for (int c = 0; c < 16; ++c) { s[c] = 0.f; s2[c] = 0.f; }
#pragma unroll
  for (int i = 0; i < 4; ++i) {
    float a0 = a[i*3], a1 = a[i*3+1], a2 = a[i*3+2];
#pragma unroll
    for (int c = 0; c < 16; ++c) {
      float v = a0*sW[c] + a1*sW[16+c] + a2*sW[32+c] + sW[48+c];
      float e = eluf(v);
      s[c] += e; s2[c] += e*e;
    }
  }
  __shared__ float wred[4][32];
  int lane = tid & 63, wav = tid >> 6;
#pragma unroll
  for (int j = 0; j < 32; ++j) {
    float v = (j < 16) ? s[j] : s2[j-16];
    for (int sh = 32; sh > 0; sh >>= 1) v += __shfl_down(v, sh);
    if (lane == 0) wred[wav][j] = v;
  }
  __syncthreads();
  if (tid < 32)
    part1[(size_t)blockIdx.x*32 + tid] =
      (double)wred[0][tid] + (double)wred[1][tid] + (double)wred[2][tid] + (double)wred[3][tid];
}

// ---------------- mlp1 layer-2 stats (folds bn1 reduce; f32 compute) --------
__global__ __launch_bounds__(256) void s1b_kernel(const float* __restrict__ drel,
                                                  const float* __restrict__ W1,
                                                  const float* __restrict__ b1,
                                                  const float* __restrict__ W2,
                                                  const float* __restrict__ b2,
                                                  const double* __restrict__ part1,
                                                  const float* __restrict__ g1,
                                                  const float* __restrict__ be1,
                                                  double* __restrict__ part2) {
  int tid = threadIdx.x;
  __shared__ double red[8][32];
  __shared__ float fsc1[16], fsh1[16];
  __shared__ float sW[64];
  __shared__ float sW2t[256];
  {
    int j = tid & 31, grp = tid >> 5;
    double v = 0.0;
    for (int bk = grp; bk < 256; bk += 8) v += part1[(size_t)bk*32 + j];
    red[grp][j] = v;
  }
  if (tid < 48) sW[tid] = W1[tid];
  if (tid < 16) sW[48+tid] = b1[tid];
  sW2t[tid] = W2[(tid & 15)*16 + (tid >> 4)];   // sW2t[c2*16+j] = W2[j][c2]
  __syncthreads();
  if (tid < 32) {
    double v = 0.0;
    for (int g = 0; g < 8; ++g) v += red[g][tid];
    red[0][tid] = v;
  }
  __syncthreads();
  if (tid < 16) {
    double S = red[0][tid], S2 = red[0][16 + tid];
    double m = S/262144.0, var = S2/262144.0 - m*m;
    double sc = (double)g1[tid]/sqrt(var + 1e-5);
    fsc1[tid] = (float)sc;
    fsh1[tid] = (float)((double)be1[tid] - m*sc);
  }
  __syncthreads();
  const float4* src4 = (const float4*)(drel + ((size_t)blockIdx.x*1024 + tid*4)*3);
  float a[12];
#pragma unroll
  for (int q = 0; q < 3; ++q) { float4 t = src4[q]; a[q*4]=t.x; a[q*4+1]=t.y; a[q*4+2]=t.z; a[q*4+3]=t.w; }
  float s[16], s2[16];
#pragma unroll
  for (int c = 0; c < 16; ++c) { s[c] = 0.f; s2[c] = 0.f; }
#pragma unroll
  for (int i = 0; i < 4; ++i) {
    float a0 = a[i*3], a1 = a[i*3+1], a2 = a[i*3+2];
    float y[16];
#pragma unroll
    for (int c = 0; c < 16; ++c) {
      float v = a0*sW[c] + a1*sW[16+c] + a2*sW[32+c] + sW[48+c];
      y[c] = eluf(v)*fsc1[c] + fsh1[c];
    }
#pragma unroll
    for (int c2 = 0; c2 < 16; ++c2) {
      float v = b2[c2];
      const float4* w4 = (const float4*)&sW2t[c2*16];
#pragma unroll
      for (int j4 = 0; j4 < 4; ++j4) {
        float4 ww = w4[j4];
        v += y[j4*4]*ww.x + y[j4*4+1]*ww.y + y[j4*4+2]*ww.z + y[j4*4+3]*ww.w;
      }
      float e = eluf(v);
      s[c2] += e; s2[c2] += e*e;
    }
  }
  __shared__ float wred[4][32];
  int lane = tid & 63, wav = tid >> 6;
#pragma unroll
  for (int j = 0; j < 32; ++j) {
    float v = (j < 16) ? s[j] : s2[j-16];
    for (int sh = 32; sh > 0; sh >>= 1) v += __shfl_down(v, sh);
    if (lane == 0) wred[wav][j] = v;
  }
  __syncthreads();
  if (tid < 32)
    part2[(size_t)blockIdx.x*32 + tid] =
      (double)wred[0][tid] + (double)wred[1][tid] + (double)wred[2][tid] + (double)wred[3][tid];
}

// ---------------- mlp2 linear: f32 compute, f32 store, f64 accum ------------
__global__ __launch_bounds__(256) void s2l_kernel(const float* __restrict__ drel,
                                                  const float* __restrict__ Wl,
                                                  const float* __restrict__ bl,
                                                  float* __restrict__ tL,
                                                  double* __restrict__ partL) {
  __shared__ float srows[128*48];
  int tid = threadIdx.x;
  const float* src = drel + (size_t)blockIdx.x * 6144;
  for (int i = tid; i < 6144; i += 256) srows[i] = src[i];
  float w[48];
#pragma unroll
  for (int j = 0; j < 48; ++j) w[j] = Wl[j*256 + tid];
  float bias = bl[tid];
  __syncthreads();
  double s = 0.0, s2 = 0.0;
  for (int r = 0; r < 128; ++r) {
    float v = bias;
    const float4* sr = (const float4*)&srows[r*48];
#pragma unroll
    for (int j4 = 0; j4 < 12; ++j4) {
      float4 a4 = sr[j4];
      v += a4.x*w[j4*4] + a4.y*w[j4*4+1] + a4.z*w[j4*4+2] + a4.w*w[j4*4+3];
    }
    float e = eluf(v);
    tL[(size_t)(blockIdx.x*128 + r)*256 + tid] = e;
    double ed = (double)e;
    s += ed; s2 += ed*ed;
  }
  partL[(size_t)blockIdx.x*512 + tid]       = s;
  partL[(size_t)blockIdx.x*512 + 256 + tid] = s2;
}

// ---------------- grouped conv (A: elu, B: none); folds prev BN reduce ------
template<int DO_ELU>
__global__ __launch_bounds__(256) void s2conv_kernel(const double* __restrict__ partIn,
                                                     const float* __restrict__ gIn,
                                                     const float* __restrict__ beIn,
                                                     const float* __restrict__ Wc,
                                                     const float* __restrict__ bc,
                                                     const float* __restrict__ tIn,
                                                     float* __restrict__ tOut,
                                                     double* __restrict__ partOut) {
  int tid = threadIdx.x;
  double S = 0.0, S2 = 0.0;
  for (int bk = 0; bk < 128; ++bk) {
    S  += partIn[(size_t)bk*512 + tid];
    S2 += partIn[(size_t)bk*512 + 256 + tid];
  }
  double m = S/16384.0, var = S2/16384.0 - m*m;
  double scd = (double)gIn[tid]/sqrt(var + 1e-5);
  float sc = (float)scd, sh = (float)((double)beIn[tid] - m*scd);
  int g = tid >> 4, o = tid & 15;
  float w[16];
#pragma unroll
  for (int k = 0; k < 16; ++k) w[k] = Wc[g*256 + o*16 + k];
  float bias = bc[tid];
  __shared__ float sin_[16*256];
  double s = 0.0, s2 = 0.0;
  const float* base = tIn + (size_t)blockIdx.x*128*256;
  float* outb = tOut + (size_t)blockIdx.x*128*256;
  for (int chunk = 0; chunk < 8; ++chunk) {
    __syncthreads();
    for (int rr = 0; rr < 16; ++rr)
      sin_[rr*256 + tid] = base[(chunk*16 + rr)*256 + tid]*sc + sh;
    __syncthreads();
    for (int rr = 0; rr < 16; ++rr) {
      float v = bias;
      const float4* row4 = (const float4*)&sin_[rr*256 + g*16];
#pragma unroll
      for (int k4 = 0; k4 < 4; ++k4) {
        float4 a4 = row4[k4];
        v += a4.x*w[k4*4] + a4.y*w[k4*4+1] + a4.z*w[k4*4+2] + a4.w*w[k4*4+3];
      }
      float e = DO_ELU ? eluf(v) : v;
      outb[(chunk*16 + rr)*256 + tid] = e;
      double ed = (double)e;
      s += ed; s2 += ed*ed;
    }
  }
  partOut[(size_t)blockIdx.x*512 + tid]       = s;
  partOut[(size_t)blockIdx.x*512 + 256 + tid] = s2;
}

// ---------------- bn1/bn2/bnB -> f32 scale/shift ----------------------------
__global__ void bnall_kernel(const double* __restrict__ part1,
                             const double* __restrict__ part2,
                             const double* __restrict__ partB,
                             const float* __restrict__ g1, const float* __restrict__ be1,
                             const float* __restrict__ g2, const float* __restrict__ be2,
                             const float* __restrict__ gB, const float* __restrict__ beB,
                             float* __restrict__ bnp) {
  int tid = threadIdx.x;
  if (tid < 32) {
    int c = tid & 15;
    const double* P = (tid < 16) ? part1 : part2;
    double S = 0.0, S2 = 0.0;
    for (int bk = 0; bk < 256; ++bk) { S += P[(size_t)bk*32 + c]; S2 += P[(size_t)bk*32 + 16 + c]; }
    double m = S/262144.0, var = S2/262144.0 - m*m;
    const float* g  = (tid < 16) ? g1 : g2;
    const float* be = (tid < 16) ? be1 : be2;
    double sc = (double)g[c]/sqrt(var + 1e-5);
    int off = (tid < 16) ? 0 : 32;
    bnp[off + c]      = (float)sc;
    bnp[off + 16 + c] = (float)((double)be[c] - m*sc);
  }
  {
    double S = 0.0, S2 = 0.0;
    for (int bk = 0; bk < 128; ++bk) { S += partB[(size_t)bk*512 + tid]; S2 += partB[(size_t)bk*512 + 256 + tid]; }
    double m = S/16384.0, var = S2/16384.0 - m*m;
    double sc = (double)gB[tid]/sqrt(var + 1e-5);
    bnp[64 + tid]  = (float)sc;
    bnp[320 + tid] = (float)((double)beB[tid] - m*sc);
  }
}

// ---------------- final: 2 points/block, xt in regs fused with dwconv -------
__global__ __launch_bounds__(256) void final_kernel(const float* __restrict__ x,
                                                    const int* __restrict__ idxbuf,
                                                    const float* __restrict__ drel,
                                                    const float* __restrict__ tB,
                                                    const float* __restrict__ bnp,
                                                    const float* __restrict__ W1,
                                                    const float* __restrict__ b1,
                                                    const float* __restrict__ W2,
                                                    const float* __restrict__ b2,
                                                    const float* __restrict__ Wd,
                                                    const float* __restrict__ bd,
                                                    const float* __restrict__ Wo,
                                                    const float* __restrict__ bo,
                                                    float* __restrict__ out) {
  int tid = threadIdx.x;
  int bn0 = blockIdx.x*2;
  int b = bn0 >> 11;
  __shared__ float sbn1[32], sbn2[32];
  __shared__ float sBs[256], sBh[256];
  __shared__ int   sidx[32];
  __shared__ float sdrel[96];
  __shared__ float sW1[48], sb1[16], sb2[16];
  __shared__ float sW2t[256];
  __shared__ float tmat[512];
  __shared__ float hs[2][16][16];
  __shared__ float xs[2][80][16];
  __shared__ float ovs[2][160];
  if (tid < 32) { sbn1[tid] = bnp[tid]; sbn2[tid] = bnp[32 + tid]; }
  sBs[tid] = bnp[64 + tid];
  sBh[tid] = bnp[320 + tid];
  if (tid < 32) sidx[tid] = idxbuf[bn0*16 + tid];
  if (tid < 96) sdrel[tid] = drel[(size_t)bn0*48 + tid];
  if (tid < 48) sW1[tid] = W1[tid];
  if (tid < 16) { sb1[tid] = b1[tid]; sb2[tid] = b2[tid]; }
  sW2t[tid] = W2[(tid & 15)*16 + (tid >> 4)];
  __syncthreads();
  for (int i = tid; i < 512; i += 256) {
    int c = i & 255;
    tmat[i] = tB[(size_t)bn0*256 + i]*sBs[c] + sBh[c];
  }
  for (int i = tid; i < 512; i += 256) {
    int pt = i >> 8, k = (i >> 4) & 15, c = i & 15;
    float a0 = sdrel[pt*48 + k*3], a1 = sdrel[pt*48 + k*3 + 1], a2 = sdrel[pt*48 + k*3 + 2];
    float v = a0*sW1[c] + a1*sW1[16+c] + a2*sW1[32+c] + sb1[c];
    hs[pt][k][c] = eluf(v)*sbn1[c] + sbn1[16+c];
  }
  __syncthreads();
  for (int i = tid; i < 512; i += 256) {
    int pt = i >> 8, k = (i >> 4) & 15, c2 = i & 15;
    float v = sb2[c2];
    const float4* w4 = (const float4*)&sW2t[c2*16];
    float* hrow = &hs[pt][k][0];
#pragma unroll
    for (int j4 = 0; j4 < 4; ++j4) {
      float4 ww = w4[j4];
      v += hrow[j4*4]*ww.x + hrow[j4*4+1]*ww.y + hrow[j4*4+2]*ww.z + hrow[j4*4+3]*ww.w;
    }
    xs[pt][c2][k] = eluf(v)*sbn2[c2] + sbn2[16+c2];
  }
  for (int i = tid; i < 2048; i += 256) {
    int pt = i >> 10, k = (i >> 6) & 15, c = i & 63;
    xs[pt][16 + c][k] = x[((size_t)b*NN + sidx[pt*16 + k])*64 + c];
  }
  __syncthreads();
  if (tid < 160) {
    int pt = (tid >= 80) ? 1 : 0;
    int c = tid - pt*80;
    float xtr[16];
#pragma unroll
    for (int o = 0; o < 16; ++o) {
      float v = 0.f;
#pragma unroll
      for (int k = 0; k < 16; ++k) v += xs[pt][c][k]*tmat[pt*256 + k*16 + o];
      xtr[o] = v;
    }
    float v0 = bd[c*2], v1 = bd[c*2 + 1];
#pragma unroll
    for (int k = 0; k < 16; ++k) {
      v0 += xtr[k]*Wd[c*32 + k];
      v1 += xtr[k]*Wd[c*32 + 16 + k];
    }
    ovs[pt][c*2]     = v0;
    ovs[pt][c*2 + 1] = v1;
  }
  __syncthreads();
  {
    int pt0 = tid >> 7, co = tid & 127;
    float v = bo[co];
    for (int i = 0; i < 160; ++i) v += ovs[pt0][i]*Wo[i*128 + co];
    out[(size_t)(bn0 + pt0)*128 + co] = v;
  }
}

extern "C" void kernel_launch(void* const* d_in, const int* in_sizes, int n_in,
                              void* d_out, int out_size, void* d_ws, size_t ws_size,
                              hipStream_t stream) {
  (void)in_sizes; (void)n_in; (void)out_size; (void)ws_size;
  const float* x   = (const float*)d_in[0];
  const float* pos = (const float*)d_in[1];
  const float* W1  = (const float*)d_in[2];
  const float* b1  = (const float*)d_in[3];
  const float* g1  = (const float*)d_in[4];
  const float* be1 = (const float*)d_in[5];
  const float* W2  = (const float*)d_in[6];
  const float* b2  = (const float*)d_in[7];
  const float* g2  = (const float*)d_in[8];
  const float* be2 = (const float*)d_in[9];
  const float* Wl  = (const float*)d_in[10];
  const float* bl  = (const float*)d_in[11];
  const float* gl  = (const float*)d_in[12];
  const float* bel = (const float*)d_in[13];
  const float* WcA = (const float*)d_in[14];
  const float* bcA = (const float*)d_in[15];
  const float* gA  = (const float*)d_in[16];
  const float* beA = (const float*)d_in[17];
  const float* WcB = (const float*)d_in[18];
  const float* bcB = (const float*)d_in[19];
  const float* gB  = (const float*)d_in[20];
  const float* beB = (const float*)d_in[21];
  const float* Wd  = (const float*)d_in[22];
  const float* bd  = (const float*)d_in[23];
  const float* Wo  = (const float*)d_in[24];
  const float* bo  = (const float*)d_in[25];
  float* out = (float*)d_out;

  char* ws = (char*)d_ws;
  int*    idxbuf = (int*)ws;                                   // 1 MB
  float*  drel   = (float*)(ws + (1u<<20));                    // 3 MB
  float*  bufX   = (float*)(ws + (4u<<20));                    // 16 MB
  float*  bufY   = (float*)(ws + (20u<<20));                   // 16 MB
  double* part1  = (double*)(ws + (36u<<20));                  // 64 KB
  double* part2  = (double*)(ws + (36u<<20) + (64u<<10));      // 64 KB
  double* partL  = (double*)(ws + (36u<<20) + (128u<<10));     // 512 KB
  double* partA  = (double*)(ws + (36u<<20) + (640u<<10));     // 512 KB
  double* partB  = (double*)(ws + (36u<<20) + (1152u<<10));    // 512 KB
  float*  bnp    = (float*)(ws + (36u<<20) + (1664u<<10));     // 2.3 KB

  knn_kernel<<<dim3(BNpts), dim3(256), 0, stream>>>(pos, idxbuf, drel);
  s1a_kernel<<<dim3(256), dim3(256), 0, stream>>>(drel, W1, b1, part1);
  s1b_kernel<<<dim3(256), dim3(256), 0, stream>>>(drel, W1, b1, W2, b2, part1, g1, be1, part2);
  s2l_kernel<<<dim3(128), dim3(256), 0, stream>>>(drel, Wl, bl, bufX, partL);
  s2conv_kernel<1><<<dim3(128), dim3(256), 0, stream>>>(partL, gl, bel, WcA, bcA, bufX, bufY, partA);
  s2conv_kernel<0><<<dim3(128), dim3(256), 0, stream>>>(partA, gA, beA, WcB, bcB, bufY, bufX, partB);
  bnall_kernel<<<dim3(1), dim3(256), 0, stream>>>(part1, part2, partB, g1, be1, g2, be2, gB, beB, bnp);
  final_kernel<<<dim3(8192), dim3(256), 0, stream>>>(x, idxbuf, drel, bufX, bnp,
                                                     W1, b1, W2, b2, Wd, bd, Wo, bo, out);
}

// Round 8
// 467.574 us; speedup vs baseline: 2.6559x; 1.1147x over previous
//
#include <hip/hip_runtime.h>
#include <math.h>

#define NN 2048
#define KNbr 16
#define BNpts 16384
#define BNKr  262144

__device__ __forceinline__ float eluf(float v) { return v > 0.f ? v : expm1f(v); }

__device__ __forceinline__ unsigned long long shfl_xor_u64(unsigned long long v, int off) {
  unsigned int lo = (unsigned int)v, hi = (unsigned int)(v >> 32);
  lo = (unsigned int)__shfl_xor((int)lo, off, 64);
  hi = (unsigned int)__shfl_xor((int)hi, off, 64);
  return ((unsigned long long)hi << 32) | (unsigned long long)lo;
}

// ---------------- KNN: u64-key min-selection, candidates in REGISTERS. ------
// Key = (monotone_u32(d2) << 32) | m  -- unique keys, so min-reduction is
// STRUCTURE-INDEPENDENT: any partition/order gives the identical top-16
// sequence (this is what makes the register layout provably safe, unlike the
// round-3 float+index tie-break rewrite). d2 formula bit-identical to the
// validated rounds 2/5/6/7. Cross-wave merge = round-7's validated
// shfl_xor_u64 + wk[] pattern; wk is parity double-buffered so one barrier
// per round suffices (writes to buffer p at round k+2 are ordered after
// round k+1's barrier, i.e. after all round-k reads of buffer p).
// Owner identity: m = r*256 + tid  =>  owner tid == (fi & 255), slot fi>>8.
__global__ __launch_bounds__(256) void knn_kernel(const float* __restrict__ pos,
                                                  int* __restrict__ idxout,
                                                  float* __restrict__ drel) {
  int bn = blockIdx.x;
  int b = bn >> 11, n = bn & (NN - 1);
  const float* pb = pos + (size_t)b * NN * 3;
  __shared__ unsigned long long wk[2][4];
  int tid = threadIdx.x;
  float qx = pb[n*3], qy = pb[n*3+1], qz = pb[n*3+2];
  float sqn = __fadd_rn(__fadd_rn(__fmul_rn(qx,qx), __fmul_rn(qy,qy)), __fmul_rn(qz,qz));
  unsigned long long kreg[8];
#pragma unroll
  for (int r = 0; r < 8; ++r) {
    int m = r*256 + tid;
    float px = pb[m*3], py = pb[m*3+1], pz = pb[m*3+2];
    float sqm = __fadd_rn(__fadd_rn(__fmul_rn(px,px), __fmul_rn(py,py)), __fmul_rn(pz,pz));
    float dot = __fmaf_rn(qz, pz, __fmaf_rn(qy, py, __fmul_rn(qx, px)));
    float d2  = __fsub_rn(__fadd_rn(sqn, sqm), __fmul_rn(2.0f, dot));
    unsigned int bits = __float_as_uint(d2);
    unsigned int u = bits ^ (0x80000000u | (unsigned int)((int)bits >> 31));
    kreg[r] = ((unsigned long long)u << 32) | (unsigned int)m;
  }
  int lane = tid & 63, wav = tid >> 6;
  for (int k = 0; k < KNbr; ++k) {
    unsigned long long bk = kreg[0];
#pragma unroll
    for (int r = 1; r < 8; ++r) if (kreg[r] < bk) bk = kreg[r];
#pragma unroll
    for (int off = 32; off > 0; off >>= 1) {
      unsigned long long ok = shfl_xor_u64(bk, off);
      if (ok < bk) bk = ok;
    }
    if (lane == 0) wk[k & 1][wav] = bk;
    __syncthreads();
    unsigned long long fk = wk[k & 1][0];
    if (wk[k & 1][1] < fk) fk = wk[k & 1][1];
    if (wk[k & 1][2] < fk) fk = wk[k & 1][2];
    if (wk[k & 1][3] < fk) fk = wk[k & 1][3];
    int fi = (int)(unsigned int)(fk & 0xFFFFFFFFull);
    if (tid == 0) {
      idxout[bn*KNbr + k] = fi;
      drel[(size_t)(bn*KNbr + k)*3 + 0] = __fsub_rn(qx, pb[fi*3+0]);
      drel[(size_t)(bn*KNbr + k)*3 + 1] = __fsub_rn(qy, pb[fi*3+1]);
      drel[(size_t)(bn*KNbr + k)*3 + 2] = __fsub_rn(qz, pb[fi*3+2]);
    }
    if ((fi & 255) == tid) {
      int wsl = fi >> 8;
#pragma unroll
      for (int r = 0; r < 8; ++r) if (r == wsl) kreg[r] = 0xFFFFFFFFFFFFFFFFull;
    }
  }
}

// ---------------- mlp1 layer-1 stats (f32 compute, f64 partial store) -------
__global__ __launch_bounds__(256) void s1a_kernel(const float* __restrict__ drel,
                                                  const float* __restrict__ W1,
                                                  const float* __restrict__ b1,
                                                  double* __restrict__ part1) {
  __shared__ float sW[64];
  int tid = threadIdx.x;
  if (tid < 48) sW[tid] = W1[tid];
  if (tid < 16) sW[48+tid] = b1[tid];
  __syncthreads();
  const float4* src4 = (const float4*)(drel + ((size_t)blockIdx.x*1024 + tid*4)*3);
  float a[12];
#pragma unroll
  for (int q = 0; q < 3; ++q) { float4 t = src4[q]; a[q*4]=t.x; a[q*4+1]=t.y; a[q*4+2]=t.z; a[q*4+3]=t.w; }
  float s[16], s2[16];
#pragma unroll
  for (int c = 0; c < 16; ++c) { s[c] = 0.f; s2[c] = 0.f; }
#pragma unroll
  for (int i = 0; i < 4; ++i) {
    float a0 = a[i*3], a1 = a[i*3+1], a2 = a[i*3+2];
#pragma unroll
    for (int c = 0; c < 16; ++c) {
      float v = a0*sW[c] + a1*sW[16+c] + a2*sW[32+c] + sW[48+c];
      float e = eluf(v);
      s[c] += e; s2[c] += e*e;
    }
  }
  __shared__ float wred[4][32];
  int lane = tid & 63, wav = tid >> 6;
#pragma unroll
  for (int j = 0; j < 32; ++j) {
    float v = (j < 16) ? s[j] : s2[j-16];
    for (int sh = 32; sh > 0; sh >>= 1) v += __shfl_down(v, sh);
    if (lane == 0) wred[wav][j] = v;
  }
  __syncthreads();
  if (tid < 32)
    part1[(size_t)blockIdx.x*32 + tid] =
      (double)wred[0][tid] + (double)wred[1][tid] + (double)wred[2][tid] + (double)wred[3][tid];
}

// ---------------- mlp1 layer-2 stats (folds bn1 reduce; f32 compute) --------
__global__ __launch_bounds__(256) void s1b_kernel(const float* __restrict__ drel,
                                                  const float* __restrict__ W1,
                                                  const float* __restrict__ b1,
                                                  const float* __restrict__ W2,
                                                  const float* __restrict__ b2,
                                                  const double* __restrict__ part1,
                                                  const float* __restrict__ g1,
                                                  const float* __restrict__ be1,
                                                  double* __restrict__ part2) {
  int tid = threadIdx.x;
  __shared__ double red[8][32];
  __shared__ float fsc1[16], fsh1[16];
  __shared__ float sW[64];
  __shared__ float sW2t[256];
  {
    int j = tid & 31, grp = tid >> 5;
    double v = 0.0;
    for (int bk = grp; bk < 256; bk += 8) v += part1[(size_t)bk*32 + j];
    red[grp][j] = v;
  }
  if (tid < 48) sW[tid] = W1[tid];
  if (tid < 16) sW[48+tid] = b1[tid];
  sW2t[tid] = W2[(tid & 15)*16 + (tid >> 4)];   // sW2t[c2*16+j] = W2[j][c2]
  __syncthreads();
  if (tid < 32) {
    double v = 0.0;
    for (int g = 0; g < 8; ++g) v += red[g][tid];
    red[0][tid] = v;
  }
  __syncthreads();
  if (tid < 16) {
    double S = red[0][tid], S2 = red[0][16 + tid];
    double m = S/262144.0, var = S2/262144.0 - m*m;
    double sc = (double)g1[tid]/sqrt(var + 1e-5);
    fsc1[tid] = (float)sc;
    fsh1[tid] = (float)((double)be1[tid] - m*sc);
  }
  __syncthreads();
  const float4* src4 = (const float4*)(drel + ((size_t)blockIdx.x*1024 + tid*4)*3);
  float a[12];
#pragma unroll
  for (int q = 0; q < 3; ++q) { float4 t = src4[q]; a[q*4]=t.x; a[q*4+1]=t.y; a[q*4+2]=t.z; a[q*4+3]=t.w; }
  float s[16], s2[16];
#pragma unroll
  for (int c = 0; c < 16; ++c) { s[c] = 0.f; s2[c] = 0.f; }
#pragma unroll
  for (int i = 0; i < 4; ++i) {
    float a0 = a[i*3], a1 = a[i*3+1], a2 = a[i*3+2];
    float y[16];
#pragma unroll
    for (int c = 0; c < 16; ++c) {
      float v = a0*sW[c] + a1*sW[16+c] + a2*sW[32+c] + sW[48+c];
      y[c] = eluf(v)*fsc1[c] + fsh1[c];
    }
#pragma unroll
    for (int c2 = 0; c2 < 16; ++c2) {
      float v = b2[c2];
      const float4* w4 = (const float4*)&sW2t[c2*16];
#pragma unroll
      for (int j4 = 0; j4 < 4; ++j4) {
        float4 ww = w4[j4];
        v += y[j4*4]*ww.x + y[j4*4+1]*ww.y + y[j4*4+2]*ww.z + y[j4*4+3]*ww.w;
      }
      float e = eluf(v);
      s[c2] += e; s2[c2] += e*e;
    }
  }
  __shared__ float wred[4][32];
  int lane = tid & 63, wav = tid >> 6;
#pragma unroll
  for (int j = 0; j < 32; ++j) {
    float v = (j < 16) ? s[j] : s2[j-16];
    for (int sh = 32; sh > 0; sh >>= 1) v += __shfl_down(v, sh);
    if (lane == 0) wred[wav][j] = v;
  }
  __syncthreads();
  if (tid < 32)
    part2[(size_t)blockIdx.x*32 + tid] =
      (double)wred[0][tid] + (double)wred[1][tid] + (double)wred[2][tid] + (double)wred[3][tid];
}

// ---------------- mlp2 linear: f32 compute, f32 store, f64 accum ------------
__global__ __launch_bounds__(256) void s2l_kernel(const float* __restrict__ drel,
                                                  const float* __restrict__ Wl,
                                                  const float* __restrict__ bl,
                                                  float* __restrict__ tL,
                                                  double* __restrict__ partL) {
  __shared__ float srows[128*48];
  int tid = threadIdx.x;
  const float* src = drel + (size_t)blockIdx.x * 6144;
  for (int i = tid; i < 6144; i += 256) srows[i] = src[i];
  float w[48];
#pragma unroll
  for (int j = 0; j < 48; ++j) w[j] = Wl[j*256 + tid];
  float bias = bl[tid];
  __syncthreads();
  double s = 0.0, s2 = 0.0;
  for (int r = 0; r < 128; ++r) {
    float v = bias;
    const float4* sr = (const float4*)&srows[r*48];
#pragma unroll
    for (int j4 = 0; j4 < 12; ++j4) {
      float4 a4 = sr[j4];
      v += a4.x*w[j4*4] + a4.y*w[j4*4+1] + a4.z*w[j4*4+2] + a4.w*w[j4*4+3];
    }
    float e = eluf(v);
    tL[(size_t)(blockIdx.x*128 + r)*256 + tid] = e;
    double ed = (double)e;
    s += ed; s2 += ed*ed;
  }
  partL[(size_t)blockIdx.x*512 + tid]       = s;
  partL[(size_t)blockIdx.x*512 + 256 + tid] = s2;
}

// ---------------- grouped conv (A: elu, B: none); folds prev BN reduce ------
template<int DO_ELU>
__global__ __launch_bounds__(256) void s2conv_kernel(const double* __restrict__ partIn,
                                                     const float* __restrict__ gIn,
                                                     const float* __restrict__ beIn,
                                                     const float* __restrict__ Wc,
                                                     const float* __restrict__ bc,
                                                     const float* __restrict__ tIn,
                                                     float* __restrict__ tOut,
                                                     double* __restrict__ partOut) {
  int tid = threadIdx.x;
  double S = 0.0, S2 = 0.0;
  for (int bk = 0; bk < 128; ++bk) {
    S  += partIn[(size_t)bk*512 + tid];
    S2 += partIn[(size_t)bk*512 + 256 + tid];
  }
  double m = S/16384.0, var = S2/16384.0 - m*m;
  double scd = (double)gIn[tid]/sqrt(var + 1e-5);
  float sc = (float)scd, sh = (float)((double)beIn[tid] - m*scd);
  int g = tid >> 4, o = tid & 15;
  float w[16];
#pragma unroll
  for (int k = 0; k < 16; ++k) w[k] = Wc[g*256 + o*16 + k];
  float bias = bc[tid];
  __shared__ float sin_[16*256];
  double s = 0.0, s2 = 0.0;
  const float* base = tIn + (size_t)blockIdx.x*128*256;
  float* outb = tOut + (size_t)blockIdx.x*128*256;
  for (int chunk = 0; chunk < 8; ++chunk) {
    __syncthreads();
    for (int rr = 0; rr < 16; ++rr)
      sin_[rr*256 + tid] = base[(chunk*16 + rr)*256 + tid]*sc + sh;
    __syncthreads();
    for (int rr = 0; rr < 16; ++rr) {
      float v = bias;
      const float4* row4 = (const float4*)&sin_[rr*256 + g*16];
#pragma unroll
      for (int k4 = 0; k4 < 4; ++k4) {
        float4 a4 = row4[k4];
        v += a4.x*w[k4*4] + a4.y*w[k4*4+1] + a4.z*w[k4*4+2] + a4.w*w[k4*4+3];
      }
      float e = DO_ELU ? eluf(v) : v;
      outb[(chunk*16 + rr)*256 + tid] = e;
      double ed = (double)e;
      s += ed; s2 += ed*ed;
    }
  }
  partOut[(size_t)blockIdx.x*512 + tid]       = s;
  partOut[(size_t)blockIdx.x*512 + 256 + tid] = s2;
}

// ---------------- bn1/bn2/bnB -> f32 scale/shift ----------------------------
__global__ void bnall_kernel(const double* __restrict__ part1,
                             const double* __restrict__ part2,
                             const double* __restrict__ partB,
                             const float* __restrict__ g1, const float* __restrict__ be1,
                             const float* __restrict__ g2, const float* __restrict__ be2,
                             const float* __restrict__ gB, const float* __restrict__ beB,
                             float* __restrict__ bnp) {
  int tid = threadIdx.x;
  if (tid < 32) {
    int c = tid & 15;
    const double* P = (tid < 16) ? part1 : part2;
    double S = 0.0, S2 = 0.0;
    for (int bk = 0; bk < 256; ++bk) { S += P[(size_t)bk*32 + c]; S2 += P[(size_t)bk*32 + 16 + c]; }
    double m = S/262144.0, var = S2/262144.0 - m*m;
    const float* g  = (tid < 16) ? g1 : g2;
    const float* be = (tid < 16) ? be1 : be2;
    double sc = (double)g[c]/sqrt(var + 1e-5);
    int off = (tid < 16) ? 0 : 32;
    bnp[off + c]      = (float)sc;
    bnp[off + 16 + c] = (float)((double)be[c] - m*sc);
  }
  {
    double S = 0.0, S2 = 0.0;
    for (int bk = 0; bk < 128; ++bk) { S += partB[(size_t)bk*512 + tid]; S2 += partB[(size_t)bk*512 + 256 + tid]; }
    double m = S/16384.0, var = S2/16384.0 - m*m;
    double sc = (double)gB[tid]/sqrt(var + 1e-5);
    bnp[64 + tid]  = (float)sc;
    bnp[320 + tid] = (float)((double)beB[tid] - m*sc);
  }
}

// ---------------- final: 2 points/block, xt in regs fused with dwconv -------
__global__ __launch_bounds__(256) void final_kernel(const float* __restrict__ x,
                                                    const int* __restrict__ idxbuf,
                                                    const float* __restrict__ drel,
                                                    const float* __restrict__ tB,
                                                    const float* __restrict__ bnp,
                                                    const float* __restrict__ W1,
                                                    const float* __restrict__ b1,
                                                    const float* __restrict__ W2,
                                                    const float* __restrict__ b2,
                                                    const float* __restrict__ Wd,
                                                    const float* __restrict__ bd,
                                                    const float* __restrict__ Wo,
                                                    const float* __restrict__ bo,
                                                    float* __restrict__ out) {
  int tid = threadIdx.x;
  int bn0 = blockIdx.x*2;
  int b = bn0 >> 11;
  __shared__ float sbn1[32], sbn2[32];
  __shared__ float sBs[256], sBh[256];
  __shared__ int   sidx[32];
  __shared__ float sdrel[96];
  __shared__ float sW1[48], sb1[16], sb2[16];
  __shared__ float sW2t[256];
  __shared__ float tmat[512];
  __shared__ float hs[2][16][16];
  __shared__ float xs[2][80][16];
  __shared__ float ovs[2][160];
  if (tid < 32) { sbn1[tid] = bnp[tid]; sbn2[tid] = bnp[32 + tid]; }
  sBs[tid] = bnp[64 + tid];
  sBh[tid] = bnp[320 + tid];
  if (tid < 32) sidx[tid] = idxbuf[bn0*16 + tid];
  if (tid < 96) sdrel[tid] = drel[(size_t)bn0*48 + tid];
  if (tid < 48) sW1[tid] = W1[tid];
  if (tid < 16) { sb1[tid] = b1[tid]; sb2[tid] = b2[tid]; }
  sW2t[tid] = W2[(tid & 15)*16 + (tid >> 4)];
  __syncthreads();
  for (int i = tid; i < 512; i += 256) {
    int c = i & 255;
    tmat[i] = tB[(size_t)bn0*256 + i]*sBs[c] + sBh[c];
  }
  for (int i = tid; i < 512; i += 256) {
    int pt = i >> 8, k = (i >> 4) & 15, c = i & 15;
    float a0 = sdrel[pt*48 + k*3], a1 = sdrel[pt*48 + k*3 + 1], a2 = sdrel[pt*48 + k*3 + 2];
    float v = a0*sW1[c] + a1*sW1[16+c] + a2*sW1[32+c] + sb1[c];
    hs[pt][k][c] = eluf(v)*sbn1[c] + sbn1[16+c];
  }
  __syncthreads();
  for (int i = tid; i < 512; i += 256) {
    int pt = i >> 8, k = (i >> 4) & 15, c2 = i & 15;
    float v = sb2[c2];
    const float4* w4 = (const float4*)&sW2t[c2*16];
    float* hrow = &hs[pt][k][0];
#pragma unroll
    for (int j4 = 0; j4 < 4; ++j4) {
      float4 ww = w4[j4];
      v += hrow[j4*4]*ww.x + hrow[j4*4+1]*ww.y + hrow[j4*4+2]*ww.z + hrow[j4*4+3]*ww.w;
    }
    xs[pt][c2][k] = eluf(v)*sbn2[c2] + sbn2[16+c2];
  }
  for (int i = tid; i < 2048; i += 256) {
    int pt = i >> 10, k = (i >> 6) & 15, c = i & 63;
    xs[pt][16 + c][k] = x[((size_t)b*NN + sidx[pt*16 + k])*64 + c];
  }
  __syncthreads();
  if (tid < 160) {
    int pt = (tid >= 80) ? 1 : 0;
    int c = tid - pt*80;
    float xtr[16];
#pragma unroll
    for (int o = 0; o < 16; ++o) {
      float v = 0.f;
#pragma unroll
      for (int k = 0; k < 16; ++k) v += xs[pt][c][k]*tmat[pt*256 + k*16 + o];
      xtr[o] = v;
    }
    float v0 = bd[c*2], v1 = bd[c*2 + 1];
#pragma unroll
    for (int k = 0; k < 16; ++k) {
      v0 += xtr[k]*Wd[c*32 + k];
      v1 += xtr[k]*Wd[c*32 + 16 + k];
    }
    ovs[pt][c*2]     = v0;
    ovs[pt][c*2 + 1] = v1;
  }
  __syncthreads();
  {
    int pt0 = tid >> 7, co = tid & 127;
    float v = bo[co];
    for (int i = 0; i < 160; ++i) v += ovs[pt0][i]*Wo[i*128 + co];
    out[(size_t)(bn0 + pt0)*128 + co] = v;
  }
}

extern "C" void kernel_launch(void* const* d_in, const int* in_sizes, int n_in,
                              void* d_out, int out_size, void* d_ws, size_t ws_size,
                              hipStream_t stream) {
  (void)in_sizes; (void)n_in; (void)out_size; (void)ws_size;
  const float* x   = (const float*)d_in[0];
  const float* pos = (const float*)d_in[1];
  const float* W1  = (const float*)d_in[2];
  const float* b1  = (const float*)d_in[3];
  const float* g1  = (const float*)d_in[4];
  const float* be1 = (const float*)d_in[5];
  const float* W2  = (const float*)d_in[6];
  const float* b2  = (const float*)d_in[7];
  const float* g2  = (const float*)d_in[8];
  const float* be2 = (const float*)d_in[9];
  const float* Wl  = (const float*)d_in[10];
  const float* bl  = (const float*)d_in[11];
  const float* gl  = (const float*)d_in[12];
  const float* bel = (const float*)d_in[13];
  const float* WcA = (const float*)d_in[14];
  const float* bcA = (const float*)d_in[15];
  const float* gA  = (const float*)d_in[16];
  const float* beA = (const float*)d_in[17];
  const float* WcB = (const float*)d_in[18];
  const float* bcB = (const float*)d_in[19];
  const float* gB  = (const float*)d_in[20];
  const float* beB = (const float*)d_in[21];
  const float* Wd  = (const float*)d_in[22];
  const float* bd  = (const float*)d_in[23];
  const float* Wo  = (const float*)d_in[24];
  const float* bo  = (const float*)d_in[25];
  float* out = (float*)d_out;

  char* ws = (char*)d_ws;
  int*    idxbuf = (int*)ws;                                   // 1 MB
  float*  drel   = (float*)(ws + (1u<<20));                    // 3 MB
  float*  bufX   = (float*)(ws + (4u<<20));                    // 16 MB
  float*  bufY   = (float*)(ws + (20u<<20));                   // 16 MB
  double* part1  = (double*)(ws + (36u<<20));                  // 64 KB
  double* part2  = (double*)(ws + (36u<<20) + (64u<<10));      // 64 KB
  double* partL  = (double*)(ws + (36u<<20) + (128u<<10));     // 512 KB
  double* partA  = (double*)(ws + (36u<<20) + (640u<<10));     // 512 KB
  double* partB  = (double*)(ws + (36u<<20) + (1152u<<10));    // 512 KB
  float*  bnp    = (float*)(ws + (36u<<20) + (1664u<<10));     // 2.3 KB

  knn_kernel<<<dim3(BNpts), dim3(256), 0, stream>>>(pos, idxbuf, drel);
  s1a_kernel<<<dim3(256), dim3(256), 0, stream>>>(drel, W1, b1, part1);
  s1b_kernel<<<dim3(256), dim3(256), 0, stream>>>(drel, W1, b1, W2, b2, part1, g1, be1, part2);
  s2l_kernel<<<dim3(128), dim3(256), 0, stream>>>(drel, Wl, bl, bufX, partL);
  s2conv_kernel<1><<<dim3(128), dim3(256), 0, stream>>>(partL, gl, bel, WcA, bcA, bufX, bufY, partA);
  s2conv_kernel<0><<<dim3(128), dim3(256), 0, stream>>>(partA, gA, beA, WcB, bcB, bufY, bufX, partB);
  bnall_kernel<<<dim3(1), dim3(256), 0, stream>>>(part1, part2, partB, g1, be1, g2, be2, gB, beB, bnp);
  final_kernel<<<dim3(8192), dim3(256), 0, stream>>>(x, idxbuf, drel, bufX, bnp,
                                                     W1, b1, W2, b2, Wd, bd, Wo, bo, out);
}

// Round 9
// 415.148 us; speedup vs baseline: 2.9913x; 1.1263x over previous
//
#include <hip/hip_runtime.h>
#include <math.h>

#define NN 2048
#define KNbr 16
#define BNpts 16384
#define BNKr  262144

__device__ __forceinline__ float eluf(float v) { return v > 0.f ? v : expm1f(v); }

__device__ __forceinline__ unsigned long long shfl_xor_u64(unsigned long long v, int off) {
  unsigned int lo = (unsigned int)v, hi = (unsigned int)(v >> 32);
  lo = (unsigned int)__shfl_xor((int)lo, off, 64);
  hi = (unsigned int)__shfl_xor((int)hi, off, 64);
  return ((unsigned long long)hi << 32) | (unsigned long long)lo;
}

__device__ __forceinline__ unsigned long long umin64(unsigned long long a, unsigned long long b) {
  return a < b ? a : b;
}

// ---------------- KNN: ONE WAVE PER QUERY, u64-key min-selection. -----------
// Safety argument (validated rounds 7/8): key = (monotone_u32(d2) << 32) | m
// with unique keys => min-reduction is STRUCTURE-INDEPENDENT — any partition
// of the 2048 candidates (here: 32 per lane across 64 lanes) yields the
// identical top-16 sequence. d2 formula bit-identical to rounds 2/5/6/7/8.
// Per round: 31-op tree min over registers + validated 6-step shfl_xor_u64
// butterfly. NO barriers, NO LDS. Owner: m = s*64+lane => lane fi&63, slot fi>>6.
__global__ __launch_bounds__(256) void knn_kernel(const float* __restrict__ pos,
                                                  int* __restrict__ idxout,
                                                  float* __restrict__ drel) {
  int wav = threadIdx.x >> 6, lane = threadIdx.x & 63;
  int bn = blockIdx.x*4 + wav;
  int b = bn >> 11, n = bn & (NN - 1);
  const float* pb = pos + (size_t)b * NN * 3;
  float qx = pb[n*3], qy = pb[n*3+1], qz = pb[n*3+2];
  float sqn = __fadd_rn(__fadd_rn(__fmul_rn(qx,qx), __fmul_rn(qy,qy)), __fmul_rn(qz,qz));
  unsigned long long kreg[32];
#pragma unroll
  for (int s = 0; s < 32; ++s) {
    int m = s*64 + lane;
    float px = pb[m*3], py = pb[m*3+1], pz = pb[m*3+2];
    float sqm = __fadd_rn(__fadd_rn(__fmul_rn(px,px), __fmul_rn(py,py)), __fmul_rn(pz,pz));
    float dot = __fmaf_rn(qz, pz, __fmaf_rn(qy, py, __fmul_rn(qx, px)));
    float d2  = __fsub_rn(__fadd_rn(sqn, sqm), __fmul_rn(2.0f, dot));
    unsigned int bits = __float_as_uint(d2);
    unsigned int u = bits ^ (0x80000000u | (unsigned int)((int)bits >> 31));
    kreg[s] = ((unsigned long long)u << 32) | (unsigned int)m;
  }
  for (int k = 0; k < KNbr; ++k) {
    // tree min over the 32 register candidates (31 ops, ~5 dependent levels)
    unsigned long long g0 = umin64(umin64(kreg[0],  kreg[1]),  umin64(kreg[2],  kreg[3]));
    unsigned long long g1 = umin64(umin64(kreg[4],  kreg[5]),  umin64(kreg[6],  kreg[7]));
    unsigned long long g2 = umin64(umin64(kreg[8],  kreg[9]),  umin64(kreg[10], kreg[11]));
    unsigned long long g3 = umin64(umin64(kreg[12], kreg[13]), umin64(kreg[14], kreg[15]));
    unsigned long long g4 = umin64(umin64(kreg[16], kreg[17]), umin64(kreg[18], kreg[19]));
    unsigned long long g5 = umin64(umin64(kreg[20], kreg[21]), umin64(kreg[22], kreg[23]));
    unsigned long long g6 = umin64(umin64(kreg[24], kreg[25]), umin64(kreg[26], kreg[27]));
    unsigned long long g7 = umin64(umin64(kreg[28], kreg[29]), umin64(kreg[30], kreg[31]));
    unsigned long long bk = umin64(umin64(umin64(g0, g1), umin64(g2, g3)),
                                   umin64(umin64(g4, g5), umin64(g6, g7)));
#pragma unroll
    for (int off = 32; off > 0; off >>= 1) {
      unsigned long long ok = shfl_xor_u64(bk, off);
      if (ok < bk) bk = ok;
    }
    int fi = (int)(unsigned int)(bk & 0xFFFFFFFFull);
    if (lane == 0) {
      idxout[bn*KNbr + k] = fi;
      drel[(size_t)(bn*KNbr + k)*3 + 0] = __fsub_rn(qx, pb[fi*3+0]);
      drel[(size_t)(bn*KNbr + k)*3 + 1] = __fsub_rn(qy, pb[fi*3+1]);
      drel[(size_t)(bn*KNbr + k)*3 + 2] = __fsub_rn(qz, pb[fi*3+2]);
    }
    if ((fi & 63) == lane) {
      int wsl = fi >> 6;
#pragma unroll
      for (int s = 0; s < 32; ++s) if (s == wsl) kreg[s] = 0xFFFFFFFFFFFFFFFFull;
    }
  }
}

// ---------------- mlp1 layer-1 stats (f32 compute, f64 partial store) -------
__global__ __launch_bounds__(256) void s1a_kernel(const float* __restrict__ drel,
                                                  const float* __restrict__ W1,
                                                  const float* __restrict__ b1,
                                                  double* __restrict__ part1) {
  __shared__ float sW[64];
  int tid = threadIdx.x;
  if (tid < 48) sW[tid] = W1[tid];
  if (tid < 16) sW[48+tid] = b1[tid];
  __syncthreads();
  const float4* src4 = (const float4*)(drel + ((size_t)blockIdx.x*1024 + tid*4)*3);
  float a[12];
#pragma unroll
  for (int q = 0; q < 3; ++q) { float4 t = src4[q]; a[q*4]=t.x; a[q*4+1]=t.y; a[q*4+2]=t.z; a[q*4+3]=t.w; }
  float s[16], s2[16];
#pragma unroll
  for (int c = 0; c < 16; ++c) { s[c] = 0.f; s2[c] = 0.f; }
#pragma unroll
  for (int i = 0; i < 4; ++i) {
    float a0 = a[i*3], a1 = a[i*3+1], a2 = a[i*3+2];
#pragma unroll
    for (int c = 0; c < 16; ++c) {
      float v = a0*sW[c] + a1*sW[16+c] + a2*sW[32+c] + sW[48+c];
      float e = eluf(v);
      s[c] += e; s2[c] += e*e;
    }
  }
  __shared__ float wred[4][32];
  int lane = tid & 63, wav = tid >> 6;
#pragma unroll
  for (int j = 0; j < 32; ++j) {
    float v = (j < 16) ? s[j] : s2[j-16];
    for (int sh = 32; sh > 0; sh >>= 1) v += __shfl_down(v, sh);
    if (lane == 0) wred[wav][j] = v;
  }
  __syncthreads();
  if (tid < 32)
    part1[(size_t)blockIdx.x*32 + tid] =
      (double)wred[0][tid] + (double)wred[1][tid] + (double)wred[2][tid] + (double)wred[3][tid];
}

// ---------------- mlp1 layer-2 stats (folds bn1 reduce; f32 compute) --------
__global__ __launch_bounds__(256) void s1b_kernel(const float* __restrict__ drel,
                                                  const float* __restrict__ W1,
                                                  const float* __restrict__ b1,
                                                  const float* __restrict__ W2,
                                                  const float* __restrict__ b2,
                                                  const double* __restrict__ part1,
                                                  const float* __restrict__ g1,
                                                  const float* __restrict__ be1,
                                                  double* __restrict__ part2) {
  int tid = threadIdx.x;
  __shared__ double red[8][32];
  __shared__ float fsc1[16], fsh1[16];
  __shared__ float sW[64];
  __shared__ float sW2t[256];
  {
    int j = tid & 31, grp = tid >> 5;
    double v = 0.0;
    for (int bk = grp; bk < 256; bk += 8) v += part1[(size_t)bk*32 + j];
    red[grp][j] = v;
  }
  if (tid < 48) sW[tid] = W1[tid];
  if (tid < 16) sW[48+tid] = b1[tid];
  sW2t[tid] = W2[(tid & 15)*16 + (tid >> 4)];   // sW2t[c2*16+j] = W2[j][c2]
  __syncthreads();
  if (tid < 32) {
    double v = 0.0;
    for (int g = 0; g < 8; ++g) v += red[g][tid];
    red[0][tid] = v;
  }
  __syncthreads();
  if (tid < 16) {
    double S = red[0][tid], S2 = red[0][16 + tid];
    double m = S/262144.0, var = S2/262144.0 - m*m;
    double sc = (double)g1[tid]/sqrt(var + 1e-5);
    fsc1[tid] = (float)sc;
    fsh1[tid] = (float)((double)be1[tid] - m*sc);
  }
  __syncthreads();
  const float4* src4 = (const float4*)(drel + ((size_t)blockIdx.x*1024 + tid*4)*3);
  float a[12];
#pragma unroll
  for (int q = 0; q < 3; ++q) { float4 t = src4[q]; a[q*4]=t.x; a[q*4+1]=t.y; a[q*4+2]=t.z; a[q*4+3]=t.w; }
  float s[16], s2[16];
#pragma unroll
  for (int c = 0; c < 16; ++c) { s[c] = 0.f; s2[c] = 0.f; }
#pragma unroll
  for (int i = 0; i < 4; ++i) {
    float a0 = a[i*3], a1 = a[i*3+1], a2 = a[i*3+2];
    float y[16];
#pragma unroll
    for (int c = 0; c < 16; ++c) {
      float v = a0*sW[c] + a1*sW[16+c] + a2*sW[32+c] + sW[48+c];
      y[c] = eluf(v)*fsc1[c] + fsh1[c];
    }
#pragma unroll
    for (int c2 = 0; c2 < 16; ++c2) {
      float v = b2[c2];
      const float4* w4 = (const float4*)&sW2t[c2*16];
#pragma unroll
      for (int j4 = 0; j4 < 4; ++j4) {
        float4 ww = w4[j4];
        v += y[j4*4]*ww.x + y[j4*4+1]*ww.y + y[j4*4+2]*ww.z + y[j4*4+3]*ww.w;
      }
      float e = eluf(v);
      s[c2] += e; s2[c2] += e*e;
    }
  }
  __shared__ float wred[4][32];
  int lane = tid & 63, wav = tid >> 6;
#pragma unroll
  for (int j = 0; j < 32; ++j) {
    float v = (j < 16) ? s[j] : s2[j-16];
    for (int sh = 32; sh > 0; sh >>= 1) v += __shfl_down(v, sh);
    if (lane == 0) wred[wav][j] = v;
  }
  __syncthreads();
  if (tid < 32)
    part2[(size_t)blockIdx.x*32 + tid] =
      (double)wred[0][tid] + (double)wred[1][tid] + (double)wred[2][tid] + (double)wred[3][tid];
}

// ---------------- mlp2 linear: f32 compute, f32 store, f64 accum ------------
__global__ __launch_bounds__(256) void s2l_kernel(const float* __restrict__ drel,
                                                  const float* __restrict__ Wl,
                                                  const float* __restrict__ bl,
                                                  float* __restrict__ tL,
                                                  double* __restrict__ partL) {
  __shared__ float srows[128*48];
  int tid = threadIdx.x;
  const float* src = drel + (size_t)blockIdx.x * 6144;
  for (int i = tid; i < 6144; i += 256) srows[i] = src[i];
  float w[48];
#pragma unroll
  for (int j = 0; j < 48; ++j) w[j] = Wl[j*256 + tid];
  float bias = bl[tid];
  __syncthreads();
  double s = 0.0, s2 = 0.0;
  for (int r = 0; r < 128; ++r) {
    float v = bias;
    const float4* sr = (const float4*)&srows[r*48];
#pragma unroll
    for (int j4 = 0; j4 < 12; ++j4) {
      float4 a4 = sr[j4];
      v += a4.x*w[j4*4] + a4.y*w[j4*4+1] + a4.z*w[j4*4+2] + a4.w*w[j4*4+3];
    }
    float e = eluf(v);
    tL[(size_t)(blockIdx.x*128 + r)*256 + tid] = e;
    double ed = (double)e;
    s += ed; s2 += ed*ed;
  }
  partL[(size_t)blockIdx.x*512 + tid]       = s;
  partL[(size_t)blockIdx.x*512 + 256 + tid] = s2;
}

// ---------------- grouped conv (A: elu, B: none); folds prev BN reduce ------
template<int DO_ELU>
__global__ __launch_bounds__(256) void s2conv_kernel(const double* __restrict__ partIn,
                                                     const float* __restrict__ gIn,
                                                     const float* __restrict__ beIn,
                                                     const float* __restrict__ Wc,
                                                     const float* __restrict__ bc,
                                                     const float* __restrict__ tIn,
                                                     float* __restrict__ tOut,
                                                     double* __restrict__ partOut) {
  int tid = threadIdx.x;
  double S = 0.0, S2 = 0.0;
  for (int bk = 0; bk < 128; ++bk) {
    S  += partIn[(size_t)bk*512 + tid];
    S2 += partIn[(size_t)bk*512 + 256 + tid];
  }
  double m = S/16384.0, var = S2/16384.0 - m*m;
  double scd = (double)gIn[tid]/sqrt(var + 1e-5);
  float sc = (float)scd, sh = (float)((double)beIn[tid] - m*scd);
  int g = tid >> 4, o = tid & 15;
  float w[16];
#pragma unroll
  for (int k = 0; k < 16; ++k) w[k] = Wc[g*256 + o*16 + k];
  float bias = bc[tid];
  __shared__ float sin_[16*256];
  double s = 0.0, s2 = 0.0;
  const float* base = tIn + (size_t)blockIdx.x*128*256;
  float* outb = tOut + (size_t)blockIdx.x*128*256;
  for (int chunk = 0; chunk < 8; ++chunk) {
    __syncthreads();
    for (int rr = 0; rr < 16; ++rr)
      sin_[rr*256 + tid] = base[(chunk*16 + rr)*256 + tid]*sc + sh;
    __syncthreads();
    for (int rr = 0; rr < 16; ++rr) {
      float v = bias;
      const float4* row4 = (const float4*)&sin_[rr*256 + g*16];
#pragma unroll
      for (int k4 = 0; k4 < 4; ++k4) {
        float4 a4 = row4[k4];
        v += a4.x*w[k4*4] + a4.y*w[k4*4+1] + a4.z*w[k4*4+2] + a4.w*w[k4*4+3];
      }
      float e = DO_ELU ? eluf(v) : v;
      outb[(chunk*16 + rr)*256 + tid] = e;
      double ed = (double)e;
      s += ed; s2 += ed*ed;
    }
  }
  partOut[(size_t)blockIdx.x*512 + tid]       = s;
  partOut[(size_t)blockIdx.x*512 + 256 + tid] = s2;
}

// ---------------- bn1/bn2/bnB -> f32 scale/shift ----------------------------
__global__ void bnall_kernel(const double* __restrict__ part1,
                             const double* __restrict__ part2,
                             const double* __restrict__ partB,
                             const float* __restrict__ g1, const float* __restrict__ be1,
                             const float* __restrict__ g2, const float* __restrict__ be2,
                             const float* __restrict__ gB, const float* __restrict__ beB,
                             float* __restrict__ bnp) {
  int tid = threadIdx.x;
  if (tid < 32) {
    int c = tid & 15;
    const double* P = (tid < 16) ? part1 : part2;
    double S = 0.0, S2 = 0.0;
    for (int bk = 0; bk < 256; ++bk) { S += P[(size_t)bk*32 + c]; S2 += P[(size_t)bk*32 + 16 + c]; }
    double m = S/262144.0, var = S2/262144.0 - m*m;
    const float* g  = (tid < 16) ? g1 : g2;
    const float* be = (tid < 16) ? be1 : be2;
    double sc = (double)g[c]/sqrt(var + 1e-5);
    int off = (tid < 16) ? 0 : 32;
    bnp[off + c]      = (float)sc;
    bnp[off + 16 + c] = (float)((double)be[c] - m*sc);
  }
  {
    double S = 0.0, S2 = 0.0;
    for (int bk = 0; bk < 128; ++bk) { S += partB[(size_t)bk*512 + tid]; S2 += partB[(size_t)bk*512 + 256 + tid]; }
    double m = S/16384.0, var = S2/16384.0 - m*m;
    double sc = (double)gB[tid]/sqrt(var + 1e-5);
    bnp[64 + tid]  = (float)sc;
    bnp[320 + tid] = (float)((double)beB[tid] - m*sc);
  }
}

// ---------------- final: 2 points/block, xt in regs fused with dwconv -------
__global__ __launch_bounds__(256) void final_kernel(const float* __restrict__ x,
                                                    const int* __restrict__ idxbuf,
                                                    const float* __restrict__ drel,
                                                    const float* __restrict__ tB,
                                                    const float* __restrict__ bnp,
                                                    const float* __restrict__ W1,
                                                    const float* __restrict__ b1,
                                                    const float* __restrict__ W2,
                                                    const float* __restrict__ b2,
                                                    const float* __restrict__ Wd,
                                                    const float* __restrict__ bd,
                                                    const float* __restrict__ Wo,
                                                    const float* __restrict__ bo,
                                                    float* __restrict__ out) {
  int tid = threadIdx.x;
  int bn0 = blockIdx.x*2;
  int b = bn0 >> 11;
  __shared__ float sbn1[32], sbn2[32];
  __shared__ float sBs[256], sBh[256];
  __shared__ int   sidx[32];
  __shared__ float sdrel[96];
  __shared__ float sW1[48], sb1[16], sb2[16];
  __shared__ float sW2t[256];
  __shared__ float tmat[512];
  __shared__ float hs[2][16][16];
  __shared__ float xs[2][80][16];
  __shared__ float ovs[2][160];
  if (tid < 32) { sbn1[tid] = bnp[tid]; sbn2[tid] = bnp[32 + tid]; }
  sBs[tid] = bnp[64 + tid];
  sBh[tid] = bnp[320 + tid];
  if (tid < 32) sidx[tid] = idxbuf[bn0*16 + tid];
  if (tid < 96) sdrel[tid] = drel[(size_t)bn0*48 + tid];
  if (tid < 48) sW1[tid] = W1[tid];
  if (tid < 16) { sb1[tid] = b1[tid]; sb2[tid] = b2[tid]; }
  sW2t[tid] = W2[(tid & 15)*16 + (tid >> 4)];
  __syncthreads();
  for (int i = tid; i < 512; i += 256) {
    int c = i & 255;
    tmat[i] = tB[(size_t)bn0*256 + i]*sBs[c] + sBh[c];
  }
  for (int i = tid; i < 512; i += 256) {
    int pt = i >> 8, k = (i >> 4) & 15, c = i & 15;
    float a0 = sdrel[pt*48 + k*3], a1 = sdrel[pt*48 + k*3 + 1], a2 = sdrel[pt*48 + k*3 + 2];
    float v = a0*sW1[c] + a1*sW1[16+c] + a2*sW1[32+c] + sb1[c];
    hs[pt][k][c] = eluf(v)*sbn1[c] + sbn1[16+c];
  }
  __syncthreads();
  for (int i = tid; i < 512; i += 256) {
    int pt = i >> 8, k = (i >> 4) & 15, c2 = i & 15;
    float v = sb2[c2];
    const float4* w4 = (const float4*)&sW2t[c2*16];
    float* hrow = &hs[pt][k][0];
#pragma unroll
    for (int j4 = 0; j4 < 4; ++j4) {
      float4 ww = w4[j4];
      v += hrow[j4*4]*ww.x + hrow[j4*4+1]*ww.y + hrow[j4*4+2]*ww.z + hrow[j4*4+3]*ww.w;
    }
    xs[pt][c2][k] = eluf(v)*sbn2[c2] + sbn2[16+c2];
  }
  for (int i = tid; i < 2048; i += 256) {
    int pt = i >> 10, k = (i >> 6) & 15, c = i & 63;
    xs[pt][16 + c][k] = x[((size_t)b*NN + sidx[pt*16 + k])*64 + c];
  }
  __syncthreads();
  if (tid < 160) {
    int pt = (tid >= 80) ? 1 : 0;
    int c = tid - pt*80;
    float xtr[16];
#pragma unroll
    for (int o = 0; o < 16; ++o) {
      float v = 0.f;
#pragma unroll
      for (int k = 0; k < 16; ++k) v += xs[pt][c][k]*tmat[pt*256 + k*16 + o];
      xtr[o] = v;
    }
    float v0 = bd[c*2], v1 = bd[c*2 + 1];
#pragma unroll
    for (int k = 0; k < 16; ++k) {
      v0 += xtr[k]*Wd[c*32 + k];
      v1 += xtr[k]*Wd[c*32 + 16 + k];
    }
    ovs[pt][c*2]     = v0;
    ovs[pt][c*2 + 1] = v1;
  }
  __syncthreads();
  {
    int pt0 = tid >> 7, co = tid & 127;
    float v = bo[co];
    for (int i = 0; i < 160; ++i) v += ovs[pt0][i]*Wo[i*128 + co];
    out[(size_t)(bn0 + pt0)*128 + co] = v;
  }
}

extern "C" void kernel_launch(void* const* d_in, const int* in_sizes, int n_in,
                              void* d_out, int out_size, void* d_ws, size_t ws_size,
                              hipStream_t stream) {
  (void)in_sizes; (void)n_in; (void)out_size; (void)ws_size;
  const float* x   = (const float*)d_in[0];
  const float* pos = (const float*)d_in[1];
  const float* W1  = (const float*)d_in[2];
  const float* b1  = (const float*)d_in[3];
  const float* g1  = (const float*)d_in[4];
  const float* be1 = (const float*)d_in[5];
  const float* W2  = (const float*)d_in[6];
  const float* b2  = (const float*)d_in[7];
  const float* g2  = (const float*)d_in[8];
  const float* be2 = (const float*)d_in[9];
  const float* Wl  = (const float*)d_in[10];
  const float* bl  = (const float*)d_in[11];
  const float* gl  = (const float*)d_in[12];
  const float* bel = (const float*)d_in[13];
  const float* WcA = (const float*)d_in[14];
  const float* bcA = (const float*)d_in[15];
  const float* gA  = (const float*)d_in[16];
  const float* beA = (const float*)d_in[17];
  const float* WcB = (const float*)d_in[18];
  const float* bcB = (const float*)d_in[19];
  const float* gB  = (const float*)d_in[20];
  const float* beB = (const float*)d_in[21];
  const float* Wd  = (const float*)d_in[22];
  const float* bd  = (const float*)d_in[23];
  const float* Wo  = (const float*)d_in[24];
  const float* bo  = (const float*)d_in[25];
  float* out = (float*)d_out;

  char* ws = (char*)d_ws;
  int*    idxbuf = (int*)ws;                                   // 1 MB
  float*  drel   = (float*)(ws + (1u<<20));                    // 3 MB
  float*  bufX   = (float*)(ws + (4u<<20));                    // 16 MB
  float*  bufY   = (float*)(ws + (20u<<20));                   // 16 MB
  double* part1  = (double*)(ws + (36u<<20));                  // 64 KB
  double* part2  = (double*)(ws + (36u<<20) + (64u<<10));      // 64 KB
  double* partL  = (double*)(ws + (36u<<20) + (128u<<10));     // 512 KB
  double* partA  = (double*)(ws + (36u<<20) + (640u<<10));     // 512 KB
  double* partB  = (double*)(ws + (36u<<20) + (1152u<<10));    // 512 KB
  float*  bnp    = (float*)(ws + (36u<<20) + (1664u<<10));     // 2.3 KB

  knn_kernel<<<dim3(4096), dim3(256), 0, stream>>>(pos, idxbuf, drel);
  s1a_kernel<<<dim3(256), dim3(256), 0, stream>>>(drel, W1, b1, part1);
  s1b_kernel<<<dim3(256), dim3(256), 0, stream>>>(drel, W1, b1, W2, b2, part1, g1, be1, part2);
  s2l_kernel<<<dim3(128), dim3(256), 0, stream>>>(drel, Wl, bl, bufX, partL);
  s2conv_kernel<1><<<dim3(128), dim3(256), 0, stream>>>(partL, gl, bel, WcA, bcA, bufX, bufY, partA);
  s2conv_kernel<0><<<dim3(128), dim3(256), 0, stream>>>(partA, gA, beA, WcB, bcB, bufY, bufX, partB);
  bnall_kernel<<<dim3(1), dim3(256), 0, stream>>>(part1, part2, partB, g1, be1, g2, be2, gB, beB, bnp);
  final_kernel<<<dim3(8192), dim3(256), 0, stream>>>(x, idxbuf, drel, bufX, bnp,
                                                     W1, b1, W2, b2, Wd, bd, Wo, bo, out);
}

// Round 10
// 370.203 us; speedup vs baseline: 3.3545x; 1.1214x over previous
//
#include <hip/hip_runtime.h>
#include <math.h>

#define NN 2048
#define KNbr 16
#define BNpts 16384
#define BNKr  262144

__device__ __forceinline__ float eluf(float v) { return v > 0.f ? v : expm1f(v); }

// ---------------- KNN: ONE WAVE PER QUERY, f64-min key selection. -----------
// Key construction: uf = bits ^ (bits<0 ? 0x7FFFFFFF : 0); kd =
// __hiloint2double(uf, m). For d2 >= 0 (bits MSB=0): uf = bits, sign(kd)=0,
// and positive f64 bit patterns are ORDER-ISOMORPHIC to their u64 patterns =>
// fmin == u64-min == lexicographic (d2, m) min (round 7/8/9's validated
// invariant). d2=+0 -> positive denormal (CDNA preserves f64 denorms).
// At most one negative-d2 candidate/query (self rounding); it maps to a
// negative f64 => correctly ranks first. NaN patterns require |d2| in f32
// denormal range — impossible for N(0,1) coords (cancellation floor
// ~2^-23*|sq| >> 1e-38). Sentinel +inf (not NaN) always loses fmin.
// fmin returns the smaller operand bit-exactly (distinct, no NaN) => index
// rides in the low word. Owner: m = s*64+lane => lane fi&63, slot fi>>6.
__global__ __launch_bounds__(256) void knn_kernel(const float* __restrict__ pos,
                                                  int* __restrict__ idxout,
                                                  float* __restrict__ drel) {
  int wav = threadIdx.x >> 6, lane = threadIdx.x & 63;
  int bn = blockIdx.x*4 + wav;
  int b = bn >> 11, n = bn & (NN - 1);
  const float* pb = pos + (size_t)b * NN * 3;
  float qx = pb[n*3], qy = pb[n*3+1], qz = pb[n*3+2];
  float sqn = __fadd_rn(__fadd_rn(__fmul_rn(qx,qx), __fmul_rn(qy,qy)), __fmul_rn(qz,qz));
  double kreg[32];
#pragma unroll
  for (int s = 0; s < 32; ++s) {
    int m = s*64 + lane;
    float px = pb[m*3], py = pb[m*3+1], pz = pb[m*3+2];
    float sqm = __fadd_rn(__fadd_rn(__fmul_rn(px,px), __fmul_rn(py,py)), __fmul_rn(pz,pz));
    float dot = __fmaf_rn(qz, pz, __fmaf_rn(qy, py, __fmul_rn(qx, px)));
    float d2  = __fsub_rn(__fadd_rn(sqn, sqm), __fmul_rn(2.0f, dot));
    unsigned int bits = __float_as_uint(d2);
    unsigned int uf = bits ^ (((unsigned int)((int)bits >> 31)) >> 1);
    kreg[s] = __hiloint2double((int)uf, m);
  }
  const double KINF = __hiloint2double(0x7FF00000, 0);
  for (int k = 0; k < KNbr; ++k) {
    double g0 = fmin(fmin(kreg[0],  kreg[1]),  fmin(kreg[2],  kreg[3]));
    double g1 = fmin(fmin(kreg[4],  kreg[5]),  fmin(kreg[6],  kreg[7]));
    double g2 = fmin(fmin(kreg[8],  kreg[9]),  fmin(kreg[10], kreg[11]));
    double g3 = fmin(fmin(kreg[12], kreg[13]), fmin(kreg[14], kreg[15]));
    double g4 = fmin(fmin(kreg[16], kreg[17]), fmin(kreg[18], kreg[19]));
    double g5 = fmin(fmin(kreg[20], kreg[21]), fmin(kreg[22], kreg[23]));
    double g6 = fmin(fmin(kreg[24], kreg[25]), fmin(kreg[26], kreg[27]));
    double g7 = fmin(fmin(kreg[28], kreg[29]), fmin(kreg[30], kreg[31]));
    double bk = fmin(fmin(fmin(g0, g1), fmin(g2, g3)),
                     fmin(fmin(g4, g5), fmin(g6, g7)));
#pragma unroll
    for (int off = 32; off > 0; off >>= 1) {
      double ok = __shfl_xor(bk, off);
      bk = fmin(bk, ok);
    }
    int fi = __double2loint(bk);
    if (lane == 0) {
      idxout[bn*KNbr + k] = fi;
      drel[(size_t)(bn*KNbr + k)*3 + 0] = __fsub_rn(qx, pb[fi*3+0]);
      drel[(size_t)(bn*KNbr + k)*3 + 1] = __fsub_rn(qy, pb[fi*3+1]);
      drel[(size_t)(bn*KNbr + k)*3 + 2] = __fsub_rn(qz, pb[fi*3+2]);
    }
    if ((fi & 63) == lane) {
      int wsl = fi >> 6;
#pragma unroll
      for (int s = 0; s < 32; ++s) if (s == wsl) kreg[s] = KINF;
    }
  }
}

// ---------------- mlp1 layer-1 stats (f32 compute, f64 partial store) -------
__global__ __launch_bounds__(256) void s1a_kernel(const float* __restrict__ drel,
                                                  const float* __restrict__ W1,
                                                  const float* __restrict__ b1,
                                                  double* __restrict__ part1) {
  __shared__ float sW[64];
  int tid = threadIdx.x;
  if (tid < 48) sW[tid] = W1[tid];
  if (tid < 16) sW[48+tid] = b1[tid];
  __syncthreads();
  const float4* src4 = (const float4*)(drel + ((size_t)blockIdx.x*1024 + tid*4)*3);
  float a[12];
#pragma unroll
  for (int q = 0; q < 3; ++q) { float4 t = src4[q]; a[q*4]=t.x; a[q*4+1]=t.y; a[q*4+2]=t.z; a[q*4+3]=t.w; }
  float s[16], s2[16];
#pragma unroll
  for (int c = 0; c < 16; ++c) { s[c] = 0.f; s2[c] = 0.f; }
#pragma unroll
  for (int i = 0; i < 4; ++i) {
    float a0 = a[i*3], a1 = a[i*3+1], a2 = a[i*3+2];
#pragma unroll
    for (int c = 0; c < 16; ++c) {
      float v = a0*sW[c] + a1*sW[16+c] + a2*sW[32+c] + sW[48+c];
      float e = eluf(v);
      s[c] += e; s2[c] += e*e;
    }
  }
  __shared__ float wred[4][32];
  int lane = tid & 63, wav = tid >> 6;
#pragma unroll
  for (int j = 0; j < 32; ++j) {
    float v = (j < 16) ? s[j] : s2[j-16];
    for (int sh = 32; sh > 0; sh >>= 1) v += __shfl_down(v, sh);
    if (lane == 0) wred[wav][j] = v;
  }
  __syncthreads();
  if (tid < 32)
    part1[(size_t)blockIdx.x*32 + tid] =
      (double)wred[0][tid] + (double)wred[1][tid] + (double)wred[2][tid] + (double)wred[3][tid];
}

// ---------------- mlp1 layer-2 stats (folds bn1 reduce; f32 compute) --------
__global__ __launch_bounds__(256) void s1b_kernel(const float* __restrict__ drel,
                                                  const float* __restrict__ W1,
                                                  const float* __restrict__ b1,
                                                  const float* __restrict__ W2,
                                                  const float* __restrict__ b2,
                                                  const double* __restrict__ part1,
                                                  const float* __restrict__ g1,
                                                  const float* __restrict__ be1,
                                                  double* __restrict__ part2) {
  int tid = threadIdx.x;
  __shared__ double red[8][32];
  __shared__ float fsc1[16], fsh1[16];
  __shared__ float sW[64];
  __shared__ float sW2t[256];
  {
    int j = tid & 31, grp = tid >> 5;
    double v = 0.0;
    for (int bk = grp; bk < 256; bk += 8) v += part1[(size_t)bk*32 + j];
    red[grp][j] = v;
  }
  if (tid < 48) sW[tid] = W1[tid];
  if (tid < 16) sW[48+tid] = b1[tid];
  sW2t[tid] = W2[(tid & 15)*16 + (tid >> 4)];   // sW2t[c2*16+j] = W2[j][c2]
  __syncthreads();
  if (tid < 32) {
    double v = 0.0;
    for (int g = 0; g < 8; ++g) v += red[g][tid];
    red[0][tid] = v;
  }
  __syncthreads();
  if (tid < 16) {
    double S = red[0][tid], S2 = red[0][16 + tid];
    double m = S/262144.0, var = S2/262144.0 - m*m;
    double sc = (double)g1[tid]/sqrt(var + 1e-5);
    fsc1[tid] = (float)sc;
    fsh1[tid] = (float)((double)be1[tid] - m*sc);
  }
  __syncthreads();
  const float4* src4 = (const float4*)(drel + ((size_t)blockIdx.x*1024 + tid*4)*3);
  float a[12];
#pragma unroll
  for (int q = 0; q < 3; ++q) { float4 t = src4[q]; a[q*4]=t.x; a[q*4+1]=t.y; a[q*4+2]=t.z; a[q*4+3]=t.w; }
  float s[16], s2[16];
#pragma unroll
  for (int c = 0; c < 16; ++c) { s[c] = 0.f; s2[c] = 0.f; }
#pragma unroll
  for (int i = 0; i < 4; ++i) {
    float a0 = a[i*3], a1 = a[i*3+1], a2 = a[i*3+2];
    float y[16];
#pragma unroll
    for (int c = 0; c < 16; ++c) {
      float v = a0*sW[c] + a1*sW[16+c] + a2*sW[32+c] + sW[48+c];
      y[c] = eluf(v)*fsc1[c] + fsh1[c];
    }
#pragma unroll
    for (int c2 = 0; c2 < 16; ++c2) {
      float v = b2[c2];
      const float4* w4 = (const float4*)&sW2t[c2*16];
#pragma unroll
      for (int j4 = 0; j4 < 4; ++j4) {
        float4 ww = w4[j4];
        v += y[j4*4]*ww.x + y[j4*4+1]*ww.y + y[j4*4+2]*ww.z + y[j4*4+3]*ww.w;
      }
      float e = eluf(v);
      s[c2] += e; s2[c2] += e*e;
    }
  }
  __shared__ float wred[4][32];
  int lane = tid & 63, wav = tid >> 6;
#pragma unroll
  for (int j = 0; j < 32; ++j) {
    float v = (j < 16) ? s[j] : s2[j-16];
    for (int sh = 32; sh > 0; sh >>= 1) v += __shfl_down(v, sh);
    if (lane == 0) wred[wav][j] = v;
  }
  __syncthreads();
  if (tid < 32)
    part2[(size_t)blockIdx.x*32 + tid] =
      (double)wred[0][tid] + (double)wred[1][tid] + (double)wred[2][tid] + (double)wred[3][tid];
}

// ---------------- mlp2 linear: 256 blocks x 64 rows -------------------------
__global__ __launch_bounds__(256) void s2l_kernel(const float* __restrict__ drel,
                                                  const float* __restrict__ Wl,
                                                  const float* __restrict__ bl,
                                                  float* __restrict__ tL,
                                                  double* __restrict__ partL) {
  __shared__ float srows[64*48];
  int tid = threadIdx.x;
  const float* src = drel + (size_t)blockIdx.x * 3072;
  for (int i = tid; i < 3072; i += 256) srows[i] = src[i];
  float w[48];
#pragma unroll
  for (int j = 0; j < 48; ++j) w[j] = Wl[j*256 + tid];
  float bias = bl[tid];
  __syncthreads();
  double s = 0.0, s2 = 0.0;
  for (int r = 0; r < 64; ++r) {
    float v = bias;
    const float4* sr = (const float4*)&srows[r*48];
#pragma unroll
    for (int j4 = 0; j4 < 12; ++j4) {
      float4 a4 = sr[j4];
      v += a4.x*w[j4*4] + a4.y*w[j4*4+1] + a4.z*w[j4*4+2] + a4.w*w[j4*4+3];
    }
    float e = eluf(v);
    tL[(size_t)(blockIdx.x*64 + r)*256 + tid] = e;
    double ed = (double)e;
    s += ed; s2 += ed*ed;
  }
  partL[(size_t)blockIdx.x*512 + tid]       = s;
  partL[(size_t)blockIdx.x*512 + 256 + tid] = s2;
}

// ---------------- grouped conv, IN-PLACE, 256 blocks x 64 rows --------------
// In-place safety: each block owns rows [64b, 64b+64) exclusively; each
// 16-row chunk is fully staged into LDS (with BN applied) before any write
// to those rows; later chunks touch disjoint rows.
template<int DO_ELU>
__global__ __launch_bounds__(256) void s2conv_kernel(const double* __restrict__ partIn,
                                                     const float* __restrict__ gIn,
                                                     const float* __restrict__ beIn,
                                                     const float* __restrict__ Wc,
                                                     const float* __restrict__ bc,
                                                     float* __restrict__ tBuf,
                                                     double* __restrict__ partOut) {
  int tid = threadIdx.x;
  double S = 0.0, S2 = 0.0;
  for (int bk = 0; bk < 256; ++bk) {
    S  += partIn[(size_t)bk*512 + tid];
    S2 += partIn[(size_t)bk*512 + 256 + tid];
  }
  double m = S/16384.0, var = S2/16384.0 - m*m;
  double scd = (double)gIn[tid]/sqrt(var + 1e-5);
  float sc = (float)scd, sh = (float)((double)beIn[tid] - m*scd);
  int g = tid >> 4, o = tid & 15;
  float w[16];
#pragma unroll
  for (int k = 0; k < 16; ++k) w[k] = Wc[g*256 + o*16 + k];
  float bias = bc[tid];
  __shared__ float sin_[16*256];
  double s = 0.0, s2 = 0.0;
  float* buf = tBuf + (size_t)blockIdx.x*64*256;
  for (int chunk = 0; chunk < 4; ++chunk) {
    __syncthreads();
    for (int rr = 0; rr < 16; ++rr)
      sin_[rr*256 + tid] = buf[(chunk*16 + rr)*256 + tid]*sc + sh;
    __syncthreads();
    for (int rr = 0; rr < 16; ++rr) {
      float v = bias;
      const float4* row4 = (const float4*)&sin_[rr*256 + g*16];
#pragma unroll
      for (int k4 = 0; k4 < 4; ++k4) {
        float4 a4 = row4[k4];
        v += a4.x*w[k4*4] + a4.y*w[k4*4+1] + a4.z*w[k4*4+2] + a4.w*w[k4*4+3];
      }
      float e = DO_ELU ? eluf(v) : v;
      buf[(chunk*16 + rr)*256 + tid] = e;
      double ed = (double)e;
      s += ed; s2 += ed*ed;
    }
  }
  partOut[(size_t)blockIdx.x*512 + tid]       = s;
  partOut[(size_t)blockIdx.x*512 + 256 + tid] = s2;
}

// ---------------- bn1/bn2/bnB -> f32 scale/shift ----------------------------
__global__ void bnall_kernel(const double* __restrict__ part1,
                             const double* __restrict__ part2,
                             const double* __restrict__ partB,
                             const float* __restrict__ g1, const float* __restrict__ be1,
                             const float* __restrict__ g2, const float* __restrict__ be2,
                             const float* __restrict__ gB, const float* __restrict__ beB,
                             float* __restrict__ bnp) {
  int tid = threadIdx.x;
  if (tid < 32) {
    int c = tid & 15;
    const double* P = (tid < 16) ? part1 : part2;
    double S = 0.0, S2 = 0.0;
    for (int bk = 0; bk < 256; ++bk) { S += P[(size_t)bk*32 + c]; S2 += P[(size_t)bk*32 + 16 + c]; }
    double m = S/262144.0, var = S2/262144.0 - m*m;
    const float* g  = (tid < 16) ? g1 : g2;
    const float* be = (tid < 16) ? be1 : be2;
    double sc = (double)g[c]/sqrt(var + 1e-5);
    int off = (tid < 16) ? 0 : 32;
    bnp[off + c]      = (float)sc;
    bnp[off + 16 + c] = (float)((double)be[c] - m*sc);
  }
  {
    double S = 0.0, S2 = 0.0;
    for (int bk = 0; bk < 256; ++bk) { S += partB[(size_t)bk*512 + tid]; S2 += partB[(size_t)bk*512 + 256 + tid]; }
    double m = S/16384.0, var = S2/16384.0 - m*m;
    double sc = (double)gB[tid]/sqrt(var + 1e-5);
    bnp[64 + tid]  = (float)sc;
    bnp[320 + tid] = (float)((double)beB[tid] - m*sc);
  }
}

// ---------------- final: 2 points/block, xt in regs fused with dwconv -------
__global__ __launch_bounds__(256) void final_kernel(const float* __restrict__ x,
                                                    const int* __restrict__ idxbuf,
                                                    const float* __restrict__ drel,
                                                    const float* __restrict__ tB,
                                                    const float* __restrict__ bnp,
                                                    const float* __restrict__ W1,
                                                    const float* __restrict__ b1,
                                                    const float* __restrict__ W2,
                                                    const float* __restrict__ b2,
                                                    const float* __restrict__ Wd,
                                                    const float* __restrict__ bd,
                                                    const float* __restrict__ Wo,
                                                    const float* __restrict__ bo,
                                                    float* __restrict__ out) {
  int tid = threadIdx.x;
  int bn0 = blockIdx.x*2;
  int b = bn0 >> 11;
  __shared__ float sbn1[32], sbn2[32];
  __shared__ float sBs[256], sBh[256];
  __shared__ int   sidx[32];
  __shared__ float sdrel[96];
  __shared__ float sW1[48], sb1[16], sb2[16];
  __shared__ float sW2t[256];
  __shared__ float tmat[512];
  __shared__ float hs[2][16][16];
  __shared__ float xs[2][80][16];
  __shared__ float ovs[2][160];
  if (tid < 32) { sbn1[tid] = bnp[tid]; sbn2[tid] = bnp[32 + tid]; }
  sBs[tid] = bnp[64 + tid];
  sBh[tid] = bnp[320 + tid];
  if (tid < 32) sidx[tid] = idxbuf[bn0*16 + tid];
  if (tid < 96) sdrel[tid] = drel[(size_t)bn0*48 + tid];
  if (tid < 48) sW1[tid] = W1[tid];
  if (tid < 16) { sb1[tid] = b1[tid]; sb2[tid] = b2[tid]; }
  sW2t[tid] = W2[(tid & 15)*16 + (tid >> 4)];
  __syncthreads();
  for (int i = tid; i < 512; i += 256) {
    int c = i & 255;
    tmat[i] = tB[(size_t)bn0*256 + i]*sBs[c] + sBh[c];
  }
  for (int i = tid; i < 512; i += 256) {
    int pt = i >> 8, k = (i >> 4) & 15, c = i & 15;
    float a0 = sdrel[pt*48 + k*3], a1 = sdrel[pt*48 + k*3 + 1], a2 = sdrel[pt*48 + k*3 + 2];
    float v = a0*sW1[c] + a1*sW1[16+c] + a2*sW1[32+c] + sb1[c];
    hs[pt][k][c] = eluf(v)*sbn1[c] + sbn1[16+c];
  }
  __syncthreads();
  for (int i = tid; i < 512; i += 256) {
    int pt = i >> 8, k = (i >> 4) & 15, c2 = i & 15;
    float v = sb2[c2];
    const float4* w4 = (const float4*)&sW2t[c2*16];
    float* hrow = &hs[pt][k][0];
#pragma unroll
    for (int j4 = 0; j4 < 4; ++j4) {
      float4 ww = w4[j4];
      v += hrow[j4*4]*ww.x + hrow[j4*4+1]*ww.y + hrow[j4*4+2]*ww.z + hrow[j4*4+3]*ww.w;
    }
    xs[pt][c2][k] = eluf(v)*sbn2[c2] + sbn2[16+c2];
  }
  for (int i = tid; i < 2048; i += 256) {
    int pt = i >> 10, k = (i >> 6) & 15, c = i & 63;
    xs[pt][16 + c][k] = x[((size_t)b*NN + sidx[pt*16 + k])*64 + c];
  }
  __syncthreads();
  if (tid < 160) {
    int pt = (tid >= 80) ? 1 : 0;
    int c = tid - pt*80;
    float xtr[16];
#pragma unroll
    for (int o = 0; o < 16; ++o) {
      float v = 0.f;
#pragma unroll
      for (int k = 0; k < 16; ++k) v += xs[pt][c][k]*tmat[pt*256 + k*16 + o];
      xtr[o] = v;
    }
    float v0 = bd[c*2], v1 = bd[c*2 + 1];
#pragma unroll
    for (int k = 0; k < 16; ++k) {
      v0 += xtr[k]*Wd[c*32 + k];
      v1 += xtr[k]*Wd[c*32 + 16 + k];
    }
    ovs[pt][c*2]     = v0;
    ovs[pt][c*2 + 1] = v1;
  }
  __syncthreads();
  {
    int pt0 = tid >> 7, co = tid & 127;
    float v = bo[co];
    for (int i = 0; i < 160; ++i) v += ovs[pt0][i]*Wo[i*128 + co];
    out[(size_t)(bn0 + pt0)*128 + co] = v;
  }
}

extern "C" void kernel_launch(void* const* d_in, const int* in_sizes, int n_in,
                              void* d_out, int out_size, void* d_ws, size_t ws_size,
                              hipStream_t stream) {
  (void)in_sizes; (void)n_in; (void)out_size; (void)ws_size;
  const float* x   = (const float*)d_in[0];
  const float* pos = (const float*)d_in[1];
  const float* W1  = (const float*)d_in[2];
  const float* b1  = (const float*)d_in[3];
  const float* g1  = (const float*)d_in[4];
  const float* be1 = (const float*)d_in[5];
  const float* W2  = (const float*)d_in[6];
  const float* b2  = (const float*)d_in[7];
  const float* g2  = (const float*)d_in[8];
  const float* be2 = (const float*)d_in[9];
  const float* Wl  = (const float*)d_in[10];
  const float* bl  = (const float*)d_in[11];
  const float* gl  = (const float*)d_in[12];
  const float* bel = (const float*)d_in[13];
  const float* WcA = (const float*)d_in[14];
  const float* bcA = (const float*)d_in[15];
  const float* gA  = (const float*)d_in[16];
  const float* beA = (const float*)d_in[17];
  const float* WcB = (const float*)d_in[18];
  const float* bcB = (const float*)d_in[19];
  const float* gB  = (const float*)d_in[20];
  const float* beB = (const float*)d_in[21];
  const float* Wd  = (const float*)d_in[22];
  const float* bd  = (const float*)d_in[23];
  const float* Wo  = (const float*)d_in[24];
  const float* bo  = (const float*)d_in[25];
  float* out = (float*)d_out;

  char* ws = (char*)d_ws;
  int*    idxbuf = (int*)ws;                                        // 1 MB
  float*  drel   = (float*)(ws + (1u<<20));                         // 3 MB
  float*  bufX   = (float*)(ws + (4u<<20));                         // 16 MB
  double* part1  = (double*)(ws + (20u<<20));                       // 64 KB
  double* part2  = (double*)(ws + (20u<<20) + (64u<<10));           // 64 KB
  double* partL  = (double*)(ws + (20u<<20) + (128u<<10));          // 1 MB
  double* partA  = (double*)(ws + (20u<<20) + (128u<<10) + (1u<<20)); // 1 MB
  double* partB  = (double*)(ws + (20u<<20) + (128u<<10) + (2u<<20)); // 1 MB
  float*  bnp    = (float*)(ws + (20u<<20) + (128u<<10) + (3u<<20));  // 2.3 KB

  knn_kernel<<<dim3(4096), dim3(256), 0, stream>>>(pos, idxbuf, drel);
  s1a_kernel<<<dim3(256), dim3(256), 0, stream>>>(drel, W1, b1, part1);
  s1b_kernel<<<dim3(256), dim3(256), 0, stream>>>(drel, W1, b1, W2, b2, part1, g1, be1, part2);
  s2l_kernel<<<dim3(256), dim3(256), 0, stream>>>(drel, Wl, bl, bufX, partL);
  s2conv_kernel<1><<<dim3(256), dim3(256), 0, stream>>>(partL, gl, bel, WcA, bcA, bufX, partA);
  s2conv_kernel<0><<<dim3(256), dim3(256), 0, stream>>>(partA, gA, beA, WcB, bcB, bufX, partB);
  bnall_kernel<<<dim3(1), dim3(256), 0, stream>>>(part1, part2, partB, g1, be1, g2, be2, gB, beB, bnp);
  final_kernel<<<dim3(8192), dim3(256), 0, stream>>>(x, idxbuf, drel, bufX, bnp,
                                                     W1, b1, W2, b2, Wd, bd, Wo, bo, out);
}

// Round 11
// 356.853 us; speedup vs baseline: 3.4799x; 1.0374x over previous
//
#include <hip/hip_runtime.h>
#include <math.h>

#define NN 2048
#define KNbr 16
#define BNpts 16384
#define BNKr  262144

__device__ __forceinline__ float eluf(float v) { return v > 0.f ? v : expm1f(v); }

// ---------------- KNN: ONE WAVE PER QUERY, f64-min key selection. -----------
// (validated round 10 — byte-identical)
__global__ __launch_bounds__(256) void knn_kernel(const float* __restrict__ pos,
                                                  int* __restrict__ idxout,
                                                  float* __restrict__ drel) {
  int wav = threadIdx.x >> 6, lane = threadIdx.x & 63;
  int bn = blockIdx.x*4 + wav;
  int b = bn >> 11, n = bn & (NN - 1);
  const float* pb = pos + (size_t)b * NN * 3;
  float qx = pb[n*3], qy = pb[n*3+1], qz = pb[n*3+2];
  float sqn = __fadd_rn(__fadd_rn(__fmul_rn(qx,qx), __fmul_rn(qy,qy)), __fmul_rn(qz,qz));
  double kreg[32];
#pragma unroll
  for (int s = 0; s < 32; ++s) {
    int m = s*64 + lane;
    float px = pb[m*3], py = pb[m*3+1], pz = pb[m*3+2];
    float sqm = __fadd_rn(__fadd_rn(__fmul_rn(px,px), __fmul_rn(py,py)), __fmul_rn(pz,pz));
    float dot = __fmaf_rn(qz, pz, __fmaf_rn(qy, py, __fmul_rn(qx, px)));
    float d2  = __fsub_rn(__fadd_rn(sqn, sqm), __fmul_rn(2.0f, dot));
    unsigned int bits = __float_as_uint(d2);
    unsigned int uf = bits ^ (((unsigned int)((int)bits >> 31)) >> 1);
    kreg[s] = __hiloint2double((int)uf, m);
  }
  const double KINF = __hiloint2double(0x7FF00000, 0);
  for (int k = 0; k < KNbr; ++k) {
    double g0 = fmin(fmin(kreg[0],  kreg[1]),  fmin(kreg[2],  kreg[3]));
    double g1 = fmin(fmin(kreg[4],  kreg[5]),  fmin(kreg[6],  kreg[7]));
    double g2 = fmin(fmin(kreg[8],  kreg[9]),  fmin(kreg[10], kreg[11]));
    double g3 = fmin(fmin(kreg[12], kreg[13]), fmin(kreg[14], kreg[15]));
    double g4 = fmin(fmin(kreg[16], kreg[17]), fmin(kreg[18], kreg[19]));
    double g5 = fmin(fmin(kreg[20], kreg[21]), fmin(kreg[22], kreg[23]));
    double g6 = fmin(fmin(kreg[24], kreg[25]), fmin(kreg[26], kreg[27]));
    double g7 = fmin(fmin(kreg[28], kreg[29]), fmin(kreg[30], kreg[31]));
    double bk = fmin(fmin(fmin(g0, g1), fmin(g2, g3)),
                     fmin(fmin(g4, g5), fmin(g6, g7)));
#pragma unroll
    for (int off = 32; off > 0; off >>= 1) {
      double ok = __shfl_xor(bk, off);
      bk = fmin(bk, ok);
    }
    int fi = __double2loint(bk);
    if (lane == 0) {
      idxout[bn*KNbr + k] = fi;
      drel[(size_t)(bn*KNbr + k)*3 + 0] = __fsub_rn(qx, pb[fi*3+0]);
      drel[(size_t)(bn*KNbr + k)*3 + 1] = __fsub_rn(qy, pb[fi*3+1]);
      drel[(size_t)(bn*KNbr + k)*3 + 2] = __fsub_rn(qz, pb[fi*3+2]);
    }
    if ((fi & 63) == lane) {
      int wsl = fi >> 6;
#pragma unroll
      for (int s = 0; s < 32; ++s) if (s == wsl) kreg[s] = KINF;
    }
  }
}

// ---------------- mlp1 layer-1 stats (f32 compute, f64 partial store) -------
__global__ __launch_bounds__(256) void s1a_kernel(const float* __restrict__ drel,
                                                  const float* __restrict__ W1,
                                                  const float* __restrict__ b1,
                                                  double* __restrict__ part1) {
  __shared__ float sW[64];
  int tid = threadIdx.x;
  if (tid < 48) sW[tid] = W1[tid];
  if (tid < 16) sW[48+tid] = b1[tid];
  __syncthreads();
  const float4* src4 = (const float4*)(drel + ((size_t)blockIdx.x*1024 + tid*4)*3);
  float a[12];
#pragma unroll
  for (int q = 0; q < 3; ++q) { float4 t = src4[q]; a[q*4]=t.x; a[q*4+1]=t.y; a[q*4+2]=t.z; a[q*4+3]=t.w; }
  float s[16], s2[16];
#pragma unroll
  for (int c = 0; c < 16; ++c) { s[c] = 0.f; s2[c] = 0.f; }
#pragma unroll
  for (int i = 0; i < 4; ++i) {
    float a0 = a[i*3], a1 = a[i*3+1], a2 = a[i*3+2];
#pragma unroll
    for (int c = 0; c < 16; ++c) {
      float v = a0*sW[c] + a1*sW[16+c] + a2*sW[32+c] + sW[48+c];
      float e = eluf(v);
      s[c] += e; s2[c] += e*e;
    }
  }
  __shared__ float wred[4][32];
  int lane = tid & 63, wav = tid >> 6;
#pragma unroll
  for (int j = 0; j < 32; ++j) {
    float v = (j < 16) ? s[j] : s2[j-16];
    for (int sh = 32; sh > 0; sh >>= 1) v += __shfl_down(v, sh);
    if (lane == 0) wred[wav][j] = v;
  }
  __syncthreads();
  if (tid < 32)
    part1[(size_t)blockIdx.x*32 + tid] =
      (double)wred[0][tid] + (double)wred[1][tid] + (double)wred[2][tid] + (double)wred[3][tid];
}

// ---------------- mlp1 layer-2 stats (folds bn1 reduce; f32 compute) --------
__global__ __launch_bounds__(256) void s1b_kernel(const float* __restrict__ drel,
                                                  const float* __restrict__ W1,
                                                  const float* __restrict__ b1,
                                                  const float* __restrict__ W2,
                                                  const float* __restrict__ b2,
                                                  const double* __restrict__ part1,
                                                  const float* __restrict__ g1,
                                                  const float* __restrict__ be1,
                                                  double* __restrict__ part2) {
  int tid = threadIdx.x;
  __shared__ double red[8][32];
  __shared__ float fsc1[16], fsh1[16];
  __shared__ float sW[64];
  __shared__ float sW2t[256];
  {
    int j = tid & 31, grp = tid >> 5;
    double v = 0.0;
    for (int bk = grp; bk < 256; bk += 8) v += part1[(size_t)bk*32 + j];
    red[grp][j] = v;
  }
  if (tid < 48) sW[tid] = W1[tid];
  if (tid < 16) sW[48+tid] = b1[tid];
  sW2t[tid] = W2[(tid & 15)*16 + (tid >> 4)];   // sW2t[c2*16+j] = W2[j][c2]
  __syncthreads();
  if (tid < 32) {
    double v = 0.0;
    for (int g = 0; g < 8; ++g) v += red[g][tid];
    red[0][tid] = v;
  }
  __syncthreads();
  if (tid < 16) {
    double S = red[0][tid], S2 = red[0][16 + tid];
    double m = S/262144.0, var = S2/262144.0 - m*m;
    double sc = (double)g1[tid]/sqrt(var + 1e-5);
    fsc1[tid] = (float)sc;
    fsh1[tid] = (float)((double)be1[tid] - m*sc);
  }
  __syncthreads();
  const float4* src4 = (const float4*)(drel + ((size_t)blockIdx.x*1024 + tid*4)*3);
  float a[12];
#pragma unroll
  for (int q = 0; q < 3; ++q) { float4 t = src4[q]; a[q*4]=t.x; a[q*4+1]=t.y; a[q*4+2]=t.z; a[q*4+3]=t.w; }
  float s[16], s2[16];
#pragma unroll
  for (int c = 0; c < 16; ++c) { s[c] = 0.f; s2[c] = 0.f; }
#pragma unroll
  for (int i = 0; i < 4; ++i) {
    float a0 = a[i*3], a1 = a[i*3+1], a2 = a[i*3+2];
    float y[16];
#pragma unroll
    for (int c = 0; c < 16; ++c) {
      float v = a0*sW[c] + a1*sW[16+c] + a2*sW[32+c] + sW[48+c];
      y[c] = eluf(v)*fsc1[c] + fsh1[c];
    }
#pragma unroll
    for (int c2 = 0; c2 < 16; ++c2) {
      float v = b2[c2];
      const float4* w4 = (const float4*)&sW2t[c2*16];
#pragma unroll
      for (int j4 = 0; j4 < 4; ++j4) {
        float4 ww = w4[j4];
        v += y[j4*4]*ww.x + y[j4*4+1]*ww.y + y[j4*4+2]*ww.z + y[j4*4+3]*ww.w;
      }
      float e = eluf(v);
      s[c2] += e; s2[c2] += e*e;
    }
  }
  __shared__ float wred[4][32];
  int lane = tid & 63, wav = tid >> 6;
#pragma unroll
  for (int j = 0; j < 32; ++j) {
    float v = (j < 16) ? s[j] : s2[j-16];
    for (int sh = 32; sh > 0; sh >>= 1) v += __shfl_down(v, sh);
    if (lane == 0) wred[wav][j] = v;
  }
  __syncthreads();
  if (tid < 32)
    part2[(size_t)blockIdx.x*32 + tid] =
      (double)wred[0][tid] + (double)wred[1][tid] + (double)wred[2][tid] + (double)wred[3][tid];
}

// ---------------- mlp2 linear: 256 blocks x 64 rows -------------------------
__global__ __launch_bounds__(256) void s2l_kernel(const float* __restrict__ drel,
                                                  const float* __restrict__ Wl,
                                                  const float* __restrict__ bl,
                                                  float* __restrict__ tL,
                                                  double* __restrict__ partL) {
  __shared__ float srows[64*48];
  int tid = threadIdx.x;
  const float* src = drel + (size_t)blockIdx.x * 3072;
  for (int i = tid; i < 3072; i += 256) srows[i] = src[i];
  float w[48];
#pragma unroll
  for (int j = 0; j < 48; ++j) w[j] = Wl[j*256 + tid];
  float bias = bl[tid];
  __syncthreads();
  double s = 0.0, s2 = 0.0;
  for (int r = 0; r < 64; ++r) {
    float v = bias;
    const float4* sr = (const float4*)&srows[r*48];
#pragma unroll
    for (int j4 = 0; j4 < 12; ++j4) {
      float4 a4 = sr[j4];
      v += a4.x*w[j4*4] + a4.y*w[j4*4+1] + a4.z*w[j4*4+2] + a4.w*w[j4*4+3];
    }
    float e = eluf(v);
    tL[(size_t)(blockIdx.x*64 + r)*256 + tid] = e;
    double ed = (double)e;
    s += ed; s2 += ed*ed;
  }
  partL[(size_t)blockIdx.x*512 + tid]       = s;
  partL[(size_t)blockIdx.x*512 + 256 + tid] = s2;
}

// ---------------- grouped conv, IN-PLACE, 256 blocks x 64 rows --------------
template<int DO_ELU>
__global__ __launch_bounds__(256) void s2conv_kernel(const double* __restrict__ partIn,
                                                     const float* __restrict__ gIn,
                                                     const float* __restrict__ beIn,
                                                     const float* __restrict__ Wc,
                                                     const float* __restrict__ bc,
                                                     float* __restrict__ tBuf,
                                                     double* __restrict__ partOut) {
  int tid = threadIdx.x;
  double S = 0.0, S2 = 0.0;
  for (int bk = 0; bk < 256; ++bk) {
    S  += partIn[(size_t)bk*512 + tid];
    S2 += partIn[(size_t)bk*512 + 256 + tid];
  }
  double m = S/16384.0, var = S2/16384.0 - m*m;
  double scd = (double)gIn[tid]/sqrt(var + 1e-5);
  float sc = (float)scd, sh = (float)((double)beIn[tid] - m*scd);
  int g = tid >> 4, o = tid & 15;
  float w[16];
#pragma unroll
  for (int k = 0; k < 16; ++k) w[k] = Wc[g*256 + o*16 + k];
  float bias = bc[tid];
  __shared__ float sin_[16*256];
  double s = 0.0, s2 = 0.0;
  float* buf = tBuf + (size_t)blockIdx.x*64*256;
  for (int chunk = 0; chunk < 4; ++chunk) {
    __syncthreads();
    for (int rr = 0; rr < 16; ++rr)
      sin_[rr*256 + tid] = buf[(chunk*16 + rr)*256 + tid]*sc + sh;
    __syncthreads();
    for (int rr = 0; rr < 16; ++rr) {
      float v = bias;
      const float4* row4 = (const float4*)&sin_[rr*256 + g*16];
#pragma unroll
      for (int k4 = 0; k4 < 4; ++k4) {
        float4 a4 = row4[k4];
        v += a4.x*w[k4*4] + a4.y*w[k4*4+1] + a4.z*w[k4*4+2] + a4.w*w[k4*4+3];
      }
      float e = DO_ELU ? eluf(v) : v;
      buf[(chunk*16 + rr)*256 + tid] = e;
      double ed = (double)e;
      s += ed; s2 += ed*ed;
    }
  }
  partOut[(size_t)blockIdx.x*512 + tid]       = s;
  partOut[(size_t)blockIdx.x*512 + 256 + tid] = s2;
}

// ---------------- bn1/bn2/bnB -> f32 scale/shift ----------------------------
__global__ void bnall_kernel(const double* __restrict__ part1,
                             const double* __restrict__ part2,
                             const double* __restrict__ partB,
                             const float* __restrict__ g1, const float* __restrict__ be1,
                             const float* __restrict__ g2, const float* __restrict__ be2,
                             const float* __restrict__ gB, const float* __restrict__ beB,
                             float* __restrict__ bnp) {
  int tid = threadIdx.x;
  if (tid < 32) {
    int c = tid & 15;
    const double* P = (tid < 16) ? part1 : part2;
    double S = 0.0, S2 = 0.0;
    for (int bk = 0; bk < 256; ++bk) { S += P[(size_t)bk*32 + c]; S2 += P[(size_t)bk*32 + 16 + c]; }
    double m = S/262144.0, var = S2/262144.0 - m*m;
    const float* g  = (tid < 16) ? g1 : g2;
    const float* be = (tid < 16) ? be1 : be2;
    double sc = (double)g[c]/sqrt(var + 1e-5);
    int off = (tid < 16) ? 0 : 32;
    bnp[off + c]      = (float)sc;
    bnp[off + 16 + c] = (float)((double)be[c] - m*sc);
  }
  {
    double S = 0.0, S2 = 0.0;
    for (int bk = 0; bk < 256; ++bk) { S += partB[(size_t)bk*512 + tid]; S2 += partB[(size_t)bk*512 + 256 + tid]; }
    double m = S/16384.0, var = S2/16384.0 - m*m;
    double sc = (double)gB[tid]/sqrt(var + 1e-5);
    bnp[64 + tid]  = (float)sc;
    bnp[320 + tid] = (float)((double)beB[tid] - m*sc);
  }
}

// ---------------- final: 2 points/block; k-major LDS staging (bank-conflict
// free: the old xs[.][c][16] rows put 64 lanes on 2 banks = 32-way conflict,
// 1.24e7 conflict cycles/dispatch). xst[pt][k][80]: xt-stage reads 64
// consecutive words per k (2-way max); gather writes float4 16B-aligned.
// FP accumulation order identical (k-ascending per o). ----------------------
__global__ __launch_bounds__(256) void final_kernel(const float* __restrict__ x,
                                                    const int* __restrict__ idxbuf,
                                                    const float* __restrict__ drel,
                                                    const float* __restrict__ tB,
                                                    const float* __restrict__ bnp,
                                                    const float* __restrict__ W1,
                                                    const float* __restrict__ b1,
                                                    const float* __restrict__ W2,
                                                    const float* __restrict__ b2,
                                                    const float* __restrict__ Wd,
                                                    const float* __restrict__ bd,
                                                    const float* __restrict__ Wo,
                                                    const float* __restrict__ bo,
                                                    float* __restrict__ out) {
  int tid = threadIdx.x;
  int bn0 = blockIdx.x*2;
  int b = bn0 >> 11;
  __shared__ float sbn1[32], sbn2[32];
  __shared__ float sBs[256], sBh[256];
  __shared__ int   sidx[32];
  __shared__ float sdrel[96];
  __shared__ float sW1[48], sb1[16], sb2[16];
  __shared__ float sW2t[256];
  __shared__ float tmat[512];
  __shared__ float hs[2][16][17];
  __shared__ float xst[2][16][80];    // [pt][k][c]
  __shared__ float ovs[2][160];
  if (tid < 32) { sbn1[tid] = bnp[tid]; sbn2[tid] = bnp[32 + tid]; }
  sBs[tid] = bnp[64 + tid];
  sBh[tid] = bnp[320 + tid];
  if (tid < 32) sidx[tid] = idxbuf[bn0*16 + tid];
  if (tid < 96) sdrel[tid] = drel[(size_t)bn0*48 + tid];
  if (tid < 48) sW1[tid] = W1[tid];
  if (tid < 16) { sb1[tid] = b1[tid]; sb2[tid] = b2[tid]; }
  sW2t[tid] = W2[(tid & 15)*16 + (tid >> 4)];
  __syncthreads();
  for (int i = tid; i < 512; i += 256) {
    int c = i & 255;
    tmat[i] = tB[(size_t)bn0*256 + i]*sBs[c] + sBh[c];
  }
  for (int i = tid; i < 512; i += 256) {
    int pt = i >> 8, k = (i >> 4) & 15, c = i & 15;
    float a0 = sdrel[pt*48 + k*3], a1 = sdrel[pt*48 + k*3 + 1], a2 = sdrel[pt*48 + k*3 + 2];
    float v = a0*sW1[c] + a1*sW1[16+c] + a2*sW1[32+c] + sb1[c];
    hs[pt][k][c] = eluf(v)*sbn1[c] + sbn1[16+c];
  }
  __syncthreads();
  for (int i = tid; i < 512; i += 256) {
    int pt = i >> 8, k = (i >> 4) & 15, c2 = i & 15;
    float v = sb2[c2];
    const float4* w4 = (const float4*)&sW2t[c2*16];
    float* hrow = &hs[pt][k][0];
#pragma unroll
    for (int j4 = 0; j4 < 4; ++j4) {
      float4 ww = w4[j4];
      v += hrow[j4*4]*ww.x + hrow[j4*4+1]*ww.y + hrow[j4*4+2]*ww.z + hrow[j4*4+3]*ww.w;
    }
    xst[pt][k][c2] = eluf(v)*sbn2[c2] + sbn2[16+c2];
  }
  // x gather, float4-vectorized: 2pt x 16k x 16 float4 = 512 items
  for (int i = tid; i < 512; i += 256) {
    int pt = i >> 8, k = (i >> 4) & 15, c4 = i & 15;
    float4 xv = *(const float4*)&x[((size_t)b*NN + sidx[pt*16 + k])*64 + c4*4];
    *(float4*)&xst[pt][k][16 + c4*4] = xv;
  }
  __syncthreads();
  if (tid < 160) {
    int pt = (tid >= 80) ? 1 : 0;
    int c = tid - pt*80;
    float xtr[16];
#pragma unroll
    for (int o = 0; o < 16; ++o) xtr[o] = 0.f;
#pragma unroll
    for (int k = 0; k < 16; ++k) {
      float xv = xst[pt][k][c];
      const float* tm = &tmat[pt*256 + k*16];
#pragma unroll
      for (int o = 0; o < 16; ++o) xtr[o] += xv*tm[o];
    }
    float v0 = bd[c*2], v1 = bd[c*2 + 1];
#pragma unroll
    for (int k = 0; k < 16; ++k) {
      v0 += xtr[k]*Wd[c*32 + k];
      v1 += xtr[k]*Wd[c*32 + 16 + k];
    }
    ovs[pt][c*2]     = v0;
    ovs[pt][c*2 + 1] = v1;
  }
  __syncthreads();
  {
    int pt0 = tid >> 7, co = tid & 127;
    float v = bo[co];
    for (int i = 0; i < 160; ++i) v += ovs[pt0][i]*Wo[i*128 + co];
    out[(size_t)(bn0 + pt0)*128 + co] = v;
  }
}

extern "C" void kernel_launch(void* const* d_in, const int* in_sizes, int n_in,
                              void* d_out, int out_size, void* d_ws, size_t ws_size,
                              hipStream_t stream) {
  (void)in_sizes; (void)n_in; (void)out_size; (void)ws_size;
  const float* x   = (const float*)d_in[0];
  const float* pos = (const float*)d_in[1];
  const float* W1  = (const float*)d_in[2];
  const float* b1  = (const float*)d_in[3];
  const float* g1  = (const float*)d_in[4];
  const float* be1 = (const float*)d_in[5];
  const float* W2  = (const float*)d_in[6];
  const float* b2  = (const float*)d_in[7];
  const float* g2  = (const float*)d_in[8];
  const float* be2 = (const float*)d_in[9];
  const float* Wl  = (const float*)d_in[10];
  const float* bl  = (const float*)d_in[11];
  const float* gl  = (const float*)d_in[12];
  const float* bel = (const float*)d_in[13];
  const float* WcA = (const float*)d_in[14];
  const float* bcA = (const float*)d_in[15];
  const float* gA  = (const float*)d_in[16];
  const float* beA = (const float*)d_in[17];
  const float* WcB = (const float*)d_in[18];
  const float* bcB = (const float*)d_in[19];
  const float* gB  = (const float*)d_in[20];
  const float* beB = (const float*)d_in[21];
  const float* Wd  = (const float*)d_in[22];
  const float* bd  = (const float*)d_in[23];
  const float* Wo  = (const float*)d_in[24];
  const float* bo  = (const float*)d_in[25];
  float* out = (float*)d_out;

  char* ws = (char*)d_ws;
  int*    idxbuf = (int*)ws;                                        // 1 MB
  float*  drel   = (float*)(ws + (1u<<20));                         // 3 MB
  float*  bufX   = (float*)(ws + (4u<<20));                         // 16 MB
  double* part1  = (double*)(ws + (20u<<20));                       // 64 KB
  double* part2  = (double*)(ws + (20u<<20) + (64u<<10));           // 64 KB
  double* partL  = (double*)(ws + (20u<<20) + (128u<<10));          // 1 MB
  double* partA  = (double*)(ws + (20u<<20) + (128u<<10) + (1u<<20)); // 1 MB
  double* partB  = (double*)(ws + (20u<<20) + (128u<<10) + (2u<<20)); // 1 MB
  float*  bnp    = (float*)(ws + (20u<<20) + (128u<<10) + (3u<<20));  // 2.3 KB

  knn_kernel<<<dim3(4096), dim3(256), 0, stream>>>(pos, idxbuf, drel);
  s1a_kernel<<<dim3(256), dim3(256), 0, stream>>>(drel, W1, b1, part1);
  s1b_kernel<<<dim3(256), dim3(256), 0, stream>>>(drel, W1, b1, W2, b2, part1, g1, be1, part2);
  s2l_kernel<<<dim3(256), dim3(256), 0, stream>>>(drel, Wl, bl, bufX, partL);
  s2conv_kernel<1><<<dim3(256), dim3(256), 0, stream>>>(partL, gl, bel, WcA, bcA, bufX, partA);
  s2conv_kernel<0><<<dim3(256), dim3(256), 0, stream>>>(partA, gA, beA, WcB, bcB, bufX, partB);
  bnall_kernel<<<dim3(1), dim3(256), 0, stream>>>(part1, part2, partB, g1, be1, g2, be2, gB, beB, bnp);
  final_kernel<<<dim3(8192), dim3(256), 0, stream>>>(x, idxbuf, drel, bufX, bnp,
                                                     W1, b1, W2, b2, Wd, bd, Wo, bo, out);
}

// Round 12
// 337.367 us; speedup vs baseline: 3.6809x; 1.0578x over previous
//
#include <hip/hip_runtime.h>
#include <math.h>

#define NN 2048
#define KNbr 16
#define BNpts 16384
#define BNKr  262144

__device__ __forceinline__ float eluf(float v) { return v > 0.f ? v : expm1f(v); }

// ---------------- KNN: ONE WAVE PER QUERY, f64-min key selection. -----------
// Selection math byte-identical to validated round 11. Change: fi is
// wave-uniform (butterfly result), so hoist to SGPR via readfirstlane and
// clear the winner slot through a SCALAR switch (branch tree, ~15 SALU)
// instead of the 32-slot cndmask cascade (~100 VALU/round). Same slot of
// the same lane is cleared => bit-identical output.
__global__ __launch_bounds__(256) void knn_kernel(const float* __restrict__ pos,
                                                  int* __restrict__ idxout,
                                                  float* __restrict__ drel) {
  int wav = threadIdx.x >> 6, lane = threadIdx.x & 63;
  int bn = blockIdx.x*4 + wav;
  int b = bn >> 11, n = bn & (NN - 1);
  const float* pb = pos + (size_t)b * NN * 3;
  float qx = pb[n*3], qy = pb[n*3+1], qz = pb[n*3+2];
  float sqn = __fadd_rn(__fadd_rn(__fmul_rn(qx,qx), __fmul_rn(qy,qy)), __fmul_rn(qz,qz));
  double kreg[32];
#pragma unroll
  for (int s = 0; s < 32; ++s) {
    int m = s*64 + lane;
    float px = pb[m*3], py = pb[m*3+1], pz = pb[m*3+2];
    float sqm = __fadd_rn(__fadd_rn(__fmul_rn(px,px), __fmul_rn(py,py)), __fmul_rn(pz,pz));
    float dot = __fmaf_rn(qz, pz, __fmaf_rn(qy, py, __fmul_rn(qx, px)));
    float d2  = __fsub_rn(__fadd_rn(sqn, sqm), __fmul_rn(2.0f, dot));
    unsigned int bits = __float_as_uint(d2);
    unsigned int uf = bits ^ (((unsigned int)((int)bits >> 31)) >> 1);
    kreg[s] = __hiloint2double((int)uf, m);
  }
  const double KINF = __hiloint2double(0x7FF00000, 0);
  for (int k = 0; k < KNbr; ++k) {
    double g0 = fmin(fmin(kreg[0],  kreg[1]),  fmin(kreg[2],  kreg[3]));
    double g1 = fmin(fmin(kreg[4],  kreg[5]),  fmin(kreg[6],  kreg[7]));
    double g2 = fmin(fmin(kreg[8],  kreg[9]),  fmin(kreg[10], kreg[11]));
    double g3 = fmin(fmin(kreg[12], kreg[13]), fmin(kreg[14], kreg[15]));
    double g4 = fmin(fmin(kreg[16], kreg[17]), fmin(kreg[18], kreg[19]));
    double g5 = fmin(fmin(kreg[20], kreg[21]), fmin(kreg[22], kreg[23]));
    double g6 = fmin(fmin(kreg[24], kreg[25]), fmin(kreg[26], kreg[27]));
    double g7 = fmin(fmin(kreg[28], kreg[29]), fmin(kreg[30], kreg[31]));
    double bk = fmin(fmin(fmin(g0, g1), fmin(g2, g3)),
                     fmin(fmin(g4, g5), fmin(g6, g7)));
#pragma unroll
    for (int off = 32; off > 0; off >>= 1) {
      double ok = __shfl_xor(bk, off);
      bk = fmin(bk, ok);
    }
    // fi is wave-uniform; pin it to an SGPR so the clear switch is scalar.
    int fi = __builtin_amdgcn_readfirstlane(__double2loint(bk));
    if (lane == 0) {
      idxout[bn*KNbr + k] = fi;
      drel[(size_t)(bn*KNbr + k)*3 + 0] = __fsub_rn(qx, pb[fi*3+0]);
      drel[(size_t)(bn*KNbr + k)*3 + 1] = __fsub_rn(qy, pb[fi*3+1]);
      drel[(size_t)(bn*KNbr + k)*3 + 2] = __fsub_rn(qz, pb[fi*3+2]);
    }
    bool owner = (lane == (fi & 63));
#define CLR(i) case i: if (owner) kreg[i] = KINF; break;
    switch (fi >> 6) {
      CLR(0)  CLR(1)  CLR(2)  CLR(3)  CLR(4)  CLR(5)  CLR(6)  CLR(7)
      CLR(8)  CLR(9)  CLR(10) CLR(11) CLR(12) CLR(13) CLR(14) CLR(15)
      CLR(16) CLR(17) CLR(18) CLR(19) CLR(20) CLR(21) CLR(22) CLR(23)
      CLR(24) CLR(25) CLR(26) CLR(27) CLR(28) CLR(29) CLR(30) CLR(31)
    }
#undef CLR
  }
}

// ---------------- mlp1 layer-1 stats (f32 compute, f64 partial store) -------
__global__ __launch_bounds__(256) void s1a_kernel(const float* __restrict__ drel,
                                                  const float* __restrict__ W1,
                                                  const float* __restrict__ b1,
                                                  double* __restrict__ part1) {
  __shared__ float sW[64];
  int tid = threadIdx.x;
  if (tid < 48) sW[tid] = W1[tid];
  if (tid < 16) sW[48+tid] = b1[tid];
  __syncthreads();
  const float4* src4 = (const float4*)(drel + ((size_t)blockIdx.x*1024 + tid*4)*3);
  float a[12];
#pragma unroll
  for (int q = 0; q < 3; ++q) { float4 t = src4[q]; a[q*4]=t.x; a[q*4+1]=t.y; a[q*4+2]=t.z; a[q*4+3]=t.w; }
  float s[16], s2[16];
#pragma unroll
  for (int c = 0; c < 16; ++c) { s[c] = 0.f; s2[c] = 0.f; }
#pragma unroll
  for (int i = 0; i < 4; ++i) {
    float a0 = a[i*3], a1 = a[i*3+1], a2 = a[i*3+2];
#pragma unroll
    for (int c = 0; c < 16; ++c) {
      float v = a0*sW[c] + a1*sW[16+c] + a2*sW[32+c] + sW[48+c];
      float e = eluf(v);
      s[c] += e; s2[c] += e*e;
    }
  }
  __shared__ float wred[4][32];
  int lane = tid & 63, wav = tid >> 6;
#pragma unroll
  for (int j = 0; j < 32; ++j) {
    float v = (j < 16) ? s[j] : s2[j-16];
    for (int sh = 32; sh > 0; sh >>= 1) v += __shfl_down(v, sh);
    if (lane == 0) wred[wav][j] = v;
  }
  __syncthreads();
  if (tid < 32)
    part1[(size_t)blockIdx.x*32 + tid] =
      (double)wred[0][tid] + (double)wred[1][tid] + (double)wred[2][tid] + (double)wred[3][tid];
}

// ---------------- mlp1 layer-2 stats (folds bn1 reduce; f32 compute) --------
__global__ __launch_bounds__(256) void s1b_kernel(const float* __restrict__ drel,
                                                  const float* __restrict__ W1,
                                                  const float* __restrict__ b1,
                                                  const float* __restrict__ W2,
                                                  const float* __restrict__ b2,
                                                  const double* __restrict__ part1,
                                                  const float* __restrict__ g1,
                                                  const float* __restrict__ be1,
                                                  double* __restrict__ part2) {
  int tid = threadIdx.x;
  __shared__ double red[8][32];
  __shared__ float fsc1[16], fsh1[16];
  __shared__ float sW[64];
  __shared__ float sW2t[256];
  {
    int j = tid & 31, grp = tid >> 5;
    double v = 0.0;
    for (int bk = grp; bk < 256; bk += 8) v += part1[(size_t)bk*32 + j];
    red[grp][j] = v;
  }
  if (tid < 48) sW[tid] = W1[tid];
  if (tid < 16) sW[48+tid] = b1[tid];
  sW2t[tid] = W2[(tid & 15)*16 + (tid >> 4)];   // sW2t[c2*16+j] = W2[j][c2]
  __syncthreads();
  if (tid < 32) {
    double v = 0.0;
    for (int g = 0; g < 8; ++g) v += red[g][tid];
    red[0][tid] = v;
  }
  __syncthreads();
  if (tid < 16) {
    double S = red[0][tid], S2 = red[0][16 + tid];
    double m = S/262144.0, var = S2/262144.0 - m*m;
    double sc = (double)g1[tid]/sqrt(var + 1e-5);
    fsc1[tid] = (float)sc;
    fsh1[tid] = (float)((double)be1[tid] - m*sc);
  }
  __syncthreads();
  const float4* src4 = (const float4*)(drel + ((size_t)blockIdx.x*1024 + tid*4)*3);
  float a[12];
#pragma unroll
  for (int q = 0; q < 3; ++q) { float4 t = src4[q]; a[q*4]=t.x; a[q*4+1]=t.y; a[q*4+2]=t.z; a[q*4+3]=t.w; }
  float s[16], s2[16];
#pragma unroll
  for (int c = 0; c < 16; ++c) { s[c] = 0.f; s2[c] = 0.f; }
#pragma unroll
  for (int i = 0; i < 4; ++i) {
    float a0 = a[i*3], a1 = a[i*3+1], a2 = a[i*3+2];
    float y[16];
#pragma unroll
    for (int c = 0; c < 16; ++c) {
      float v = a0*sW[c] + a1*sW[16+c] + a2*sW[32+c] + sW[48+c];
      y[c] = eluf(v)*fsc1[c] + fsh1[c];
    }
#pragma unroll
    for (int c2 = 0; c2 < 16; ++c2) {
      float v = b2[c2];
      const float4* w4 = (const float4*)&sW2t[c2*16];
#pragma unroll
      for (int j4 = 0; j4 < 4; ++j4) {
        float4 ww = w4[j4];
        v += y[j4*4]*ww.x + y[j4*4+1]*ww.y + y[j4*4+2]*ww.z + y[j4*4+3]*ww.w;
      }
      float e = eluf(v);
      s[c2] += e; s2[c2] += e*e;
    }
  }
  __shared__ float wred[4][32];
  int lane = tid & 63, wav = tid >> 6;
#pragma unroll
  for (int j = 0; j < 32; ++j) {
    float v = (j < 16) ? s[j] : s2[j-16];
    for (int sh = 32; sh > 0; sh >>= 1) v += __shfl_down(v, sh);
    if (lane == 0) wred[wav][j] = v;
  }
  __syncthreads();
  if (tid < 32)
    part2[(size_t)blockIdx.x*32 + tid] =
      (double)wred[0][tid] + (double)wred[1][tid] + (double)wred[2][tid] + (double)wred[3][tid];
}

// ---------------- mlp2 linear: 256 blocks x 64 rows -------------------------
__global__ __launch_bounds__(256) void s2l_kernel(const float* __restrict__ drel,
                                                  const float* __restrict__ Wl,
                                                  const float* __restrict__ bl,
                                                  float* __restrict__ tL,
                                                  double* __restrict__ partL) {
  __shared__ float srows[64*48];
  int tid = threadIdx.x;
  const float* src = drel + (size_t)blockIdx.x * 3072;
  for (int i = tid; i < 3072; i += 256) srows[i] = src[i];
  float w[48];
#pragma unroll
  for (int j = 0; j < 48; ++j) w[j] = Wl[j*256 + tid];
  float bias = bl[tid];
  __syncthreads();
  double s = 0.0, s2 = 0.0;
  for (int r = 0; r < 64; ++r) {
    float v = bias;
    const float4* sr = (const float4*)&srows[r*48];
#pragma unroll
    for (int j4 = 0; j4 < 12; ++j4) {
      float4 a4 = sr[j4];
      v += a4.x*w[j4*4] + a4.y*w[j4*4+1] + a4.z*w[j4*4+2] + a4.w*w[j4*4+3];
    }
    float e = eluf(v);
    tL[(size_t)(blockIdx.x*64 + r)*256 + tid] = e;
    double ed = (double)e;
    s += ed; s2 += ed*ed;
  }
  partL[(size_t)blockIdx.x*512 + tid]       = s;
  partL[(size_t)blockIdx.x*512 + 256 + tid] = s2;
}

// ---------------- grouped conv, IN-PLACE, 256 blocks x 64 rows --------------
template<int DO_ELU>
__global__ __launch_bounds__(256) void s2conv_kernel(const double* __restrict__ partIn,
                                                     const float* __restrict__ gIn,
                                                     const float* __restrict__ beIn,
                                                     const float* __restrict__ Wc,
                                                     const float* __restrict__ bc,
                                                     float* __restrict__ tBuf,
                                                     double* __restrict__ partOut) {
  int tid = threadIdx.x;
  double S = 0.0, S2 = 0.0;
  for (int bk = 0; bk < 256; ++bk) {
    S  += partIn[(size_t)bk*512 + tid];
    S2 += partIn[(size_t)bk*512 + 256 + tid];
  }
  double m = S/16384.0, var = S2/16384.0 - m*m;
  double scd = (double)gIn[tid]/sqrt(var + 1e-5);
  float sc = (float)scd, sh = (float)((double)beIn[tid] - m*scd);
  int g = tid >> 4, o = tid & 15;
  float w[16];
#pragma unroll
  for (int k = 0; k < 16; ++k) w[k] = Wc[g*256 + o*16 + k];
  float bias = bc[tid];
  __shared__ float sin_[16*256];
  double s = 0.0, s2 = 0.0;
  float* buf = tBuf + (size_t)blockIdx.x*64*256;
  for (int chunk = 0; chunk < 4; ++chunk) {
    __syncthreads();
    for (int rr = 0; rr < 16; ++rr)
      sin_[rr*256 + tid] = buf[(chunk*16 + rr)*256 + tid]*sc + sh;
    __syncthreads();
    for (int rr = 0; rr < 16; ++rr) {
      float v = bias;
      const float4* row4 = (const float4*)&sin_[rr*256 + g*16];
#pragma unroll
      for (int k4 = 0; k4 < 4; ++k4) {
        float4 a4 = row4[k4];
        v += a4.x*w[k4*4] + a4.y*w[k4*4+1] + a4.z*w[k4*4+2] + a4.w*w[k4*4+3];
      }
      float e = DO_ELU ? eluf(v) : v;
      buf[(chunk*16 + rr)*256 + tid] = e;
      double ed = (double)e;
      s += ed; s2 += ed*ed;
    }
  }
  partOut[(size_t)blockIdx.x*512 + tid]       = s;
  partOut[(size_t)blockIdx.x*512 + 256 + tid] = s2;
}

// ---------------- bn1/bn2/bnB -> f32 scale/shift ----------------------------
__global__ void bnall_kernel(const double* __restrict__ part1,
                             const double* __restrict__ part2,
                             const double* __restrict__ partB,
                             const float* __restrict__ g1, const float* __restrict__ be1,
                             const float* __restrict__ g2, const float* __restrict__ be2,
                             const float* __restrict__ gB, const float* __restrict__ beB,
                             float* __restrict__ bnp) {
  int tid = threadIdx.x;
  if (tid < 32) {
    int c = tid & 15;
    const double* P = (tid < 16) ? part1 : part2;
    double S = 0.0, S2 = 0.0;
    for (int bk = 0; bk < 256; ++bk) { S += P[(size_t)bk*32 + c]; S2 += P[(size_t)bk*32 + 16 + c]; }
    double m = S/262144.0, var = S2/262144.0 - m*m;
    const float* g  = (tid < 16) ? g1 : g2;
    const float* be = (tid < 16) ? be1 : be2;
    double sc = (double)g[c]/sqrt(var + 1e-5);
    int off = (tid < 16) ? 0 : 32;
    bnp[off + c]      = (float)sc;
    bnp[off + 16 + c] = (float)((double)be[c] - m*sc);
  }
  {
    double S = 0.0, S2 = 0.0;
    for (int bk = 0; bk < 256; ++bk) { S += partB[(size_t)bk*512 + tid]; S2 += partB[(size_t)bk*512 + 256 + tid]; }
    double m = S/16384.0, var = S2/16384.0 - m*m;
    double sc = (double)gB[tid]/sqrt(var + 1e-5);
    bnp[64 + tid]  = (float)sc;
    bnp[320 + tid] = (float)((double)beB[tid] - m*sc);
  }
}

// ---------------- final: 2 points/block; k-major LDS staging ----------------
__global__ __launch_bounds__(256) void final_kernel(const float* __restrict__ x,
                                                    const int* __restrict__ idxbuf,
                                                    const float* __restrict__ drel,
                                                    const float* __restrict__ tB,
                                                    const float* __restrict__ bnp,
                                                    const float* __restrict__ W1,
                                                    const float* __restrict__ b1,
                                                    const float* __restrict__ W2,
                                                    const float* __restrict__ b2,
                                                    const float* __restrict__ Wd,
                                                    const float* __restrict__ bd,
                                                    const float* __restrict__ Wo,
                                                    const float* __restrict__ bo,
                                                    float* __restrict__ out) {
  int tid = threadIdx.x;
  int bn0 = blockIdx.x*2;
  int b = bn0 >> 11;
  __shared__ float sbn1[32], sbn2[32];
  __shared__ float sBs[256], sBh[256];
  __shared__ int   sidx[32];
  __shared__ float sdrel[96];
  __shared__ float sW1[48], sb1[16], sb2[16];
  __shared__ float sW2t[256];
  __shared__ float tmat[512];
  __shared__ float hs[2][16][17];
  __shared__ float xst[2][16][80];    // [pt][k][c]
  __shared__ float ovs[2][160];
  if (tid < 32) { sbn1[tid] = bnp[tid]; sbn2[tid] = bnp[32 + tid]; }
  sBs[tid] = bnp[64 + tid];
  sBh[tid] = bnp[320 + tid];
  if (tid < 32) sidx[tid] = idxbuf[bn0*16 + tid];
  if (tid < 96) sdrel[tid] = drel[(size_t)bn0*48 + tid];
  if (tid < 48) sW1[tid] = W1[tid];
  if (tid < 16) { sb1[tid] = b1[tid]; sb2[tid] = b2[tid]; }
  sW2t[tid] = W2[(tid & 15)*16 + (tid >> 4)];
  __syncthreads();
  for (int i = tid; i < 512; i += 256) {
    int c = i & 255;
    tmat[i] = tB[(size_t)bn0*256 + i]*sBs[c] + sBh[c];
  }
  for (int i = tid; i < 512; i += 256) {
    int pt = i >> 8, k = (i >> 4) & 15, c = i & 15;
    float a0 = sdrel[pt*48 + k*3], a1 = sdrel[pt*48 + k*3 + 1], a2 = sdrel[pt*48 + k*3 + 2];
    float v = a0*sW1[c] + a1*sW1[16+c] + a2*sW1[32+c] + sb1[c];
    hs[pt][k][c] = eluf(v)*sbn1[c] + sbn1[16+c];
  }
  __syncthreads();
  for (int i = tid; i < 512; i += 256) {
    int pt = i >> 8, k = (i >> 4) & 15, c2 = i & 15;
    float v = sb2[c2];
    const float4* w4 = (const float4*)&sW2t[c2*16];
    float* hrow = &hs[pt][k][0];
#pragma unroll
    for (int j4 = 0; j4 < 4; ++j4) {
      float4 ww = w4[j4];
      v += hrow[j4*4]*ww.x + hrow[j4*4+1]*ww.y + hrow[j4*4+2]*ww.z + hrow[j4*4+3]*ww.w;
    }
    xst[pt][k][c2] = eluf(v)*sbn2[c2] + sbn2[16+c2];
  }
  for (int i = tid; i < 512; i += 256) {
    int pt = i >> 8, k = (i >> 4) & 15, c4 = i & 15;
    float4 xv = *(const float4*)&x[((size_t)b*NN + sidx[pt*16 + k])*64 + c4*4];
    *(float4*)&xst[pt][k][16 + c4*4] = xv;
  }
  __syncthreads();
  if (tid < 160) {
    int pt = (tid >= 80) ? 1 : 0;
    int c = tid - pt*80;
    float xtr[16];
#pragma unroll
    for (int o = 0; o < 16; ++o) xtr[o] = 0.f;
#pragma unroll
    for (int k = 0; k < 16; ++k) {
      float xv = xst[pt][k][c];
      const float* tm = &tmat[pt*256 + k*16];
#pragma unroll
      for (int o = 0; o < 16; ++o) xtr[o] += xv*tm[o];
    }
    float v0 = bd[c*2], v1 = bd[c*2 + 1];
#pragma unroll
    for (int k = 0; k < 16; ++k) {
      v0 += xtr[k]*Wd[c*32 + k];
      v1 += xtr[k]*Wd[c*32 + 16 + k];
    }
    ovs[pt][c*2]     = v0;
    ovs[pt][c*2 + 1] = v1;
  }
  __syncthreads();
  {
    int pt0 = tid >> 7, co = tid & 127;
    float v = bo[co];
    for (int i = 0; i < 160; ++i) v += ovs[pt0][i]*Wo[i*128 + co];
    out[(size_t)(bn0 + pt0)*128 + co] = v;
  }
}

extern "C" void kernel_launch(void* const* d_in, const int* in_sizes, int n_in,
                              void* d_out, int out_size, void* d_ws, size_t ws_size,
                              hipStream_t stream) {
  (void)in_sizes; (void)n_in; (void)out_size; (void)ws_size;
  const float* x   = (const float*)d_in[0];
  const float* pos = (const float*)d_in[1];
  const float* W1  = (const float*)d_in[2];
  const float* b1  = (const float*)d_in[3];
  const float* g1  = (const float*)d_in[4];
  const float* be1 = (const float*)d_in[5];
  const float* W2  = (const float*)d_in[6];
  const float* b2  = (const float*)d_in[7];
  const float* g2  = (const float*)d_in[8];
  const float* be2 = (const float*)d_in[9];
  const float* Wl  = (const float*)d_in[10];
  const float* bl  = (const float*)d_in[11];
  const float* gl  = (const float*)d_in[12];
  const float* bel = (const float*)d_in[13];
  const float* WcA = (const float*)d_in[14];
  const float* bcA = (const float*)d_in[15];
  const float* gA  = (const float*)d_in[16];
  const float* beA = (const float*)d_in[17];
  const float* WcB = (const float*)d_in[18];
  const float* bcB = (const float*)d_in[19];
  const float* gB  = (const float*)d_in[20];
  const float* beB = (const float*)d_in[21];
  const float* Wd  = (const float*)d_in[22];
  const float* bd  = (const float*)d_in[23];
  const float* Wo  = (const float*)d_in[24];
  const float* bo  = (const float*)d_in[25];
  float* out = (float*)d_out;

  char* ws = (char*)d_ws;
  int*    idxbuf = (int*)ws;                                        // 1 MB
  float*  drel   = (float*)(ws + (1u<<20));                         // 3 MB
  float*  bufX   = (float*)(ws + (4u<<20));                         // 16 MB
  double* part1  = (double*)(ws + (20u<<20));                       // 64 KB
  double* part2  = (double*)(ws + (20u<<20) + (64u<<10));           // 64 KB
  double* partL  = (double*)(ws + (20u<<20) + (128u<<10));          // 1 MB
  double* partA  = (double*)(ws + (20u<<20) + (128u<<10) + (1u<<20)); // 1 MB
  double* partB  = (double*)(ws + (20u<<20) + (128u<<10) + (2u<<20)); // 1 MB
  float*  bnp    = (float*)(ws + (20u<<20) + (128u<<10) + (3u<<20));  // 2.3 KB

  knn_kernel<<<dim3(4096), dim3(256), 0, stream>>>(pos, idxbuf, drel);
  s1a_kernel<<<dim3(256), dim3(256), 0, stream>>>(drel, W1, b1, part1);
  s1b_kernel<<<dim3(256), dim3(256), 0, stream>>>(drel, W1, b1, W2, b2, part1, g1, be1, part2);
  s2l_kernel<<<dim3(256), dim3(256), 0, stream>>>(drel, Wl, bl, bufX, partL);
  s2conv_kernel<1><<<dim3(256), dim3(256), 0, stream>>>(partL, gl, bel, WcA, bcA, bufX, partA);
  s2conv_kernel<0><<<dim3(256), dim3(256), 0, stream>>>(partA, gA, beA, WcB, bcB, bufX, partB);
  bnall_kernel<<<dim3(1), dim3(256), 0, stream>>>(part1, part2, partB, g1, be1, g2, be2, gB, beB, bnp);
  final_kernel<<<dim3(8192), dim3(256), 0, stream>>>(x, idxbuf, drel, bufX, bnp,
                                                     W1, b1, W2, b2, Wd, bd, Wo, bo, out);
}

// Round 13
// 324.531 us; speedup vs baseline: 3.8265x; 1.0396x over previous
//
#include <hip/hip_runtime.h>
#include <math.h>

#define NN 2048
#define KNbr 16
#define BNpts 16384
#define BNKr  262144

__device__ __forceinline__ float eluf(float v) { return v > 0.f ? v : expm1f(v); }

// ---------------- KNN: ONE WAVE PER QUERY, f64-min key selection. -----------
// (validated round 12 — byte-identical)
__global__ __launch_bounds__(256) void knn_kernel(const float* __restrict__ pos,
                                                  int* __restrict__ idxout,
                                                  float* __restrict__ drel) {
  int wav = threadIdx.x >> 6, lane = threadIdx.x & 63;
  int bn = blockIdx.x*4 + wav;
  int b = bn >> 11, n = bn & (NN - 1);
  const float* pb = pos + (size_t)b * NN * 3;
  float qx = pb[n*3], qy = pb[n*3+1], qz = pb[n*3+2];
  float sqn = __fadd_rn(__fadd_rn(__fmul_rn(qx,qx), __fmul_rn(qy,qy)), __fmul_rn(qz,qz));
  double kreg[32];
#pragma unroll
  for (int s = 0; s < 32; ++s) {
    int m = s*64 + lane;
    float px = pb[m*3], py = pb[m*3+1], pz = pb[m*3+2];
    float sqm = __fadd_rn(__fadd_rn(__fmul_rn(px,px), __fmul_rn(py,py)), __fmul_rn(pz,pz));
    float dot = __fmaf_rn(qz, pz, __fmaf_rn(qy, py, __fmul_rn(qx, px)));
    float d2  = __fsub_rn(__fadd_rn(sqn, sqm), __fmul_rn(2.0f, dot));
    unsigned int bits = __float_as_uint(d2);
    unsigned int uf = bits ^ (((unsigned int)((int)bits >> 31)) >> 1);
    kreg[s] = __hiloint2double((int)uf, m);
  }
  const double KINF = __hiloint2double(0x7FF00000, 0);
  for (int k = 0; k < KNbr; ++k) {
    double g0 = fmin(fmin(kreg[0],  kreg[1]),  fmin(kreg[2],  kreg[3]));
    double g1 = fmin(fmin(kreg[4],  kreg[5]),  fmin(kreg[6],  kreg[7]));
    double g2 = fmin(fmin(kreg[8],  kreg[9]),  fmin(kreg[10], kreg[11]));
    double g3 = fmin(fmin(kreg[12], kreg[13]), fmin(kreg[14], kreg[15]));
    double g4 = fmin(fmin(kreg[16], kreg[17]), fmin(kreg[18], kreg[19]));
    double g5 = fmin(fmin(kreg[20], kreg[21]), fmin(kreg[22], kreg[23]));
    double g6 = fmin(fmin(kreg[24], kreg[25]), fmin(kreg[26], kreg[27]));
    double g7 = fmin(fmin(kreg[28], kreg[29]), fmin(kreg[30], kreg[31]));
    double bk = fmin(fmin(fmin(g0, g1), fmin(g2, g3)),
                     fmin(fmin(g4, g5), fmin(g6, g7)));
#pragma unroll
    for (int off = 32; off > 0; off >>= 1) {
      double ok = __shfl_xor(bk, off);
      bk = fmin(bk, ok);
    }
    int fi = __builtin_amdgcn_readfirstlane(__double2loint(bk));
    if (lane == 0) {
      idxout[bn*KNbr + k] = fi;
      drel[(size_t)(bn*KNbr + k)*3 + 0] = __fsub_rn(qx, pb[fi*3+0]);
      drel[(size_t)(bn*KNbr + k)*3 + 1] = __fsub_rn(qy, pb[fi*3+1]);
      drel[(size_t)(bn*KNbr + k)*3 + 2] = __fsub_rn(qz, pb[fi*3+2]);
    }
    bool owner = (lane == (fi & 63));
#define CLR(i) case i: if (owner) kreg[i] = KINF; break;
    switch (fi >> 6) {
      CLR(0)  CLR(1)  CLR(2)  CLR(3)  CLR(4)  CLR(5)  CLR(6)  CLR(7)
      CLR(8)  CLR(9)  CLR(10) CLR(11) CLR(12) CLR(13) CLR(14) CLR(15)
      CLR(16) CLR(17) CLR(18) CLR(19) CLR(20) CLR(21) CLR(22) CLR(23)
      CLR(24) CLR(25) CLR(26) CLR(27) CLR(28) CLR(29) CLR(30) CLR(31)
    }
#undef CLR
  }
}

// ---------------- mlp1 layer-1 stats (f32 compute, f64 partial store) -------
__global__ __launch_bounds__(256) void s1a_kernel(const float* __restrict__ drel,
                                                  const float* __restrict__ W1,
                                                  const float* __restrict__ b1,
                                                  double* __restrict__ part1) {
  __shared__ float sW[64];
  int tid = threadIdx.x;
  if (tid < 48) sW[tid] = W1[tid];
  if (tid < 16) sW[48+tid] = b1[tid];
  __syncthreads();
  const float4* src4 = (const float4*)(drel + ((size_t)blockIdx.x*1024 + tid*4)*3);
  float a[12];
#pragma unroll
  for (int q = 0; q < 3; ++q) { float4 t = src4[q]; a[q*4]=t.x; a[q*4+1]=t.y; a[q*4+2]=t.z; a[q*4+3]=t.w; }
  float s[16], s2[16];
#pragma unroll
  for (int c = 0; c < 16; ++c) { s[c] = 0.f; s2[c] = 0.f; }
#pragma unroll
  for (int i = 0; i < 4; ++i) {
    float a0 = a[i*3], a1 = a[i*3+1], a2 = a[i*3+2];
#pragma unroll
    for (int c = 0; c < 16; ++c) {
      float v = a0*sW[c] + a1*sW[16+c] + a2*sW[32+c] + sW[48+c];
      float e = eluf(v);
      s[c] += e; s2[c] += e*e;
    }
  }
  __shared__ float wred[4][32];
  int lane = tid & 63, wav = tid >> 6;
#pragma unroll
  for (int j = 0; j < 32; ++j) {
    float v = (j < 16) ? s[j] : s2[j-16];
    for (int sh = 32; sh > 0; sh >>= 1) v += __shfl_down(v, sh);
    if (lane == 0) wred[wav][j] = v;
  }
  __syncthreads();
  if (tid < 32)
    part1[(size_t)blockIdx.x*32 + tid] =
      (double)wred[0][tid] + (double)wred[1][tid] + (double)wred[2][tid] + (double)wred[3][tid];
}

// ---------------- mlp1 layer-2 stats (folds bn1 reduce; f32 compute) --------
__global__ __launch_bounds__(256) void s1b_kernel(const float* __restrict__ drel,
                                                  const float* __restrict__ W1,
                                                  const float* __restrict__ b1,
                                                  const float* __restrict__ W2,
                                                  const float* __restrict__ b2,
                                                  const double* __restrict__ part1,
                                                  const float* __restrict__ g1,
                                                  const float* __restrict__ be1,
                                                  double* __restrict__ part2) {
  int tid = threadIdx.x;
  __shared__ double red[8][32];
  __shared__ float fsc1[16], fsh1[16];
  __shared__ float sW[64];
  __shared__ float sW2t[256];
  {
    int j = tid & 31, grp = tid >> 5;
    double v = 0.0;
    for (int bk = grp; bk < 256; bk += 8) v += part1[(size_t)bk*32 + j];
    red[grp][j] = v;
  }
  if (tid < 48) sW[tid] = W1[tid];
  if (tid < 16) sW[48+tid] = b1[tid];
  sW2t[tid] = W2[(tid & 15)*16 + (tid >> 4)];   // sW2t[c2*16+j] = W2[j][c2]
  __syncthreads();
  if (tid < 32) {
    double v = 0.0;
    for (int g = 0; g < 8; ++g) v += red[g][tid];
    red[0][tid] = v;
  }
  __syncthreads();
  if (tid < 16) {
    double S = red[0][tid], S2 = red[0][16 + tid];
    double m = S/262144.0, var = S2/262144.0 - m*m;
    double sc = (double)g1[tid]/sqrt(var + 1e-5);
    fsc1[tid] = (float)sc;
    fsh1[tid] = (float)((double)be1[tid] - m*sc);
  }
  __syncthreads();
  const float4* src4 = (const float4*)(drel + ((size_t)blockIdx.x*1024 + tid*4)*3);
  float a[12];
#pragma unroll
  for (int q = 0; q < 3; ++q) { float4 t = src4[q]; a[q*4]=t.x; a[q*4+1]=t.y; a[q*4+2]=t.z; a[q*4+3]=t.w; }
  float s[16], s2[16];
#pragma unroll
  for (int c = 0; c < 16; ++c) { s[c] = 0.f; s2[c] = 0.f; }
#pragma unroll
  for (int i = 0; i < 4; ++i) {
    float a0 = a[i*3], a1 = a[i*3+1], a2 = a[i*3+2];
    float y[16];
#pragma unroll
    for (int c = 0; c < 16; ++c) {
      float v = a0*sW[c] + a1*sW[16+c] + a2*sW[32+c] + sW[48+c];
      y[c] = eluf(v)*fsc1[c] + fsh1[c];
    }
#pragma unroll
    for (int c2 = 0; c2 < 16; ++c2) {
      float v = b2[c2];
      const float4* w4 = (const float4*)&sW2t[c2*16];
#pragma unroll
      for (int j4 = 0; j4 < 4; ++j4) {
        float4 ww = w4[j4];
        v += y[j4*4]*ww.x + y[j4*4+1]*ww.y + y[j4*4+2]*ww.z + y[j4*4+3]*ww.w;
      }
      float e = eluf(v);
      s[c2] += e; s2[c2] += e*e;
    }
  }
  __shared__ float wred[4][32];
  int lane = tid & 63, wav = tid >> 6;
#pragma unroll
  for (int j = 0; j < 32; ++j) {
    float v = (j < 16) ? s[j] : s2[j-16];
    for (int sh = 32; sh > 0; sh >>= 1) v += __shfl_down(v, sh);
    if (lane == 0) wred[wav][j] = v;
  }
  __syncthreads();
  if (tid < 32)
    part2[(size_t)blockIdx.x*32 + tid] =
      (double)wred[0][tid] + (double)wred[1][tid] + (double)wred[2][tid] + (double)wred[3][tid];
}

// ---------------- mlp2 linear: 256 blocks x 64 rows -------------------------
__global__ __launch_bounds__(256) void s2l_kernel(const float* __restrict__ drel,
                                                  const float* __restrict__ Wl,
                                                  const float* __restrict__ bl,
                                                  float* __restrict__ tL,
                                                  double* __restrict__ partL) {
  __shared__ float srows[64*48];
  int tid = threadIdx.x;
  const float* src = drel + (size_t)blockIdx.x * 3072;
  for (int i = tid; i < 3072; i += 256) srows[i] = src[i];
  float w[48];
#pragma unroll
  for (int j = 0; j < 48; ++j) w[j] = Wl[j*256 + tid];
  float bias = bl[tid];
  __syncthreads();
  double s = 0.0, s2 = 0.0;
  for (int r = 0; r < 64; ++r) {
    float v = bias;
    const float4* sr = (const float4*)&srows[r*48];
#pragma unroll
    for (int j4 = 0; j4 < 12; ++j4) {
      float4 a4 = sr[j4];
      v += a4.x*w[j4*4] + a4.y*w[j4*4+1] + a4.z*w[j4*4+2] + a4.w*w[j4*4+3];
    }
    float e = eluf(v);
    tL[(size_t)(blockIdx.x*64 + r)*256 + tid] = e;
    double ed = (double)e;
    s += ed; s2 += ed*ed;
  }
  partL[(size_t)blockIdx.x*512 + tid]       = s;
  partL[(size_t)blockIdx.x*512 + 256 + tid] = s2;
}

// ---------------- BN partial reduce: part[256][512] -> sc/sh (f32) ----------
// 1 block x 1024 threads; thread (q,half,c): sums bk in [q*128,(q+1)*128).
__global__ __launch_bounds__(1024) void bnred_kernel(const double* __restrict__ part,
                                                     const float* __restrict__ g,
                                                     const float* __restrict__ be,
                                                     float* __restrict__ bnp) {
  __shared__ double red[1024];
  int t = threadIdx.x;
  int c = t & 255, half = (t >> 8) & 1, q = t >> 9;
  const double* p = part + (size_t)(q*128)*512 + half*256 + c;
  double v = 0.0;
  for (int bk = 0; bk < 128; ++bk) v += p[(size_t)bk*512];
  red[t] = v;
  __syncthreads();
  if (t < 256) {
    double S  = red[t]       + red[512 + t];
    double S2 = red[256 + t] + red[768 + t];
    double m = S/16384.0, var = S2/16384.0 - m*m;
    double sc = (double)g[t]/sqrt(var + 1e-5);
    bnp[t]       = (float)sc;
    bnp[256 + t] = (float)((double)be[t] - m*sc);
  }
}

// ---------------- grouped conv, IN-PLACE, 256 blocks x 64 rows --------------
// BN scale/shift now precomputed by bnred_kernel (removes the 1 MB/block
// redundant f64-partial prologue = 268 MB L2 per conv stage).
template<int DO_ELU>
__global__ __launch_bounds__(256) void s2conv_kernel(const float* __restrict__ bnIn,
                                                     const float* __restrict__ Wc,
                                                     const float* __restrict__ bc,
                                                     float* __restrict__ tBuf,
                                                     double* __restrict__ partOut) {
  int tid = threadIdx.x;
  float sc = bnIn[tid], sh = bnIn[256 + tid];
  int g = tid >> 4, o = tid & 15;
  float w[16];
#pragma unroll
  for (int k = 0; k < 16; ++k) w[k] = Wc[g*256 + o*16 + k];
  float bias = bc[tid];
  __shared__ float sin_[16*256];
  double s = 0.0, s2 = 0.0;
  float* buf = tBuf + (size_t)blockIdx.x*64*256;
  for (int chunk = 0; chunk < 4; ++chunk) {
    __syncthreads();
    for (int rr = 0; rr < 16; ++rr)
      sin_[rr*256 + tid] = buf[(chunk*16 + rr)*256 + tid]*sc + sh;
    __syncthreads();
    for (int rr = 0; rr < 16; ++rr) {
      float v = bias;
      const float4* row4 = (const float4*)&sin_[rr*256 + g*16];
#pragma unroll
      for (int k4 = 0; k4 < 4; ++k4) {
        float4 a4 = row4[k4];
        v += a4.x*w[k4*4] + a4.y*w[k4*4+1] + a4.z*w[k4*4+2] + a4.w*w[k4*4+3];
      }
      float e = DO_ELU ? eluf(v) : v;
      buf[(chunk*16 + rr)*256 + tid] = e;
      double ed = (double)e;
      s += ed; s2 += ed*ed;
    }
  }
  partOut[(size_t)blockIdx.x*512 + tid]       = s;
  partOut[(size_t)blockIdx.x*512 + 256 + tid] = s2;
}

// ---------------- bn1/bn2/bnB -> f32 scale/shift ----------------------------
__global__ void bnall_kernel(const double* __restrict__ part1,
                             const double* __restrict__ part2,
                             const double* __restrict__ partB,
                             const float* __restrict__ g1, const float* __restrict__ be1,
                             const float* __restrict__ g2, const float* __restrict__ be2,
                             const float* __restrict__ gB, const float* __restrict__ beB,
                             float* __restrict__ bnp) {
  int tid = threadIdx.x;
  if (tid < 32) {
    int c = tid & 15;
    const double* P = (tid < 16) ? part1 : part2;
    double S = 0.0, S2 = 0.0;
    for (int bk = 0; bk < 256; ++bk) { S += P[(size_t)bk*32 + c]; S2 += P[(size_t)bk*32 + 16 + c]; }
    double m = S/262144.0, var = S2/262144.0 - m*m;
    const float* g  = (tid < 16) ? g1 : g2;
    const float* be = (tid < 16) ? be1 : be2;
    double sc = (double)g[c]/sqrt(var + 1e-5);
    int off = (tid < 16) ? 0 : 32;
    bnp[off + c]      = (float)sc;
    bnp[off + 16 + c] = (float)((double)be[c] - m*sc);
  }
  {
    double S = 0.0, S2 = 0.0;
    for (int bk = 0; bk < 256; ++bk) { S += partB[(size_t)bk*512 + tid]; S2 += partB[(size_t)bk*512 + 256 + tid]; }
    double m = S/16384.0, var = S2/16384.0 - m*m;
    double sc = (double)gB[tid]/sqrt(var + 1e-5);
    bnp[64 + tid]  = (float)sc;
    bnp[320 + tid] = (float)((double)beB[tid] - m*sc);
  }
}

// ---------------- final: 4 points/block; k-major LDS staging ----------------
// 4 pts amortize Wo (320 vs 640 MB L2) and per-block bn/weight staging; the
// xt/dw stage pairs pt and pt+2 per thread so Wd loads are reused. FP order
// per point identical to round 12 (k-ascending, i-ascending).
__global__ __launch_bounds__(256) void final_kernel(const float* __restrict__ x,
                                                    const int* __restrict__ idxbuf,
                                                    const float* __restrict__ drel,
                                                    const float* __restrict__ tB,
                                                    const float* __restrict__ bnp,
                                                    const float* __restrict__ W1,
                                                    const float* __restrict__ b1,
                                                    const float* __restrict__ W2,
                                                    const float* __restrict__ b2,
                                                    const float* __restrict__ Wd,
                                                    const float* __restrict__ bd,
                                                    const float* __restrict__ Wo,
                                                    const float* __restrict__ bo,
                                                    float* __restrict__ out) {
  int tid = threadIdx.x;
  int bn0 = blockIdx.x*4;
  int b = bn0 >> 11;
  __shared__ float sbn1[32], sbn2[32];
  __shared__ float sBs[256], sBh[256];
  __shared__ int   sidx[64];
  __shared__ float sdrel[192];
  __shared__ float sW1[48], sb1[16], sb2[16];
  __shared__ float sW2t[256];
  __shared__ float tmat[1024];
  __shared__ float hs[4][16][17];
  __shared__ float xst[4][16][80];    // [pt][k][c]
  __shared__ float ovs[4][160];
  if (tid < 32) { sbn1[tid] = bnp[tid]; sbn2[tid] = bnp[32 + tid]; }
  sBs[tid] = bnp[64 + tid];
  sBh[tid] = bnp[320 + tid];
  if (tid < 64) sidx[tid] = idxbuf[bn0*16 + tid];
  if (tid < 192) sdrel[tid] = drel[(size_t)bn0*48 + tid];
  if (tid < 48) sW1[tid] = W1[tid];
  if (tid < 16) { sb1[tid] = b1[tid]; sb2[tid] = b2[tid]; }
  sW2t[tid] = W2[(tid & 15)*16 + (tid >> 4)];
  __syncthreads();
  for (int i = tid; i < 1024; i += 256) {
    int c = i & 255;
    tmat[i] = tB[(size_t)bn0*256 + i]*sBs[c] + sBh[c];
  }
  for (int i = tid; i < 1024; i += 256) {
    int pt = i >> 8, k = (i >> 4) & 15, c = i & 15;
    float a0 = sdrel[pt*48 + k*3], a1 = sdrel[pt*48 + k*3 + 1], a2 = sdrel[pt*48 + k*3 + 2];
    float v = a0*sW1[c] + a1*sW1[16+c] + a2*sW1[32+c] + sb1[c];
    hs[pt][k][c] = eluf(v)*sbn1[c] + sbn1[16+c];
  }
  __syncthreads();
  for (int i = tid; i < 1024; i += 256) {
    int pt = i >> 8, k = (i >> 4) & 15, c2 = i & 15;
    float v = sb2[c2];
    const float4* w4 = (const float4*)&sW2t[c2*16];
    float* hrow = &hs[pt][k][0];
#pragma unroll
    for (int j4 = 0; j4 < 4; ++j4) {
      float4 ww = w4[j4];
      v += hrow[j4*4]*ww.x + hrow[j4*4+1]*ww.y + hrow[j4*4+2]*ww.z + hrow[j4*4+3]*ww.w;
    }
    xst[pt][k][c2] = eluf(v)*sbn2[c2] + sbn2[16+c2];
  }
  for (int i = tid; i < 1024; i += 256) {
    int pt = i >> 8, k = (i >> 4) & 15, c4 = i & 15;
    float4 xv = *(const float4*)&x[((size_t)b*NN + sidx[pt*16 + k])*64 + c4*4];
    *(float4*)&xst[pt][k][16 + c4*4] = xv;
  }
  __syncthreads();
  if (tid < 160) {
    int pt = (tid >= 80) ? 1 : 0;
    int c = tid - pt*80;
    float xtr0[16], xtr1[16];
#pragma unroll
    for (int o = 0; o < 16; ++o) { xtr0[o] = 0.f; xtr1[o] = 0.f; }
#pragma unroll
    for (int k = 0; k < 16; ++k) {
      float xv0 = xst[pt][k][c];
      float xv1 = xst[pt + 2][k][c];
      const float* tm0 = &tmat[pt*256 + k*16];
      const float* tm1 = &tmat[(pt + 2)*256 + k*16];
#pragma unroll
      for (int o = 0; o < 16; ++o) {
        xtr0[o] += xv0*tm0[o];
        xtr1[o] += xv1*tm1[o];
      }
    }
    float b0 = bd[c*2], b1v = bd[c*2 + 1];
    float v00 = b0, v01 = b1v, v10 = b0, v11 = b1v;
#pragma unroll
    for (int k = 0; k < 16; ++k) {
      float w0 = Wd[c*32 + k], w1 = Wd[c*32 + 16 + k];
      v00 += xtr0[k]*w0; v01 += xtr0[k]*w1;
      v10 += xtr1[k]*w0; v11 += xtr1[k]*w1;
    }
    ovs[pt][c*2]       = v00;
    ovs[pt][c*2 + 1]   = v01;
    ovs[pt+2][c*2]     = v10;
    ovs[pt+2][c*2 + 1] = v11;
  }
  __syncthreads();
  {
    int pt0 = tid >> 7, co = tid & 127;
    float v0 = bo[co], v1 = v0;
#pragma unroll 8
    for (int i = 0; i < 160; ++i) {
      float wv = Wo[i*128 + co];
      v0 += ovs[pt0][i]*wv;
      v1 += ovs[pt0 + 2][i]*wv;
    }
    out[(size_t)(bn0 + pt0)*128 + co]     = v0;
    out[(size_t)(bn0 + pt0 + 2)*128 + co] = v1;
  }
}

extern "C" void kernel_launch(void* const* d_in, const int* in_sizes, int n_in,
                              void* d_out, int out_size, void* d_ws, size_t ws_size,
                              hipStream_t stream) {
  (void)in_sizes; (void)n_in; (void)out_size; (void)ws_size;
  const float* x   = (const float*)d_in[0];
  const float* pos = (const float*)d_in[1];
  const float* W1  = (const float*)d_in[2];
  const float* b1  = (const float*)d_in[3];
  const float* g1  = (const float*)d_in[4];
  const float* be1 = (const float*)d_in[5];
  const float* W2  = (const float*)d_in[6];
  const float* b2  = (const float*)d_in[7];
  const float* g2  = (const float*)d_in[8];
  const float* be2 = (const float*)d_in[9];
  const float* Wl  = (const float*)d_in[10];
  const float* bl  = (const float*)d_in[11];
  const float* gl  = (const float*)d_in[12];
  const float* bel = (const float*)d_in[13];
  const float* WcA = (const float*)d_in[14];
  const float* bcA = (const float*)d_in[15];
  const float* gA  = (const float*)d_in[16];
  const float* beA = (const float*)d_in[17];
  const float* WcB = (const float*)d_in[18];
  const float* bcB = (const float*)d_in[19];
  const float* gB  = (const float*)d_in[20];
  const float* beB = (const float*)d_in[21];
  const float* Wd  = (const float*)d_in[22];
  const float* bd  = (const float*)d_in[23];
  const float* Wo  = (const float*)d_in[24];
  const float* bo  = (const float*)d_in[25];
  float* out = (float*)d_out;

  char* ws = (char*)d_ws;
  int*    idxbuf = (int*)ws;                                        // 1 MB
  float*  drel   = (float*)(ws + (1u<<20));                         // 3 MB
  float*  bufX   = (float*)(ws + (4u<<20));                         // 16 MB
  double* part1  = (double*)(ws + (20u<<20));                       // 64 KB
  double* part2  = (double*)(ws + (20u<<20) + (64u<<10));           // 64 KB
  double* partL  = (double*)(ws + (20u<<20) + (128u<<10));          // 1 MB
  double* partA  = (double*)(ws + (20u<<20) + (128u<<10) + (1u<<20)); // 1 MB
  double* partB  = (double*)(ws + (20u<<20) + (128u<<10) + (2u<<20)); // 1 MB
  float*  bnp    = (float*)(ws + (20u<<20) + (128u<<10) + (3u<<20));  // 4 KB
  float*  bnpL   = (float*)(ws + (20u<<20) + (128u<<10) + (3u<<20) + 4096);   // 2 KB
  float*  bnpA   = (float*)(ws + (20u<<20) + (128u<<10) + (3u<<20) + 8192);   // 2 KB

  knn_kernel<<<dim3(4096), dim3(256), 0, stream>>>(pos, idxbuf, drel);
  s1a_kernel<<<dim3(256), dim3(256), 0, stream>>>(drel, W1, b1, part1);
  s1b_kernel<<<dim3(256), dim3(256), 0, stream>>>(drel, W1, b1, W2, b2, part1, g1, be1, part2);
  s2l_kernel<<<dim3(256), dim3(256), 0, stream>>>(drel, Wl, bl, bufX, partL);
  bnred_kernel<<<dim3(1), dim3(1024), 0, stream>>>(partL, gl, bel, bnpL);
  s2conv_kernel<1><<<dim3(256), dim3(256), 0, stream>>>(bnpL, WcA, bcA, bufX, partA);
  bnred_kernel<<<dim3(1), dim3(1024), 0, stream>>>(partA, gA, beA, bnpA);
  s2conv_kernel<0><<<dim3(256), dim3(256), 0, stream>>>(bnpA, WcB, bcB, bufX, partB);
  bnall_kernel<<<dim3(1), dim3(256), 0, stream>>>(part1, part2, partB, g1, be1, g2, be2, gB, beB, bnp);
  final_kernel<<<dim3(4096), dim3(256), 0, stream>>>(x, idxbuf, drel, bufX, bnp,
                                                     W1, b1, W2, b2, Wd, bd, Wo, bo, out);
}